// Round 3
// baseline (2386.724 us; speedup 1.0000x reference)
//
#include <hip/hip_runtime.h>
#include <hip/hip_bf16.h>

#define DEV __device__ __forceinline__

DEV float bf2f(__hip_bfloat16 v) { return __bfloat162float(v); }

// dtype-polymorphic load/store for internal h/xb buffers
DEV void  sth(float* p, float v)            { *p = v; }
DEV void  sth(__hip_bfloat16* p, float v)   { *p = __float2bfloat16(v); }
DEV float ldh(const float* p)               { return *p; }
DEV float ldh(const __hip_bfloat16* p)      { return bf2f(*p); }

// ---------------- dtype detection ----------------
// true bf16 N(0,1) data: no u16 with biased exp >= 0x8F (|v| >= 2^16).
// f32 data read as u16: low halves are uniform bits -> ~30-40% "bad".
__global__ void k_detect(const unsigned short* xr, int nprobe, int* flag) {
    __shared__ int red[256];
    int t = threadIdx.x, bad = 0;
    for (int i = t; i < nprobe; i += 256) {
        unsigned e = (xr[i] >> 7) & 0xFF;
        if (e >= 0x8F) bad++;
    }
    red[t] = bad; __syncthreads();
    for (int o = 128; o > 0; o >>= 1) { if (t < o) red[t] += red[t + o]; __syncthreads(); }
    if (t == 0) flag[0] = (red[0] > 256) ? 1 : 0;   // 1 = inputs are f32
}

// ---------------- ingest: convert all float inputs to canonical f32 ---------
struct Seg  { const void* src; int off; int len; };
struct Segs { Seg s[22]; };

__global__ void k_ingest(const void* xsrc, int nx, Segs segs, float* canon,
                         const int* flag) {
    int f32 = flag[0];
    int t = threadIdx.x;
    if (blockIdx.x < 64) {
        for (int i = blockIdx.x * 256 + t; i < nx; i += 64 * 256) {
            float v = f32 ? ((const float*)xsrc)[i] : bf2f(((const __hip_bfloat16*)xsrc)[i]);
            if (!(v == v) || fabsf(v) > 1e30f) v = 0.f;   // scrub
            canon[i] = v;
        }
    } else {
        Seg sg = segs.s[blockIdx.x - 64];
        for (int i = t; i < sg.len; i += 256) {
            float v = f32 ? ((const float*)sg.src)[i] : bf2f(((const __hip_bfloat16*)sg.src)[i]);
            if (!(v == v) || fabsf(v) > 1e30f) v = 0.f;
            canon[sg.off + i] = v;
        }
    }
}

// ---------------- exclusive scan over int[n] (1024 elems/block) -------------

__global__ void k_scan_partial(const int* __restrict__ a, int n, int* __restrict__ partials) {
    __shared__ int red[256];
    int t = threadIdx.x, b = blockIdx.x;
    int base = b * 1024 + t * 4;
    int s = 0;
    #pragma unroll
    for (int j = 0; j < 4; j++) { int i = base + j; if (i < n) s += a[i]; }
    red[t] = s; __syncthreads();
    for (int o = 128; o > 0; o >>= 1) { if (t < o) red[t] += red[t + o]; __syncthreads(); }
    if (t == 0) partials[b] = red[0];
}

__global__ void k_scan_serial(int* partials, int nb, int* total) {
    int run = 0;
    for (int i = 0; i < nb; i++) { int v = partials[i]; partials[i] = run; run += v; }
    if (total) *total = run;
}

__global__ void k_scan_final(const int* __restrict__ a, int n, const int* __restrict__ partials,
                             int* __restrict__ out) {
    __shared__ int sums[256];
    int t = threadIdx.x, b = blockIdx.x;
    int base = b * 1024 + t * 4;
    int v0 = 0, v1 = 0, v2 = 0, v3 = 0;
    if (base     < n) v0 = a[base];
    if (base + 1 < n) v1 = a[base + 1];
    if (base + 2 < n) v2 = a[base + 2];
    if (base + 3 < n) v3 = a[base + 3];
    int s = v0 + v1 + v2 + v3;
    sums[t] = s; __syncthreads();
    for (int o = 1; o < 256; o <<= 1) {
        int x = 0;
        if (t >= o) x = sums[t - o];
        __syncthreads();
        sums[t] += x;
        __syncthreads();
    }
    int run = partials[b] + (sums[t] - s);
    if (base     < n) { out[base]     = run; run += v0; }
    if (base + 1 < n) { out[base + 1] = run; run += v1; }
    if (base + 2 < n) { out[base + 2] = run; run += v2; }
    if (base + 3 < n) { out[base + 3] = run; run += v3; }
}

// ---------------- CSR build ----------------

__global__ void k_init(const float* __restrict__ xF, int N,
                       int* __restrict__ deg, int* __restrict__ msk) {
    int i = blockIdx.x * 256 + threadIdx.x;
    if (i < N) {
        deg[i] = 1;  // self-loop
        msk[i] = (xF[i * 3] == 0.0f) ? 1 : 0;
    }
}

__global__ void k_count(const int* __restrict__ eidx, int E, int N, int* __restrict__ deg) {
    int e = blockIdx.x * 256 + threadIdx.x;
    if (e < E) {
        int d = eidx[E + e];
        if ((unsigned)d < (unsigned)N) atomicAdd(&deg[d], 1);
    }
}

__global__ void k_cursor(const int* __restrict__ off, int N, int EE, int* __restrict__ cursor,
                         int* __restrict__ offN) {
    int i = blockIdx.x * 256 + threadIdx.x;
    if (i < N) cursor[i] = off[i];
    if (i == 0 && blockIdx.x == 0) *offN = EE;
}

__global__ void k_fill(const int* __restrict__ eidx, int E, int N, int EE,
                       int* __restrict__ cursor, int* __restrict__ esrc) {
    int e = blockIdx.x * 256 + threadIdx.x;
    if (e < E) {
        int s = eidx[e], d = eidx[E + e];
        if ((unsigned)d < (unsigned)N && (unsigned)s < (unsigned)N) {
            int p = atomicAdd(&cursor[d], 1);
            if ((unsigned)p < (unsigned)EE) esrc[p] = s;
        }
    } else if (e < E + N) {
        int i = e - E;
        int p = atomicAdd(&cursor[i], 1);
        if ((unsigned)p < (unsigned)EE) esrc[p] = i;
    }
}

// ---------------- GAT node kernels: h = x@W, attention dots -----------------
// one wave per node; lane l owns h columns l and l+64.

template<typename HT>
__global__ __launch_bounds__(256) void k_node_first(
    const float* __restrict__ xF, const float* __restrict__ W,
    const float* __restrict__ atS, const float* __restrict__ atD,
    int N, HT* __restrict__ h, float* __restrict__ as_, float* __restrict__ ad_) {
    __shared__ float Wl[3 * 128];
    __shared__ float aS[128], aD[128];
    int t = threadIdx.x;
    for (int i = t; i < 384; i += 256) Wl[i] = W[i];
    if (t < 128) { aS[t] = atS[t]; aD[t] = atD[t]; }
    __syncthreads();
    int lane = t & 63;
    int n = blockIdx.x * 4 + (t >> 6);
    if (n >= N) return;
    float xv = (lane < 3) ? xF[n * 3 + lane] : 0.f;
    float acc0 = 0.f, acc1 = 0.f;
    #pragma unroll
    for (int k = 0; k < 3; k++) {
        float xk = __shfl(xv, k, 64);
        acc0 += xk * Wl[k * 128 + lane];
        acc1 += xk * Wl[k * 128 + 64 + lane];
    }
    sth(&h[(size_t)n * 128 + lane], acc0);
    sth(&h[(size_t)n * 128 + 64 + lane], acc1);
    float p0 = acc0 * aS[lane], p1 = acc1 * aS[64 + lane];
    float q0 = acc0 * aD[lane], q1 = acc1 * aD[64 + lane];
    #pragma unroll
    for (int o = 1; o < 32; o <<= 1) {
        p0 += __shfl_xor(p0, o, 64); p1 += __shfl_xor(p1, o, 64);
        q0 += __shfl_xor(q0, o, 64); q1 += __shfl_xor(q1, o, 64);
    }
    if (lane == 0)  { as_[n*4+0] = p0; as_[n*4+2] = p1; ad_[n*4+0] = q0; ad_[n*4+2] = q1; }
    if (lane == 32) { as_[n*4+1] = p0; as_[n*4+3] = p1; ad_[n*4+1] = q0; ad_[n*4+3] = q1; }
}

template<typename HT>
__global__ __launch_bounds__(256) void k_node_mid(
    const HT* __restrict__ xin, const float* __restrict__ W,
    const float* __restrict__ atS, const float* __restrict__ atD,
    int N, HT* __restrict__ h, float* __restrict__ as_, float* __restrict__ ad_) {
    __shared__ float Wl[32 * 128];
    __shared__ float aS[128], aD[128];
    int t = threadIdx.x;
    for (int i = t; i < 4096; i += 256) Wl[i] = W[i];
    if (t < 128) { aS[t] = atS[t]; aD[t] = atD[t]; }
    __syncthreads();
    int lane = t & 63;
    int n = blockIdx.x * 4 + (t >> 6);
    if (n >= N) return;
    float xv = (lane < 32) ? ldh(&xin[(size_t)n * 32 + lane]) : 0.f;
    float acc0 = 0.f, acc1 = 0.f;
    #pragma unroll
    for (int k = 0; k < 32; k++) {
        float xk = __shfl(xv, k, 64);
        acc0 += xk * Wl[k * 128 + lane];
        acc1 += xk * Wl[k * 128 + 64 + lane];
    }
    sth(&h[(size_t)n * 128 + lane], acc0);
    sth(&h[(size_t)n * 128 + 64 + lane], acc1);
    float p0 = acc0 * aS[lane], p1 = acc1 * aS[64 + lane];
    float q0 = acc0 * aD[lane], q1 = acc1 * aD[64 + lane];
    #pragma unroll
    for (int o = 1; o < 32; o <<= 1) {
        p0 += __shfl_xor(p0, o, 64); p1 += __shfl_xor(p1, o, 64);
        q0 += __shfl_xor(q0, o, 64); q1 += __shfl_xor(q1, o, 64);
    }
    if (lane == 0)  { as_[n*4+0] = p0; as_[n*4+2] = p1; ad_[n*4+0] = q0; ad_[n*4+2] = q1; }
    if (lane == 32) { as_[n*4+1] = p0; as_[n*4+3] = p1; ad_[n*4+1] = q0; ad_[n*4+3] = q1; }
}

// ---------------- GAT edge kernel: per-dst softmax + weighted gather --------

template<typename HT>
__global__ __launch_bounds__(256) void k_edge(
    const HT* __restrict__ h, const float* __restrict__ as_, const float* __restrict__ ad_,
    const int* __restrict__ off, const int* __restrict__ esrc,
    const float* __restrict__ bias, int N, HT* __restrict__ xout) {
    int t = threadIdx.x;
    int lane = t & 63;
    int n = blockIdx.x * 4 + (t >> 6);
    if (n >= N) return;
    int beg = off[n], end = off[n + 1];
    float4 adn = ((const float4*)ad_)[n];

    float m0 = -1e30f, m1 = -1e30f, m2 = -1e30f, m3 = -1e30f;
    for (int e = beg + lane; e < end; e += 64) {
        int s = esrc[e];
        if ((unsigned)s >= (unsigned)N) continue;
        float4 a = ((const float4*)as_)[s];
        float v0 = a.x + adn.x; v0 = v0 >= 0.f ? v0 : 0.2f * v0;
        float v1 = a.y + adn.y; v1 = v1 >= 0.f ? v1 : 0.2f * v1;
        float v2 = a.z + adn.z; v2 = v2 >= 0.f ? v2 : 0.2f * v2;
        float v3 = a.w + adn.w; v3 = v3 >= 0.f ? v3 : 0.2f * v3;
        m0 = fmaxf(m0, v0); m1 = fmaxf(m1, v1); m2 = fmaxf(m2, v2); m3 = fmaxf(m3, v3);
    }
    #pragma unroll
    for (int o = 1; o < 64; o <<= 1) {
        m0 = fmaxf(m0, __shfl_xor(m0, o, 64));
        m1 = fmaxf(m1, __shfl_xor(m1, o, 64));
        m2 = fmaxf(m2, __shfl_xor(m2, o, 64));
        m3 = fmaxf(m3, __shfl_xor(m3, o, 64));
    }
    float s0 = 0.f, s1 = 0.f, s2 = 0.f, s3 = 0.f;
    for (int e = beg + lane; e < end; e += 64) {
        int s = esrc[e];
        if ((unsigned)s >= (unsigned)N) continue;
        float4 a = ((const float4*)as_)[s];
        float v0 = a.x + adn.x; v0 = v0 >= 0.f ? v0 : 0.2f * v0;
        float v1 = a.y + adn.y; v1 = v1 >= 0.f ? v1 : 0.2f * v1;
        float v2 = a.z + adn.z; v2 = v2 >= 0.f ? v2 : 0.2f * v2;
        float v3 = a.w + adn.w; v3 = v3 >= 0.f ? v3 : 0.2f * v3;
        s0 += __expf(v0 - m0); s1 += __expf(v1 - m1);
        s2 += __expf(v2 - m2); s3 += __expf(v3 - m3);
    }
    #pragma unroll
    for (int o = 1; o < 64; o <<= 1) {
        s0 += __shfl_xor(s0, o, 64); s1 += __shfl_xor(s1, o, 64);
        s2 += __shfl_xor(s2, o, 64); s3 += __shfl_xor(s3, o, 64);
    }
    float i0 = 1.f / (s0 + 1e-16f), i1 = 1.f / (s1 + 1e-16f);
    float i2 = 1.f / (s2 + 1e-16f), i3 = 1.f / (s3 + 1e-16f);

    bool lo = lane < 32;
    float mA = lo ? m0 : m1, mB = lo ? m2 : m3;
    float iA = lo ? i0 : i1, iB = lo ? i2 : i3;
    float adA = lo ? adn.x : adn.y, adB = lo ? adn.z : adn.w;
    float acc0 = 0.f, acc1 = 0.f;
    for (int e = beg; e < end; e++) {
        int s = esrc[e];
        if ((unsigned)s >= (unsigned)N) continue;
        float4 a = ((const float4*)as_)[s];
        float vA = (lo ? a.x : a.y) + adA; vA = vA >= 0.f ? vA : 0.2f * vA;
        float vB = (lo ? a.z : a.w) + adB; vB = vB >= 0.f ? vB : 0.2f * vB;
        float wA = __expf(vA - mA) * iA;
        float wB = __expf(vB - mB) * iB;
        acc0 += wA * ldh(&h[(size_t)s * 128 + lane]);
        acc1 += wB * ldh(&h[(size_t)s * 128 + 64 + lane]);
    }
    float v = acc0 + acc1;
    v += __shfl_xor(v, 32, 64);
    if (lane < 32) {
        float o = v * 0.25f + bias[lane];
        o = o >= 0.f ? o : 0.01f * o;
        sth(&xout[(size_t)n * 32 + lane], o);
    }
}

// ---------------- MLP + output scatter ----------------

template<typename HT>
__global__ __launch_bounds__(256) void k_mlp(
    const float* __restrict__ xF, const HT* __restrict__ x3,
    const float* __restrict__ mW1, const float* __restrict__ mb1,
    const float* __restrict__ mW2, const float* __restrict__ mb2,
    const float* __restrict__ mW3, const float* __restrict__ mb3,
    const float* __restrict__ mW4, const float* __restrict__ mb4,
    const float* __restrict__ mW5, const float* __restrict__ mb5,
    const int* __restrict__ smask, const int* __restrict__ totals,
    const int* __restrict__ flag, int N, void* __restrict__ out) {
    __shared__ float W1[35 * 32], W2[1024], W3[1024], W4[1024], W5[32 * 12];
    __shared__ float B1[32], B2[32], B3[32], B4[32], B5[12];
    int t = threadIdx.x;
    for (int i = t; i < 1120; i += 256) W1[i] = mW1[i];
    for (int i = t; i < 1024; i += 256) { W2[i] = mW2[i]; W3[i] = mW3[i]; W4[i] = mW4[i]; }
    for (int i = t; i < 384; i += 256) W5[i] = mW5[i];
    if (t < 32) { B1[t] = mb1[t]; B2[t] = mb2[t]; B3[t] = mb3[t]; B4[t] = mb4[t]; }
    if (t < 12) B5[t] = mb5[t];
    __syncthreads();
    int n = blockIdx.x * 256 + t;
    if (n >= N) return;

    float a[35];
    a[0] = xF[n * 3 + 0];
    a[1] = xF[n * 3 + 1];
    a[2] = xF[n * 3 + 2];
    #pragma unroll
    for (int i = 0; i < 32; i++) a[3 + i] = ldh(&x3[(size_t)n * 32 + i]);

    float b[32], c[32];
    #pragma unroll
    for (int o = 0; o < 32; o++) {
        float acc = B1[o];
        #pragma unroll
        for (int i = 0; i < 35; i++) acc += a[i] * W1[i * 32 + o];
        b[o] = acc >= 0.f ? acc : 0.01f * acc;
    }
    #pragma unroll
    for (int o = 0; o < 32; o++) {
        float acc = B2[o];
        #pragma unroll
        for (int i = 0; i < 32; i++) acc += b[i] * W2[i * 32 + o];
        c[o] = acc >= 0.f ? acc : 0.01f * acc;
    }
    #pragma unroll
    for (int o = 0; o < 32; o++) {
        float acc = B3[o];
        #pragma unroll
        for (int i = 0; i < 32; i++) acc += c[i] * W3[i * 32 + o];
        b[o] = acc >= 0.f ? acc : 0.01f * acc;
    }
    #pragma unroll
    for (int o = 0; o < 32; o++) {
        float acc = B4[o];
        #pragma unroll
        for (int i = 0; i < 32; i++) acc += b[i] * W4[i * 32 + o];
        c[o] = acc >= 0.f ? acc : 0.01f * acc;
    }
    float d[12];
    #pragma unroll
    for (int o = 0; o < 12; o++) {
        float acc = B5[o];
        #pragma unroll
        for (int i = 0; i < 32; i++) acc += c[i] * W5[i * 12 + o];
        if (!(acc == acc)) acc = 0.f;   // scrub: output can never carry NaN
        d[o] = acc;
    }

    bool tower = (a[0] == 0.0f);
    int r = smask[n];
    int Nt = *totals;
    int f32o = *flag;
    int base9, base3, rr;
    if (tower) { rr = r;     base9 = 0;      base3 = 9 * N; }
    else       { rr = n - r; base9 = 9 * Nt; base3 = 9 * N + 3 * Nt; }
    if (f32o) {
        float* o = (float*)out;
        #pragma unroll
        for (int j = 0; j < 9; j++) o[base9 + rr * 9 + j] = d[j];
        #pragma unroll
        for (int j = 0; j < 3; j++) o[base3 + rr * 3 + j] = d[9 + j];
    } else {
        __hip_bfloat16* o = (__hip_bfloat16*)out;
        #pragma unroll
        for (int j = 0; j < 9; j++) o[base9 + rr * 9 + j] = __float2bfloat16(d[j]);
        #pragma unroll
        for (int j = 0; j < 3; j++) o[base3 + rr * 3 + j] = __float2bfloat16(d[9 + j]);
    }
}

// ---------------- host-side pipeline (templated on internal dtype) ----------

template<typename HT>
static void run_layers(const float* xF, const float* canon, const int* coff,
                       const int* off, const int* esrc, const int* smsk,
                       const int* totals, const int* flag,
                       HT* h, HT* xb, float* as_, float* ad_,
                       int N, void* d_out, hipStream_t stream) {
    int g4 = (N + 3) / 4;
    int gN = (N + 255) / 256;
    const float* W1  = canon + coff[0];  const float* aS1 = canon + coff[1];
    const float* aD1 = canon + coff[2];  const float* b1  = canon + coff[3];
    const float* W2  = canon + coff[4];  const float* aS2 = canon + coff[5];
    const float* aD2 = canon + coff[6];  const float* b2  = canon + coff[7];
    const float* W3  = canon + coff[8];  const float* aS3 = canon + coff[9];
    const float* aD3 = canon + coff[10]; const float* b3  = canon + coff[11];
    const float* mW1 = canon + coff[12]; const float* mb1 = canon + coff[13];
    const float* mW2 = canon + coff[14]; const float* mb2 = canon + coff[15];
    const float* mW3 = canon + coff[16]; const float* mb3 = canon + coff[17];
    const float* mW4 = canon + coff[18]; const float* mb4 = canon + coff[19];
    const float* mW5 = canon + coff[20]; const float* mb5 = canon + coff[21];

    k_node_first<HT><<<g4, 256, 0, stream>>>(xF, W1, aS1, aD1, N, h, as_, ad_);
    k_edge<HT><<<g4, 256, 0, stream>>>(h, as_, ad_, off, esrc, b1, N, xb);
    k_node_mid<HT><<<g4, 256, 0, stream>>>(xb, W2, aS2, aD2, N, h, as_, ad_);
    k_edge<HT><<<g4, 256, 0, stream>>>(h, as_, ad_, off, esrc, b2, N, xb);
    k_node_mid<HT><<<g4, 256, 0, stream>>>(xb, W3, aS3, aD3, N, h, as_, ad_);
    k_edge<HT><<<g4, 256, 0, stream>>>(h, as_, ad_, off, esrc, b3, N, xb);
    k_mlp<HT><<<gN, 256, 0, stream>>>(xF, xb, mW1, mb1, mW2, mb2, mW3, mb3, mW4, mb4,
                                      mW5, mb5, smsk, totals, flag, N, d_out);
}

extern "C" void kernel_launch(void* const* d_in, const int* in_sizes, int n_in,
                              void* d_out, int out_size, void* d_ws, size_t ws_size,
                              hipStream_t stream) {
    const void* xraw = d_in[0];
    const int*  eidx = (const int*)d_in[1];
    // d_in[2] edge_attr: unused

    int N  = in_sizes[0] / 3;
    int E  = in_sizes[1] / 2;
    int EE = E + N;

    // canonical f32 region: x first, then the 22 float param arrays (inputs 3..24)
    Segs segs;
    int coff[22];
    int canonN = 3 * N;
    for (int i = 3; i <= 24; i++) {
        int a = i - 3;
        segs.s[a].src = d_in[i];
        segs.s[a].off = canonN;
        segs.s[a].len = in_sizes[i];
        coff[a] = canonN;
        canonN += in_sizes[i];
    }

    auto align16 = [](size_t v) { return (v + 15) & ~(size_t)15; };
    char* base = (char*)d_ws;
    size_t o = 0;
    float* canon = (float*)(base + o); o = align16(o + (size_t)canonN * 4);
    int* flag     = (int*)(base + o); o = align16(o + 16);
    int* partials = (int*)(base + o); o = align16(o + 4096);
    int* totals   = (int*)(base + o); o = align16(o + 16);
    int* off      = (int*)(base + o); o = align16(o + (size_t)(N + 1) * 4);
    int* cur      = (int*)(base + o); o = align16(o + (size_t)N * 4);
    int* esrc     = (int*)(base + o); o = align16(o + (size_t)EE * 4);
    int* smsk     = (int*)(base + o); o = align16(o + (size_t)N * 4);
    size_t fixed = o;

    size_t need_f32 = fixed + (size_t)N * 128 * 4 + (size_t)N * 32 * 4 + (size_t)N * 32 + 64;
    bool use_f32 = (ws_size >= need_f32);

    float* xF = canon;
    int nb = (N + 1023) / 1024;
    int gN = (N + 255) / 256;

    // dtype detect + ingest
    int nprobe = in_sizes[0] < 4096 ? in_sizes[0] : 4096;
    k_detect<<<1, 256, 0, stream>>>((const unsigned short*)xraw, nprobe, flag);
    k_ingest<<<64 + 22, 256, 0, stream>>>(xraw, 3 * N, segs, canon, flag);

    // CSR build (cur doubles as deg)
    k_init<<<gN, 256, 0, stream>>>(xF, N, cur, smsk);
    k_count<<<(E + 255) / 256, 256, 0, stream>>>(eidx, E, N, cur);
    k_scan_partial<<<nb, 256, 0, stream>>>(cur, N, partials);
    k_scan_serial<<<1, 1, 0, stream>>>(partials, nb, nullptr);
    k_scan_final<<<nb, 256, 0, stream>>>(cur, N, partials, off);
    k_cursor<<<gN, 256, 0, stream>>>(off, N, EE, cur, off + N);
    k_fill<<<(EE + 255) / 256, 256, 0, stream>>>(eidx, E, N, EE, cur, esrc);

    // tower-mask exclusive scan (in place)
    k_scan_partial<<<nb, 256, 0, stream>>>(smsk, N, partials);
    k_scan_serial<<<1, 1, 0, stream>>>(partials, nb, totals);
    k_scan_final<<<nb, 256, 0, stream>>>(smsk, N, partials, smsk);

    if (use_f32) {
        size_t q = fixed;
        float* h  = (float*)(base + q); q = align16(q + (size_t)N * 128 * 4);
        float* xb = (float*)(base + q); q = align16(q + (size_t)N * 32 * 4);
        float* as_ = (float*)(base + q); q = align16(q + (size_t)N * 16);
        float* ad_ = (float*)(base + q);
        run_layers<float>(xF, canon, coff, off, esrc, smsk, totals, flag,
                          h, xb, as_, ad_, N, d_out, stream);
    } else {
        size_t q = fixed;
        __hip_bfloat16* h  = (__hip_bfloat16*)(base + q); q = align16(q + (size_t)N * 128 * 2);
        __hip_bfloat16* xb = (__hip_bfloat16*)(base + q); q = align16(q + (size_t)N * 32 * 2);
        float* as_ = (float*)(base + q); q = align16(q + (size_t)N * 16);
        float* ad_ = (float*)(base + q);
        run_layers<__hip_bfloat16>(xF, canon, coff, off, esrc, smsk, totals, flag,
                                   h, xb, as_, ad_, N, d_out, stream);
    }
}

// Round 4
// 926.432 us; speedup vs baseline: 2.5763x; 2.5763x over previous
//
#include <hip/hip_runtime.h>
#include <hip/hip_bf16.h>

#define DEV __device__ __forceinline__

DEV float bf2f(__hip_bfloat16 v) { return __bfloat162float(v); }

// dtype-polymorphic load/store for internal h/xb buffers
DEV void  sth(float* p, float v)            { *p = v; }
DEV void  sth(__hip_bfloat16* p, float v)   { *p = __float2bfloat16(v); }
DEV float ldh(const float* p)               { return *p; }
DEV float ldh(const __hip_bfloat16* p)      { return bf2f(*p); }

// ---------------- dtype detection ----------------
// true bf16 N(0,1) data: no u16 with biased exp >= 0x8F (|v| >= 2^16).
// f32 data read as u16: low halves are uniform bits -> ~30-40% "bad".
__global__ void k_detect(const unsigned short* xr, int nprobe, int* flag) {
    __shared__ int red[256];
    int t = threadIdx.x, bad = 0;
    for (int i = t; i < nprobe; i += 256) {
        unsigned e = (xr[i] >> 7) & 0xFF;
        if (e >= 0x8F) bad++;
    }
    red[t] = bad; __syncthreads();
    for (int o = 128; o > 0; o >>= 1) { if (t < o) red[t] += red[t + o]; __syncthreads(); }
    if (t == 0) flag[0] = (red[0] > 256) ? 1 : 0;   // 1 = inputs are f32
}

// ---------------- ingest: convert all float inputs to canonical f32 ---------
struct Seg  { const void* src; int off; int len; };
struct Segs { Seg s[22]; };

__global__ void k_ingest(const void* xsrc, int nx, Segs segs, float* canon,
                         const int* flag) {
    int f32 = flag[0];
    int t = threadIdx.x;
    if (blockIdx.x < 64) {
        for (int i = blockIdx.x * 256 + t; i < nx; i += 64 * 256) {
            float v = f32 ? ((const float*)xsrc)[i] : bf2f(((const __hip_bfloat16*)xsrc)[i]);
            if (!(v == v) || fabsf(v) > 1e30f) v = 0.f;   // scrub
            canon[i] = v;
        }
    } else {
        Seg sg = segs.s[blockIdx.x - 64];
        for (int i = t; i < sg.len; i += 256) {
            float v = f32 ? ((const float*)sg.src)[i] : bf2f(((const __hip_bfloat16*)sg.src)[i]);
            if (!(v == v) || fabsf(v) > 1e30f) v = 0.f;
            canon[sg.off + i] = v;
        }
    }
}

// ---------------- exclusive scan over int[n] (1024 elems/block) -------------

__global__ void k_scan_partial(const int* __restrict__ a, int n, int* __restrict__ partials) {
    __shared__ int red[256];
    int t = threadIdx.x, b = blockIdx.x;
    int base = b * 1024 + t * 4;
    int s = 0;
    #pragma unroll
    for (int j = 0; j < 4; j++) { int i = base + j; if (i < n) s += a[i]; }
    red[t] = s; __syncthreads();
    for (int o = 128; o > 0; o >>= 1) { if (t < o) red[t] += red[t + o]; __syncthreads(); }
    if (t == 0) partials[b] = red[0];
}

__global__ void k_scan_serial(int* partials, int nb, int* total) {
    int run = 0;
    for (int i = 0; i < nb; i++) { int v = partials[i]; partials[i] = run; run += v; }
    if (total) *total = run;
}

__global__ void k_scan_final(const int* __restrict__ a, int n, const int* __restrict__ partials,
                             int* __restrict__ out) {
    __shared__ int sums[256];
    int t = threadIdx.x, b = blockIdx.x;
    int base = b * 1024 + t * 4;
    int v0 = 0, v1 = 0, v2 = 0, v3 = 0;
    if (base     < n) v0 = a[base];
    if (base + 1 < n) v1 = a[base + 1];
    if (base + 2 < n) v2 = a[base + 2];
    if (base + 3 < n) v3 = a[base + 3];
    int s = v0 + v1 + v2 + v3;
    sums[t] = s; __syncthreads();
    for (int o = 1; o < 256; o <<= 1) {
        int x = 0;
        if (t >= o) x = sums[t - o];
        __syncthreads();
        sums[t] += x;
        __syncthreads();
    }
    int run = partials[b] + (sums[t] - s);
    if (base     < n) { out[base]     = run; run += v0; }
    if (base + 1 < n) { out[base + 1] = run; run += v1; }
    if (base + 2 < n) { out[base + 2] = run; run += v2; }
    if (base + 3 < n) { out[base + 3] = run; run += v3; }
}

// ---------------- CSR build ----------------

__global__ void k_init(const float* __restrict__ xF, int N,
                       int* __restrict__ deg, int* __restrict__ msk) {
    int i = blockIdx.x * 256 + threadIdx.x;
    if (i < N) {
        deg[i] = 1;  // self-loop
        msk[i] = (xF[i * 3] == 0.0f) ? 1 : 0;
    }
}

__global__ void k_count(const int* __restrict__ eidx, int E, int N, int* __restrict__ deg) {
    int e = blockIdx.x * 256 + threadIdx.x;
    if (e < E) {
        int d = eidx[E + e];
        if ((unsigned)d < (unsigned)N) atomicAdd(&deg[d], 1);
    }
}

__global__ void k_cursor(const int* __restrict__ off, int N, int EE, int* __restrict__ cursor,
                         int* __restrict__ offN) {
    int i = blockIdx.x * 256 + threadIdx.x;
    if (i < N) cursor[i] = off[i];
    if (i == 0 && blockIdx.x == 0) *offN = EE;
}

__global__ void k_fill(const int* __restrict__ eidx, int E, int N, int EE,
                       int* __restrict__ cursor, int* __restrict__ esrc) {
    int e = blockIdx.x * 256 + threadIdx.x;
    if (e < E) {
        int s = eidx[e], d = eidx[E + e];
        if ((unsigned)d < (unsigned)N && (unsigned)s < (unsigned)N) {
            int p = atomicAdd(&cursor[d], 1);
            if ((unsigned)p < (unsigned)EE) esrc[p] = s;
        }
    } else if (e < E + N) {
        int i = e - E;
        int p = atomicAdd(&cursor[i], 1);
        if ((unsigned)p < (unsigned)EE) esrc[p] = i;
    }
}

// ---------------- GAT node kernels: h = x@W, attention dots -----------------
// one wave per node; lane l owns h columns l and l+64.

template<typename HT>
__global__ __launch_bounds__(256) void k_node_first(
    const float* __restrict__ xF, const float* __restrict__ W,
    const float* __restrict__ atS, const float* __restrict__ atD,
    int N, HT* __restrict__ h, float* __restrict__ as_, float* __restrict__ ad_) {
    __shared__ float Wl[3 * 128];
    __shared__ float aS[128], aD[128];
    int t = threadIdx.x;
    for (int i = t; i < 384; i += 256) Wl[i] = W[i];
    if (t < 128) { aS[t] = atS[t]; aD[t] = atD[t]; }
    __syncthreads();
    int lane = t & 63;
    int n = blockIdx.x * 4 + (t >> 6);
    if (n >= N) return;
    float xv = (lane < 3) ? xF[n * 3 + lane] : 0.f;
    float acc0 = 0.f, acc1 = 0.f;
    #pragma unroll
    for (int k = 0; k < 3; k++) {
        float xk = __shfl(xv, k, 64);
        acc0 += xk * Wl[k * 128 + lane];
        acc1 += xk * Wl[k * 128 + 64 + lane];
    }
    sth(&h[(size_t)n * 128 + lane], acc0);
    sth(&h[(size_t)n * 128 + 64 + lane], acc1);
    float p0 = acc0 * aS[lane], p1 = acc1 * aS[64 + lane];
    float q0 = acc0 * aD[lane], q1 = acc1 * aD[64 + lane];
    #pragma unroll
    for (int o = 1; o < 32; o <<= 1) {
        p0 += __shfl_xor(p0, o, 64); p1 += __shfl_xor(p1, o, 64);
        q0 += __shfl_xor(q0, o, 64); q1 += __shfl_xor(q1, o, 64);
    }
    if (lane == 0)  { as_[n*4+0] = p0; as_[n*4+2] = p1; ad_[n*4+0] = q0; ad_[n*4+2] = q1; }
    if (lane == 32) { as_[n*4+1] = p0; as_[n*4+3] = p1; ad_[n*4+1] = q0; ad_[n*4+3] = q1; }
}

template<typename HT>
__global__ __launch_bounds__(256) void k_node_mid(
    const HT* __restrict__ xin, const float* __restrict__ W,
    const float* __restrict__ atS, const float* __restrict__ atD,
    int N, HT* __restrict__ h, float* __restrict__ as_, float* __restrict__ ad_) {
    __shared__ float Wl[32 * 128];
    __shared__ float aS[128], aD[128];
    int t = threadIdx.x;
    for (int i = t; i < 4096; i += 256) Wl[i] = W[i];
    if (t < 128) { aS[t] = atS[t]; aD[t] = atD[t]; }
    __syncthreads();
    int lane = t & 63;
    int n = blockIdx.x * 4 + (t >> 6);
    if (n >= N) return;
    float xv = (lane < 32) ? ldh(&xin[(size_t)n * 32 + lane]) : 0.f;
    float acc0 = 0.f, acc1 = 0.f;
    #pragma unroll
    for (int k = 0; k < 32; k++) {
        float xk = __shfl(xv, k, 64);
        acc0 += xk * Wl[k * 128 + lane];
        acc1 += xk * Wl[k * 128 + 64 + lane];
    }
    sth(&h[(size_t)n * 128 + lane], acc0);
    sth(&h[(size_t)n * 128 + 64 + lane], acc1);
    float p0 = acc0 * aS[lane], p1 = acc1 * aS[64 + lane];
    float q0 = acc0 * aD[lane], q1 = acc1 * aD[64 + lane];
    #pragma unroll
    for (int o = 1; o < 32; o <<= 1) {
        p0 += __shfl_xor(p0, o, 64); p1 += __shfl_xor(p1, o, 64);
        q0 += __shfl_xor(q0, o, 64); q1 += __shfl_xor(q1, o, 64);
    }
    if (lane == 0)  { as_[n*4+0] = p0; as_[n*4+2] = p1; ad_[n*4+0] = q0; ad_[n*4+2] = q1; }
    if (lane == 32) { as_[n*4+1] = p0; as_[n*4+3] = p1; ad_[n*4+1] = q0; ad_[n*4+3] = q1; }
}

// ---------------- GAT edge kernel: per-dst softmax + weighted gather --------

template<typename HT>
__global__ __launch_bounds__(256) void k_edge(
    const HT* __restrict__ h, const float* __restrict__ as_, const float* __restrict__ ad_,
    const int* __restrict__ off, const int* __restrict__ esrc,
    const float* __restrict__ bias, int N, HT* __restrict__ xout) {
    int t = threadIdx.x;
    int lane = t & 63;
    int n = blockIdx.x * 4 + (t >> 6);
    if (n >= N) return;
    int beg = off[n], end = off[n + 1];
    float4 adn = ((const float4*)ad_)[n];

    float m0 = -1e30f, m1 = -1e30f, m2 = -1e30f, m3 = -1e30f;
    for (int e = beg + lane; e < end; e += 64) {
        int s = esrc[e];
        if ((unsigned)s >= (unsigned)N) continue;
        float4 a = ((const float4*)as_)[s];
        float v0 = a.x + adn.x; v0 = v0 >= 0.f ? v0 : 0.2f * v0;
        float v1 = a.y + adn.y; v1 = v1 >= 0.f ? v1 : 0.2f * v1;
        float v2 = a.z + adn.z; v2 = v2 >= 0.f ? v2 : 0.2f * v2;
        float v3 = a.w + adn.w; v3 = v3 >= 0.f ? v3 : 0.2f * v3;
        m0 = fmaxf(m0, v0); m1 = fmaxf(m1, v1); m2 = fmaxf(m2, v2); m3 = fmaxf(m3, v3);
    }
    #pragma unroll
    for (int o = 1; o < 64; o <<= 1) {
        m0 = fmaxf(m0, __shfl_xor(m0, o, 64));
        m1 = fmaxf(m1, __shfl_xor(m1, o, 64));
        m2 = fmaxf(m2, __shfl_xor(m2, o, 64));
        m3 = fmaxf(m3, __shfl_xor(m3, o, 64));
    }
    float s0 = 0.f, s1 = 0.f, s2 = 0.f, s3 = 0.f;
    for (int e = beg + lane; e < end; e += 64) {
        int s = esrc[e];
        if ((unsigned)s >= (unsigned)N) continue;
        float4 a = ((const float4*)as_)[s];
        float v0 = a.x + adn.x; v0 = v0 >= 0.f ? v0 : 0.2f * v0;
        float v1 = a.y + adn.y; v1 = v1 >= 0.f ? v1 : 0.2f * v1;
        float v2 = a.z + adn.z; v2 = v2 >= 0.f ? v2 : 0.2f * v2;
        float v3 = a.w + adn.w; v3 = v3 >= 0.f ? v3 : 0.2f * v3;
        s0 += __expf(v0 - m0); s1 += __expf(v1 - m1);
        s2 += __expf(v2 - m2); s3 += __expf(v3 - m3);
    }
    #pragma unroll
    for (int o = 1; o < 64; o <<= 1) {
        s0 += __shfl_xor(s0, o, 64); s1 += __shfl_xor(s1, o, 64);
        s2 += __shfl_xor(s2, o, 64); s3 += __shfl_xor(s3, o, 64);
    }
    float i0 = 1.f / (s0 + 1e-16f), i1 = 1.f / (s1 + 1e-16f);
    float i2 = 1.f / (s2 + 1e-16f), i3 = 1.f / (s3 + 1e-16f);

    bool lo = lane < 32;
    float mA = lo ? m0 : m1, mB = lo ? m2 : m3;
    float iA = lo ? i0 : i1, iB = lo ? i2 : i3;
    float adA = lo ? adn.x : adn.y, adB = lo ? adn.z : adn.w;
    float acc0 = 0.f, acc1 = 0.f;
    for (int e = beg; e < end; e++) {
        int s = esrc[e];
        if ((unsigned)s >= (unsigned)N) continue;
        float4 a = ((const float4*)as_)[s];
        float vA = (lo ? a.x : a.y) + adA; vA = vA >= 0.f ? vA : 0.2f * vA;
        float vB = (lo ? a.z : a.w) + adB; vB = vB >= 0.f ? vB : 0.2f * vB;
        float wA = __expf(vA - mA) * iA;
        float wB = __expf(vB - mB) * iB;
        acc0 += wA * ldh(&h[(size_t)s * 128 + lane]);
        acc1 += wB * ldh(&h[(size_t)s * 128 + 64 + lane]);
    }
    float v = acc0 + acc1;
    v += __shfl_xor(v, 32, 64);
    if (lane < 32) {
        float o = v * 0.25f + bias[lane];
        o = o >= 0.f ? o : 0.01f * o;
        sth(&xout[(size_t)n * 32 + lane], o);
    }
}

// ---------------- MLP + output scatter ----------------
// 128 threads/block, one node per thread. Activations live in LDS transposed
// (act[i*128+tid]) so NO per-thread array needs register promotion — only
// acc[32] is register-resident, touched by small fully-unrolled loops with
// constant indices. Weights read from LDS at wave-uniform addresses as float4
// (broadcast, conflict-free). This replaces the round-3 version whose fully
// unrolled 4500-stmt body overflowed LLVM's unroll/promotion limits ->
// per-thread arrays spilled to scratch -> 2.9 GB HBM traffic, 1500 us.

template<typename HT>
__global__ __launch_bounds__(128) void k_mlp(
    const float* __restrict__ xF, const HT* __restrict__ x3,
    const float* __restrict__ mW1, const float* __restrict__ mb1,
    const float* __restrict__ mW2, const float* __restrict__ mb2,
    const float* __restrict__ mW3, const float* __restrict__ mb3,
    const float* __restrict__ mW4, const float* __restrict__ mb4,
    const float* __restrict__ mW5, const float* __restrict__ mb5,
    const int* __restrict__ smask, const int* __restrict__ totals,
    const int* __restrict__ flag, int N, void* __restrict__ out) {
    __shared__ float W1[35 * 32], W2[1024], W3[1024], W4[1024], W5[32 * 12];
    __shared__ float B1[32], B2[32], B3[32], B4[32], B5[12];
    __shared__ float actA[35 * 128];   // layer inputs  (transposed: [i][tid])
    __shared__ float actB[32 * 128];   // layer outputs
    int t = threadIdx.x;
    for (int i = t; i < 1120; i += 128) W1[i] = mW1[i];
    for (int i = t; i < 1024; i += 128) { W2[i] = mW2[i]; W3[i] = mW3[i]; W4[i] = mW4[i]; }
    for (int i = t; i < 384; i += 128) W5[i] = mW5[i];
    if (t < 32) { B1[t] = mb1[t]; B2[t] = mb2[t]; B3[t] = mb3[t]; B4[t] = mb4[t]; }
    if (t < 12) B5[t] = mb5[t];
    __syncthreads();

    int n = blockIdx.x * 128 + t;
    bool alive = (n < N);
    float x0 = 0.f;
    if (alive) {
        x0 = xF[n * 3 + 0];
        actA[0 * 128 + t] = x0;
        actA[1 * 128 + t] = xF[n * 3 + 1];
        actA[2 * 128 + t] = xF[n * 3 + 2];
        for (int i = 0; i < 32; i++) actA[(3 + i) * 128 + t] = ldh(&x3[(size_t)n * 32 + i]);
    }
    // no cross-thread act sharing -> no barrier needed for act buffers

    float acc[32];

    // L1: 35 -> 32
    #pragma unroll
    for (int o = 0; o < 32; o++) acc[o] = B1[o];
    #pragma unroll 2
    for (int i = 0; i < 35; i++) {
        float ai = actA[i * 128 + t];
        const float4* w4 = (const float4*)&W1[i * 32];
        #pragma unroll
        for (int q = 0; q < 8; q++) {
            float4 w = w4[q];
            acc[q*4+0] += ai * w.x; acc[q*4+1] += ai * w.y;
            acc[q*4+2] += ai * w.z; acc[q*4+3] += ai * w.w;
        }
    }
    #pragma unroll
    for (int o = 0; o < 32; o++) { float v = acc[o]; actB[o * 128 + t] = (v >= 0.f ? v : 0.01f * v); }

    // L2: 32 -> 32
    #pragma unroll
    for (int o = 0; o < 32; o++) acc[o] = B2[o];
    #pragma unroll 2
    for (int i = 0; i < 32; i++) {
        float ai = actB[i * 128 + t];
        const float4* w4 = (const float4*)&W2[i * 32];
        #pragma unroll
        for (int q = 0; q < 8; q++) {
            float4 w = w4[q];
            acc[q*4+0] += ai * w.x; acc[q*4+1] += ai * w.y;
            acc[q*4+2] += ai * w.z; acc[q*4+3] += ai * w.w;
        }
    }
    #pragma unroll
    for (int o = 0; o < 32; o++) { float v = acc[o]; actA[o * 128 + t] = (v >= 0.f ? v : 0.01f * v); }

    // L3: 32 -> 32
    #pragma unroll
    for (int o = 0; o < 32; o++) acc[o] = B3[o];
    #pragma unroll 2
    for (int i = 0; i < 32; i++) {
        float ai = actA[i * 128 + t];
        const float4* w4 = (const float4*)&W3[i * 32];
        #pragma unroll
        for (int q = 0; q < 8; q++) {
            float4 w = w4[q];
            acc[q*4+0] += ai * w.x; acc[q*4+1] += ai * w.y;
            acc[q*4+2] += ai * w.z; acc[q*4+3] += ai * w.w;
        }
    }
    #pragma unroll
    for (int o = 0; o < 32; o++) { float v = acc[o]; actB[o * 128 + t] = (v >= 0.f ? v : 0.01f * v); }

    // L4: 32 -> 32
    #pragma unroll
    for (int o = 0; o < 32; o++) acc[o] = B4[o];
    #pragma unroll 2
    for (int i = 0; i < 32; i++) {
        float ai = actB[i * 128 + t];
        const float4* w4 = (const float4*)&W4[i * 32];
        #pragma unroll
        for (int q = 0; q < 8; q++) {
            float4 w = w4[q];
            acc[q*4+0] += ai * w.x; acc[q*4+1] += ai * w.y;
            acc[q*4+2] += ai * w.z; acc[q*4+3] += ai * w.w;
        }
    }
    #pragma unroll
    for (int o = 0; o < 32; o++) { float v = acc[o]; actA[o * 128 + t] = (v >= 0.f ? v : 0.01f * v); }

    // L5: 32 -> 12 (rows of W5 are 48 B -> 16B-aligned, 3 float4 per row)
    float d[12];
    #pragma unroll
    for (int o = 0; o < 12; o++) d[o] = B5[o];
    #pragma unroll 2
    for (int i = 0; i < 32; i++) {
        float ai = actA[i * 128 + t];
        const float4* w4 = (const float4*)&W5[i * 12];
        #pragma unroll
        for (int q = 0; q < 3; q++) {
            float4 w = w4[q];
            d[q*4+0] += ai * w.x; d[q*4+1] += ai * w.y;
            d[q*4+2] += ai * w.z; d[q*4+3] += ai * w.w;
        }
    }
    if (!alive) return;
    #pragma unroll
    for (int o = 0; o < 12; o++) if (!(d[o] == d[o])) d[o] = 0.f;  // NaN scrub

    bool tower = (x0 == 0.0f);
    int r = smask[n];
    int Nt = *totals;
    int f32o = *flag;
    int base9, base3, rr;
    if (tower) { rr = r;     base9 = 0;      base3 = 9 * N; }
    else       { rr = n - r; base9 = 9 * Nt; base3 = 9 * N + 3 * Nt; }
    if (f32o) {
        float* o = (float*)out;
        #pragma unroll
        for (int j = 0; j < 9; j++) o[base9 + rr * 9 + j] = d[j];
        #pragma unroll
        for (int j = 0; j < 3; j++) o[base3 + rr * 3 + j] = d[9 + j];
    } else {
        __hip_bfloat16* o = (__hip_bfloat16*)out;
        #pragma unroll
        for (int j = 0; j < 9; j++) o[base9 + rr * 9 + j] = __float2bfloat16(d[j]);
        #pragma unroll
        for (int j = 0; j < 3; j++) o[base3 + rr * 3 + j] = __float2bfloat16(d[9 + j]);
    }
}

// ---------------- host-side pipeline (templated on internal dtype) ----------

template<typename HT>
static void run_layers(const float* xF, const float* canon, const int* coff,
                       const int* off, const int* esrc, const int* smsk,
                       const int* totals, const int* flag,
                       HT* h, HT* xb, float* as_, float* ad_,
                       int N, void* d_out, hipStream_t stream) {
    int g4 = (N + 3) / 4;
    int gM = (N + 127) / 128;
    const float* W1  = canon + coff[0];  const float* aS1 = canon + coff[1];
    const float* aD1 = canon + coff[2];  const float* b1  = canon + coff[3];
    const float* W2  = canon + coff[4];  const float* aS2 = canon + coff[5];
    const float* aD2 = canon + coff[6];  const float* b2  = canon + coff[7];
    const float* W3  = canon + coff[8];  const float* aS3 = canon + coff[9];
    const float* aD3 = canon + coff[10]; const float* b3  = canon + coff[11];
    const float* mW1 = canon + coff[12]; const float* mb1 = canon + coff[13];
    const float* mW2 = canon + coff[14]; const float* mb2 = canon + coff[15];
    const float* mW3 = canon + coff[16]; const float* mb3 = canon + coff[17];
    const float* mW4 = canon + coff[18]; const float* mb4 = canon + coff[19];
    const float* mW5 = canon + coff[20]; const float* mb5 = canon + coff[21];

    k_node_first<HT><<<g4, 256, 0, stream>>>(xF, W1, aS1, aD1, N, h, as_, ad_);
    k_edge<HT><<<g4, 256, 0, stream>>>(h, as_, ad_, off, esrc, b1, N, xb);
    k_node_mid<HT><<<g4, 256, 0, stream>>>(xb, W2, aS2, aD2, N, h, as_, ad_);
    k_edge<HT><<<g4, 256, 0, stream>>>(h, as_, ad_, off, esrc, b2, N, xb);
    k_node_mid<HT><<<g4, 256, 0, stream>>>(xb, W3, aS3, aD3, N, h, as_, ad_);
    k_edge<HT><<<g4, 256, 0, stream>>>(h, as_, ad_, off, esrc, b3, N, xb);
    k_mlp<HT><<<gM, 128, 0, stream>>>(xF, xb, mW1, mb1, mW2, mb2, mW3, mb3, mW4, mb4,
                                      mW5, mb5, smsk, totals, flag, N, d_out);
}

extern "C" void kernel_launch(void* const* d_in, const int* in_sizes, int n_in,
                              void* d_out, int out_size, void* d_ws, size_t ws_size,
                              hipStream_t stream) {
    const void* xraw = d_in[0];
    const int*  eidx = (const int*)d_in[1];
    // d_in[2] edge_attr: unused

    int N  = in_sizes[0] / 3;
    int E  = in_sizes[1] / 2;
    int EE = E + N;

    // canonical f32 region: x first, then the 22 float param arrays (inputs 3..24)
    Segs segs;
    int coff[22];
    int canonN = 3 * N;
    for (int i = 3; i <= 24; i++) {
        int a = i - 3;
        segs.s[a].src = d_in[i];
        segs.s[a].off = canonN;
        segs.s[a].len = in_sizes[i];
        coff[a] = canonN;
        canonN += in_sizes[i];
    }

    auto align16 = [](size_t v) { return (v + 15) & ~(size_t)15; };
    char* base = (char*)d_ws;
    size_t o = 0;
    float* canon = (float*)(base + o); o = align16(o + (size_t)canonN * 4);
    int* flag     = (int*)(base + o); o = align16(o + 16);
    int* partials = (int*)(base + o); o = align16(o + 4096);
    int* totals   = (int*)(base + o); o = align16(o + 16);
    int* off      = (int*)(base + o); o = align16(o + (size_t)(N + 1) * 4);
    int* cur      = (int*)(base + o); o = align16(o + (size_t)N * 4);
    int* esrc     = (int*)(base + o); o = align16(o + (size_t)EE * 4);
    int* smsk     = (int*)(base + o); o = align16(o + (size_t)N * 4);
    size_t fixed = o;

    size_t need_f32 = fixed + (size_t)N * 128 * 4 + (size_t)N * 32 * 4 + (size_t)N * 32 + 64;
    bool use_f32 = (ws_size >= need_f32);

    float* xF = canon;
    int nb = (N + 1023) / 1024;
    int gN = (N + 255) / 256;

    // dtype detect + ingest
    int nprobe = in_sizes[0] < 4096 ? in_sizes[0] : 4096;
    k_detect<<<1, 256, 0, stream>>>((const unsigned short*)xraw, nprobe, flag);
    k_ingest<<<64 + 22, 256, 0, stream>>>(xraw, 3 * N, segs, canon, flag);

    // CSR build (cur doubles as deg)
    k_init<<<gN, 256, 0, stream>>>(xF, N, cur, smsk);
    k_count<<<(E + 255) / 256, 256, 0, stream>>>(eidx, E, N, cur);
    k_scan_partial<<<nb, 256, 0, stream>>>(cur, N, partials);
    k_scan_serial<<<1, 1, 0, stream>>>(partials, nb, nullptr);
    k_scan_final<<<nb, 256, 0, stream>>>(cur, N, partials, off);
    k_cursor<<<gN, 256, 0, stream>>>(off, N, EE, cur, off + N);
    k_fill<<<(EE + 255) / 256, 256, 0, stream>>>(eidx, E, N, EE, cur, esrc);

    // tower-mask exclusive scan (in place)
    k_scan_partial<<<nb, 256, 0, stream>>>(smsk, N, partials);
    k_scan_serial<<<1, 1, 0, stream>>>(partials, nb, totals);
    k_scan_final<<<nb, 256, 0, stream>>>(smsk, N, partials, smsk);

    if (use_f32) {
        size_t q = fixed;
        float* h  = (float*)(base + q); q = align16(q + (size_t)N * 128 * 4);
        float* xb = (float*)(base + q); q = align16(q + (size_t)N * 32 * 4);
        float* as_ = (float*)(base + q); q = align16(q + (size_t)N * 16);
        float* ad_ = (float*)(base + q);
        run_layers<float>(xF, canon, coff, off, esrc, smsk, totals, flag,
                          h, xb, as_, ad_, N, d_out, stream);
    } else {
        size_t q = fixed;
        __hip_bfloat16* h  = (__hip_bfloat16*)(base + q); q = align16(q + (size_t)N * 128 * 2);
        __hip_bfloat16* xb = (__hip_bfloat16*)(base + q); q = align16(q + (size_t)N * 32 * 2);
        float* as_ = (float*)(base + q); q = align16(q + (size_t)N * 16);
        float* ad_ = (float*)(base + q);
        run_layers<__hip_bfloat16>(xF, canon, coff, off, esrc, smsk, totals, flag,
                                   h, xb, as_, ad_, N, d_out, stream);
    }
}

// Round 5
// 728.050 us; speedup vs baseline: 3.2782x; 1.2725x over previous
//
#include <hip/hip_runtime.h>
#include <hip/hip_bf16.h>

#define DEV __device__ __forceinline__

DEV float bf2f(__hip_bfloat16 v) { return __bfloat162float(v); }

// ---------------- dtype detection ----------------
// true bf16 N(0,1) data: no u16 with biased exp >= 0x8F (|v| >= 2^16).
// f32 data read as u16: low halves are uniform bits -> ~30-40% "bad".
__global__ void k_detect(const unsigned short* xr, int nprobe, int* flag) {
    __shared__ int red[256];
    int t = threadIdx.x, bad = 0;
    for (int i = t; i < nprobe; i += 256) {
        unsigned e = (xr[i] >> 7) & 0xFF;
        if (e >= 0x8F) bad++;
    }
    red[t] = bad; __syncthreads();
    for (int o = 128; o > 0; o >>= 1) { if (t < o) red[t] += red[t + o]; __syncthreads(); }
    if (t == 0) flag[0] = (red[0] > 256) ? 1 : 0;   // 1 = inputs are f32
}

// ---------------- ingest: convert all float inputs to canonical f32 ---------
struct Seg  { const void* src; int off; int len; };
struct Segs { Seg s[22]; };

__global__ void k_ingest(const void* xsrc, int nx, Segs segs, float* canon,
                         const int* flag) {
    int f32 = flag[0];
    int t = threadIdx.x;
    if (blockIdx.x < 64) {
        for (int i = blockIdx.x * 256 + t; i < nx; i += 64 * 256) {
            float v = f32 ? ((const float*)xsrc)[i] : bf2f(((const __hip_bfloat16*)xsrc)[i]);
            if (!(v == v) || fabsf(v) > 1e30f) v = 0.f;   // scrub
            canon[i] = v;
        }
    } else {
        Seg sg = segs.s[blockIdx.x - 64];
        for (int i = t; i < sg.len; i += 256) {
            float v = f32 ? ((const float*)sg.src)[i] : bf2f(((const __hip_bfloat16*)sg.src)[i]);
            if (!(v == v) || fabsf(v) > 1e30f) v = 0.f;
            canon[sg.off + i] = v;
        }
    }
}

// ---------------- exclusive scan over int[n] (1024 elems/block) -------------

__global__ void k_scan_partial(const int* __restrict__ a, int n, int* __restrict__ partials) {
    __shared__ int red[256];
    int t = threadIdx.x, b = blockIdx.x;
    int base = b * 1024 + t * 4;
    int s = 0;
    #pragma unroll
    for (int j = 0; j < 4; j++) { int i = base + j; if (i < n) s += a[i]; }
    red[t] = s; __syncthreads();
    for (int o = 128; o > 0; o >>= 1) { if (t < o) red[t] += red[t + o]; __syncthreads(); }
    if (t == 0) partials[b] = red[0];
}

__global__ void k_scan_serial(int* partials, int nb, int* total) {
    int run = 0;
    for (int i = 0; i < nb; i++) { int v = partials[i]; partials[i] = run; run += v; }
    if (total) *total = run;
}

__global__ void k_scan_final(const int* __restrict__ a, int n, const int* __restrict__ partials,
                             int* __restrict__ out) {
    __shared__ int sums[256];
    int t = threadIdx.x, b = blockIdx.x;
    int base = b * 1024 + t * 4;
    int v0 = 0, v1 = 0, v2 = 0, v3 = 0;
    if (base     < n) v0 = a[base];
    if (base + 1 < n) v1 = a[base + 1];
    if (base + 2 < n) v2 = a[base + 2];
    if (base + 3 < n) v3 = a[base + 3];
    int s = v0 + v1 + v2 + v3;
    sums[t] = s; __syncthreads();
    for (int o = 1; o < 256; o <<= 1) {
        int x = 0;
        if (t >= o) x = sums[t - o];
        __syncthreads();
        sums[t] += x;
        __syncthreads();
    }
    int run = partials[b] + (sums[t] - s);
    if (base     < n) { out[base]     = run; run += v0; }
    if (base + 1 < n) { out[base + 1] = run; run += v1; }
    if (base + 2 < n) { out[base + 2] = run; run += v2; }
    if (base + 3 < n) { out[base + 3] = run; run += v3; }
}

// ---------------- CSR build ----------------

__global__ void k_init(const float* __restrict__ xF, int N,
                       int* __restrict__ deg, int* __restrict__ msk) {
    int i = blockIdx.x * 256 + threadIdx.x;
    if (i < N) {
        deg[i] = 1;  // self-loop
        msk[i] = (xF[i * 3] == 0.0f) ? 1 : 0;
    }
}

__global__ void k_count(const int* __restrict__ eidx, int E, int N, int* __restrict__ deg) {
    int e = blockIdx.x * 256 + threadIdx.x;
    if (e < E) {
        int d = eidx[E + e];
        if ((unsigned)d < (unsigned)N) atomicAdd(&deg[d], 1);
    }
}

__global__ void k_cursor(const int* __restrict__ off, int N, int EE, int* __restrict__ cursor,
                         int* __restrict__ offN) {
    int i = blockIdx.x * 256 + threadIdx.x;
    if (i < N) cursor[i] = off[i];
    if (i == 0 && blockIdx.x == 0) *offN = EE;
}

__global__ void k_fill(const int* __restrict__ eidx, int E, int N, int EE,
                       int* __restrict__ cursor, int* __restrict__ esrc) {
    int e = blockIdx.x * 256 + threadIdx.x;
    if (e < E) {
        int s = eidx[e], d = eidx[E + e];
        if ((unsigned)d < (unsigned)N && (unsigned)s < (unsigned)N) {
            int p = atomicAdd(&cursor[d], 1);
            if ((unsigned)p < (unsigned)EE) esrc[p] = s;
        }
    } else if (e < E + N) {
        int i = e - E;
        int p = atomicAdd(&cursor[i], 1);
        if ((unsigned)p < (unsigned)EE) esrc[p] = i;
    }
}

// ---------------- GAT node kernels ------------------------------------------
// One wave per node. Lane l owns COLUMN PAIR (2l, 2l+1) of h (head = l>>4).
// h stored as packed bf16x2: h2[n*64 + l] = {col 2l, col 2l+1} -> a gather
// of one h row is 256 B/wave instead of 512 B (the round-4 bottleneck).

__global__ __launch_bounds__(256) void k_node_first(
    const float* __restrict__ xF, const float* __restrict__ W,
    const float* __restrict__ atS, const float* __restrict__ atD,
    int N, __hip_bfloat162* __restrict__ h2, float* __restrict__ as_, float* __restrict__ ad_) {
    __shared__ float Wl[3 * 128];
    __shared__ float aS[128], aD[128];
    int t = threadIdx.x;
    for (int i = t; i < 384; i += 256) Wl[i] = W[i];
    if (t < 128) { aS[t] = atS[t]; aD[t] = atD[t]; }
    __syncthreads();
    int lane = t & 63;
    int n = blockIdx.x * 4 + (t >> 6);
    if (n >= N) return;
    float xv = (lane < 3) ? xF[n * 3 + lane] : 0.f;
    float acc0 = 0.f, acc1 = 0.f;
    const float2* W2 = (const float2*)Wl;
    #pragma unroll
    for (int k = 0; k < 3; k++) {
        float xk = __shfl(xv, k, 64);
        float2 wv = W2[k * 64 + lane];          // cols 2l, 2l+1 (2-way alias: free)
        acc0 += xk * wv.x; acc1 += xk * wv.y;
    }
    __hip_bfloat162 hv; hv.x = __float2bfloat16(acc0); hv.y = __float2bfloat16(acc1);
    h2[(size_t)n * 64 + lane] = hv;
    int c0 = 2 * lane;
    float p = acc0 * aS[c0] + acc1 * aS[c0 + 1];
    float q = acc0 * aD[c0] + acc1 * aD[c0 + 1];
    #pragma unroll
    for (int o = 1; o < 16; o <<= 1) { p += __shfl_xor(p, o, 64); q += __shfl_xor(q, o, 64); }
    if ((lane & 15) == 0) { int hd = lane >> 4; as_[n * 4 + hd] = p; ad_[n * 4 + hd] = q; }
}

__global__ __launch_bounds__(256) void k_node_mid(
    const float* __restrict__ xin, const float* __restrict__ W,
    const float* __restrict__ atS, const float* __restrict__ atD,
    int N, __hip_bfloat162* __restrict__ h2, float* __restrict__ as_, float* __restrict__ ad_) {
    __shared__ float Wl[32 * 128];
    __shared__ float aS[128], aD[128];
    int t = threadIdx.x;
    for (int i = t; i < 4096; i += 256) Wl[i] = W[i];
    if (t < 128) { aS[t] = atS[t]; aD[t] = atD[t]; }
    __syncthreads();
    int lane = t & 63;
    int n = blockIdx.x * 4 + (t >> 6);
    if (n >= N) return;
    float xv = (lane < 32) ? xin[(size_t)n * 32 + lane] : 0.f;
    float acc0 = 0.f, acc1 = 0.f;
    const float2* W2 = (const float2*)Wl;
    #pragma unroll
    for (int k = 0; k < 32; k++) {
        float xk = __shfl(xv, k, 64);
        float2 wv = W2[k * 64 + lane];
        acc0 += xk * wv.x; acc1 += xk * wv.y;
    }
    __hip_bfloat162 hv; hv.x = __float2bfloat16(acc0); hv.y = __float2bfloat16(acc1);
    h2[(size_t)n * 64 + lane] = hv;
    int c0 = 2 * lane;
    float p = acc0 * aS[c0] + acc1 * aS[c0 + 1];
    float q = acc0 * aD[c0] + acc1 * aD[c0 + 1];
    #pragma unroll
    for (int o = 1; o < 16; o <<= 1) { p += __shfl_xor(p, o, 64); q += __shfl_xor(q, o, 64); }
    if ((lane & 15) == 0) { int hd = lane >> 4; as_[n * 4 + hd] = p; ad_[n * 4 + hd] = q; }
}

// ---------------- GAT edge kernel -------------------------------------------
// One wave per dst node. Softmax weights computed once in the sum-exp pass and
// stashed in LDS (alpha SoA, head-stride padded to 264 so the 4 broadcast
// groups of phase 2 hit distinct banks); phase 2 = LDS read + coalesced
// 256 B/edge bf16 h-row gather + 2 FMA. Degree>256 falls back to recompute.

constexpr int ECAP  = 256;
constexpr int ECAPP = 264;

__global__ __launch_bounds__(256) void k_edge(
    const __hip_bfloat162* __restrict__ h2, const float* __restrict__ as_,
    const float* __restrict__ ad_, const int* __restrict__ off,
    const int* __restrict__ esrc, const float* __restrict__ bias,
    int N, float* __restrict__ xout) {
    __shared__ float alphaS[4][4 * ECAPP];
    __shared__ int   srcS[4][ECAP];
    int t = threadIdx.x, lane = t & 63, w = t >> 6;
    int n = blockIdx.x * 4 + w;
    if (n >= N) return;
    int beg = off[n], end = off[n + 1];
    int deg = end - beg;
    bool fits = (deg <= ECAP);
    float4 adn = ((const float4*)ad_)[n];
    const float4* as4 = (const float4*)as_;

    // pass 1: per-head max
    float m0 = -1e30f, m1 = -1e30f, m2 = -1e30f, m3 = -1e30f;
    for (int e = beg + lane; e < end; e += 64) {
        int s = esrc[e];
        if ((unsigned)s >= (unsigned)N) continue;
        float4 a = as4[s];
        float v0 = a.x + adn.x; v0 = v0 >= 0.f ? v0 : 0.2f * v0;
        float v1 = a.y + adn.y; v1 = v1 >= 0.f ? v1 : 0.2f * v1;
        float v2 = a.z + adn.z; v2 = v2 >= 0.f ? v2 : 0.2f * v2;
        float v3 = a.w + adn.w; v3 = v3 >= 0.f ? v3 : 0.2f * v3;
        m0 = fmaxf(m0, v0); m1 = fmaxf(m1, v1); m2 = fmaxf(m2, v2); m3 = fmaxf(m3, v3);
    }
    #pragma unroll
    for (int o = 1; o < 64; o <<= 1) {
        m0 = fmaxf(m0, __shfl_xor(m0, o, 64));
        m1 = fmaxf(m1, __shfl_xor(m1, o, 64));
        m2 = fmaxf(m2, __shfl_xor(m2, o, 64));
        m3 = fmaxf(m3, __shfl_xor(m3, o, 64));
    }
    // pass 2: sum of exp + stash per-edge alpha and src in LDS
    float s0 = 0.f, s1 = 0.f, s2 = 0.f, s3 = 0.f;
    for (int e = beg + lane; e < end; e += 64) {
        int s = esrc[e];
        bool ok = (unsigned)s < (unsigned)N;
        float4 a = ok ? as4[s] : make_float4(-1e30f, -1e30f, -1e30f, -1e30f);
        float v0 = a.x + adn.x; v0 = v0 >= 0.f ? v0 : 0.2f * v0;
        float v1 = a.y + adn.y; v1 = v1 >= 0.f ? v1 : 0.2f * v1;
        float v2 = a.z + adn.z; v2 = v2 >= 0.f ? v2 : 0.2f * v2;
        float v3 = a.w + adn.w; v3 = v3 >= 0.f ? v3 : 0.2f * v3;
        float e0 = __expf(v0 - m0), e1 = __expf(v1 - m1);
        float e2 = __expf(v2 - m2), e3 = __expf(v3 - m3);
        s0 += e0; s1 += e1; s2 += e2; s3 += e3;
        if (fits) {
            int i = e - beg;
            srcS[w][i] = ok ? s : n;
            alphaS[w][0 * ECAPP + i] = e0;
            alphaS[w][1 * ECAPP + i] = e1;
            alphaS[w][2 * ECAPP + i] = e2;
            alphaS[w][3 * ECAPP + i] = e3;
        }
    }
    #pragma unroll
    for (int o = 1; o < 64; o <<= 1) {
        s0 += __shfl_xor(s0, o, 64); s1 += __shfl_xor(s1, o, 64);
        s2 += __shfl_xor(s2, o, 64); s3 += __shfl_xor(s3, o, 64);
    }
    float i0 = 1.f / (s0 + 1e-16f), i1 = 1.f / (s1 + 1e-16f);
    float i2 = 1.f / (s2 + 1e-16f), i3 = 1.f / (s3 + 1e-16f);

    // pass 3: weighted gather. lane owns cols (2l, 2l+1) of head hd = l>>4.
    int hd = lane >> 4;
    float invH = hd == 0 ? i0 : hd == 1 ? i1 : hd == 2 ? i2 : i3;
    float acc0 = 0.f, acc1 = 0.f;
    if (fits) {
        for (int i = 0; i < deg; i++) {
            int s = srcS[w][i];
            float wt = alphaS[w][hd * ECAPP + i] * invH;   // broadcast per 16-lane group
            __hip_bfloat162 hv = h2[(size_t)s * 64 + lane];
            acc0 += wt * bf2f(hv.x);
            acc1 += wt * bf2f(hv.y);
        }
    } else {
        float mH  = hd == 0 ? m0 : hd == 1 ? m1 : hd == 2 ? m2 : m3;
        float adH = hd == 0 ? adn.x : hd == 1 ? adn.y : hd == 2 ? adn.z : adn.w;
        for (int e = beg; e < end; e++) {
            int s = esrc[e];
            if ((unsigned)s >= (unsigned)N) continue;
            float4 a = as4[s];
            float aH = hd == 0 ? a.x : hd == 1 ? a.y : hd == 2 ? a.z : a.w;
            float v = aH + adH; v = v >= 0.f ? v : 0.2f * v;
            float wt = __expf(v - mH) * invH;
            __hip_bfloat162 hv = h2[(size_t)s * 64 + lane];
            acc0 += wt * bf2f(hv.x);
            acc1 += wt * bf2f(hv.y);
        }
    }
    // head mean: same col-pair lives in lanes {x, x+16, x+32, x+48}
    acc0 += __shfl_xor(acc0, 16, 64); acc0 += __shfl_xor(acc0, 32, 64);
    acc1 += __shfl_xor(acc1, 16, 64); acc1 += __shfl_xor(acc1, 32, 64);
    if (lane < 16) {
        float o0 = acc0 * 0.25f + bias[2 * lane];     o0 = o0 >= 0.f ? o0 : 0.01f * o0;
        float o1 = acc1 * 0.25f + bias[2 * lane + 1]; o1 = o1 >= 0.f ? o1 : 0.01f * o1;
        ((float2*)xout)[(size_t)n * 16 + lane] = make_float2(o0, o1);
    }
}

// ---------------- MLP + output scatter ----------------
// 128 threads/block, one node per thread; activations transposed in LDS so no
// per-thread array needs register promotion (round-4 fix for scratch spill).

__global__ __launch_bounds__(128) void k_mlp(
    const float* __restrict__ xF, const float* __restrict__ x3,
    const float* __restrict__ mW1, const float* __restrict__ mb1,
    const float* __restrict__ mW2, const float* __restrict__ mb2,
    const float* __restrict__ mW3, const float* __restrict__ mb3,
    const float* __restrict__ mW4, const float* __restrict__ mb4,
    const float* __restrict__ mW5, const float* __restrict__ mb5,
    const int* __restrict__ smask, const int* __restrict__ totals,
    const int* __restrict__ flag, int N, void* __restrict__ out) {
    __shared__ float W1[35 * 32], W2[1024], W3[1024], W4[1024], W5[32 * 12];
    __shared__ float B1[32], B2[32], B3[32], B4[32], B5[12];
    __shared__ float actA[35 * 128];
    __shared__ float actB[32 * 128];
    int t = threadIdx.x;
    for (int i = t; i < 1120; i += 128) W1[i] = mW1[i];
    for (int i = t; i < 1024; i += 128) { W2[i] = mW2[i]; W3[i] = mW3[i]; W4[i] = mW4[i]; }
    for (int i = t; i < 384; i += 128) W5[i] = mW5[i];
    if (t < 32) { B1[t] = mb1[t]; B2[t] = mb2[t]; B3[t] = mb3[t]; B4[t] = mb4[t]; }
    if (t < 12) B5[t] = mb5[t];
    __syncthreads();

    int n = blockIdx.x * 128 + t;
    bool alive = (n < N);
    float x0 = 0.f;
    if (alive) {
        x0 = xF[n * 3 + 0];
        actA[0 * 128 + t] = x0;
        actA[1 * 128 + t] = xF[n * 3 + 1];
        actA[2 * 128 + t] = xF[n * 3 + 2];
        for (int i = 0; i < 32; i++) actA[(3 + i) * 128 + t] = x3[(size_t)n * 32 + i];
    }

    float acc[32];

    #pragma unroll
    for (int o = 0; o < 32; o++) acc[o] = B1[o];
    #pragma unroll 2
    for (int i = 0; i < 35; i++) {
        float ai = actA[i * 128 + t];
        const float4* w4 = (const float4*)&W1[i * 32];
        #pragma unroll
        for (int q = 0; q < 8; q++) {
            float4 w = w4[q];
            acc[q*4+0] += ai * w.x; acc[q*4+1] += ai * w.y;
            acc[q*4+2] += ai * w.z; acc[q*4+3] += ai * w.w;
        }
    }
    #pragma unroll
    for (int o = 0; o < 32; o++) { float v = acc[o]; actB[o * 128 + t] = (v >= 0.f ? v : 0.01f * v); }

    #pragma unroll
    for (int o = 0; o < 32; o++) acc[o] = B2[o];
    #pragma unroll 2
    for (int i = 0; i < 32; i++) {
        float ai = actB[i * 128 + t];
        const float4* w4 = (const float4*)&W2[i * 32];
        #pragma unroll
        for (int q = 0; q < 8; q++) {
            float4 w = w4[q];
            acc[q*4+0] += ai * w.x; acc[q*4+1] += ai * w.y;
            acc[q*4+2] += ai * w.z; acc[q*4+3] += ai * w.w;
        }
    }
    #pragma unroll
    for (int o = 0; o < 32; o++) { float v = acc[o]; actA[o * 128 + t] = (v >= 0.f ? v : 0.01f * v); }

    #pragma unroll
    for (int o = 0; o < 32; o++) acc[o] = B3[o];
    #pragma unroll 2
    for (int i = 0; i < 32; i++) {
        float ai = actA[i * 128 + t];
        const float4* w4 = (const float4*)&W3[i * 32];
        #pragma unroll
        for (int q = 0; q < 8; q++) {
            float4 w = w4[q];
            acc[q*4+0] += ai * w.x; acc[q*4+1] += ai * w.y;
            acc[q*4+2] += ai * w.z; acc[q*4+3] += ai * w.w;
        }
    }
    #pragma unroll
    for (int o = 0; o < 32; o++) { float v = acc[o]; actB[o * 128 + t] = (v >= 0.f ? v : 0.01f * v); }

    #pragma unroll
    for (int o = 0; o < 32; o++) acc[o] = B4[o];
    #pragma unroll 2
    for (int i = 0; i < 32; i++) {
        float ai = actB[i * 128 + t];
        const float4* w4 = (const float4*)&W4[i * 32];
        #pragma unroll
        for (int q = 0; q < 8; q++) {
            float4 w = w4[q];
            acc[q*4+0] += ai * w.x; acc[q*4+1] += ai * w.y;
            acc[q*4+2] += ai * w.z; acc[q*4+3] += ai * w.w;
        }
    }
    #pragma unroll
    for (int o = 0; o < 32; o++) { float v = acc[o]; actA[o * 128 + t] = (v >= 0.f ? v : 0.01f * v); }

    float d[12];
    #pragma unroll
    for (int o = 0; o < 12; o++) d[o] = B5[o];
    #pragma unroll 2
    for (int i = 0; i < 32; i++) {
        float ai = actA[i * 128 + t];
        const float4* w4 = (const float4*)&W5[i * 12];
        #pragma unroll
        for (int q = 0; q < 3; q++) {
            float4 w = w4[q];
            d[q*4+0] += ai * w.x; d[q*4+1] += ai * w.y;
            d[q*4+2] += ai * w.z; d[q*4+3] += ai * w.w;
        }
    }
    if (!alive) return;
    #pragma unroll
    for (int o = 0; o < 12; o++) if (!(d[o] == d[o])) d[o] = 0.f;  // NaN scrub

    bool tower = (x0 == 0.0f);
    int r = smask[n];
    int Nt = *totals;
    int f32o = *flag;
    int base9, base3, rr;
    if (tower) { rr = r;     base9 = 0;      base3 = 9 * N; }
    else       { rr = n - r; base9 = 9 * Nt; base3 = 9 * N + 3 * Nt; }
    if (f32o) {
        float* o = (float*)out;
        #pragma unroll
        for (int j = 0; j < 9; j++) o[base9 + rr * 9 + j] = d[j];
        #pragma unroll
        for (int j = 0; j < 3; j++) o[base3 + rr * 3 + j] = d[9 + j];
    } else {
        __hip_bfloat16* o = (__hip_bfloat16*)out;
        #pragma unroll
        for (int j = 0; j < 9; j++) o[base9 + rr * 9 + j] = __float2bfloat16(d[j]);
        #pragma unroll
        for (int j = 0; j < 3; j++) o[base3 + rr * 3 + j] = __float2bfloat16(d[9 + j]);
    }
}

// ---------------- launch ----------------

extern "C" void kernel_launch(void* const* d_in, const int* in_sizes, int n_in,
                              void* d_out, int out_size, void* d_ws, size_t ws_size,
                              hipStream_t stream) {
    const void* xraw = d_in[0];
    const int*  eidx = (const int*)d_in[1];
    // d_in[2] edge_attr: unused

    int N  = in_sizes[0] / 3;
    int E  = in_sizes[1] / 2;
    int EE = E + N;

    Segs segs;
    int coff[22];
    int canonN = 3 * N;
    for (int i = 3; i <= 24; i++) {
        int a = i - 3;
        segs.s[a].src = d_in[i];
        segs.s[a].off = canonN;
        segs.s[a].len = in_sizes[i];
        coff[a] = canonN;
        canonN += in_sizes[i];
    }

    auto alignv = [](size_t v, size_t a) { return (v + a - 1) & ~(a - 1); };
    char* base = (char*)d_ws;
    size_t o = 0;
    float* canon = (float*)(base + o); o = alignv(o + (size_t)canonN * 4, 16);
    int* flag     = (int*)(base + o); o = alignv(o + 16, 16);
    int* partials = (int*)(base + o); o = alignv(o + 4096, 16);
    int* totals   = (int*)(base + o); o = alignv(o + 16, 16);
    int* off      = (int*)(base + o); o = alignv(o + (size_t)(N + 1) * 4, 16);
    int* cur      = (int*)(base + o); o = alignv(o + (size_t)N * 4, 16);
    int* esrc     = (int*)(base + o); o = alignv(o + (size_t)EE * 4, 16);
    int* smsk     = (int*)(base + o); o = alignv(o + (size_t)N * 4, 256);
    __hip_bfloat162* h2 = (__hip_bfloat162*)(base + o); o = alignv(o + (size_t)N * 64 * 4, 16);
    float* xb  = (float*)(base + o); o = alignv(o + (size_t)N * 32 * 4, 16);
    float* as_ = (float*)(base + o); o = alignv(o + (size_t)N * 16, 16);
    float* ad_ = (float*)(base + o);

    int nb = (N + 1023) / 1024;
    int gN = (N + 255) / 256;
    int g4 = (N + 3) / 4;
    int gM = (N + 127) / 128;

    // dtype detect + ingest
    int nprobe = in_sizes[0] < 4096 ? in_sizes[0] : 4096;
    k_detect<<<1, 256, 0, stream>>>((const unsigned short*)xraw, nprobe, flag);
    k_ingest<<<64 + 22, 256, 0, stream>>>(xraw, 3 * N, segs, canon, flag);
    float* xF = canon;

    // CSR build (cur doubles as deg)
    k_init<<<gN, 256, 0, stream>>>(xF, N, cur, smsk);
    k_count<<<(E + 255) / 256, 256, 0, stream>>>(eidx, E, N, cur);
    k_scan_partial<<<nb, 256, 0, stream>>>(cur, N, partials);
    k_scan_serial<<<1, 1, 0, stream>>>(partials, nb, nullptr);
    k_scan_final<<<nb, 256, 0, stream>>>(cur, N, partials, off);
    k_cursor<<<gN, 256, 0, stream>>>(off, N, EE, cur, off + N);
    k_fill<<<(EE + 255) / 256, 256, 0, stream>>>(eidx, E, N, EE, cur, esrc);

    // tower-mask exclusive scan (in place)
    k_scan_partial<<<nb, 256, 0, stream>>>(smsk, N, partials);
    k_scan_serial<<<1, 1, 0, stream>>>(partials, nb, totals);
    k_scan_final<<<nb, 256, 0, stream>>>(smsk, N, partials, smsk);

    const float* W1  = canon + coff[0];  const float* aS1 = canon + coff[1];
    const float* aD1 = canon + coff[2];  const float* b1  = canon + coff[3];
    const float* W2  = canon + coff[4];  const float* aS2 = canon + coff[5];
    const float* aD2 = canon + coff[6];  const float* b2  = canon + coff[7];
    const float* W3  = canon + coff[8];  const float* aS3 = canon + coff[9];
    const float* aD3 = canon + coff[10]; const float* b3  = canon + coff[11];

    k_node_first<<<g4, 256, 0, stream>>>(xF, W1, aS1, aD1, N, h2, as_, ad_);
    k_edge<<<g4, 256, 0, stream>>>(h2, as_, ad_, off, esrc, b1, N, xb);
    k_node_mid<<<g4, 256, 0, stream>>>(xb, W2, aS2, aD2, N, h2, as_, ad_);
    k_edge<<<g4, 256, 0, stream>>>(h2, as_, ad_, off, esrc, b2, N, xb);
    k_node_mid<<<g4, 256, 0, stream>>>(xb, W3, aS3, aD3, N, h2, as_, ad_);
    k_edge<<<g4, 256, 0, stream>>>(h2, as_, ad_, off, esrc, b3, N, xb);

    k_mlp<<<gM, 128, 0, stream>>>(xF, xb,
        canon + coff[12], canon + coff[13], canon + coff[14], canon + coff[15],
        canon + coff[16], canon + coff[17], canon + coff[18], canon + coff[19],
        canon + coff[20], canon + coff[21], smsk, totals, flag, N, d_out);
}

// Round 6
// 665.128 us; speedup vs baseline: 3.5884x; 1.0946x over previous
//
#include <hip/hip_runtime.h>
#include <hip/hip_bf16.h>

#define DEV __device__ __forceinline__

DEV float bf2f(__hip_bfloat16 v) { return __bfloat162float(v); }

typedef unsigned long long ull;

// ---------------- detect dtype + zero degree array ----------------
// true bf16 N(0,1): no u16 with biased exp >= 0x8F. f32-as-u16: low halves
// are uniform bits -> ~40% "bad". Block 0 probes; all blocks zero cnt.
__global__ void k_detect_zero(const unsigned short* xr, int nprobe, int* flag,
                              int* cnt, int N) {
    int i = blockIdx.x * 256 + threadIdx.x;
    if (i < N) cnt[i] = 0;
    if (blockIdx.x == 0) {
        __shared__ int red[256];
        int t = threadIdx.x, bad = 0;
        for (int j = t; j < nprobe; j += 256) {
            unsigned e = (xr[j] >> 7) & 0xFF;
            if (e >= 0x8F) bad++;
        }
        red[t] = bad; __syncthreads();
        for (int o = 128; o > 0; o >>= 1) { if (t < o) red[t] += red[t + o]; __syncthreads(); }
        if (t == 0) flag[0] = (red[0] > 256) ? 1 : 0;   // 1 = inputs are f32
    }
}

// ---------------- fused ingest + tower mask + degree count ------------------
struct Seg  { const void* src; int off; int len; };
struct Segs { Seg s[22]; };

__global__ void k_fused(const void* xsrc, int nx3, Segs segs, float* canon,
                        const int* flag, const int* eidx, int E, int N,
                        int* cnt, int* msk) {
    int f32 = flag[0];
    int t = threadIdx.x, b = blockIdx.x;
    if (b < 64) {
        for (int i = b * 256 + t; i < nx3; i += 64 * 256) {
            float v = f32 ? ((const float*)xsrc)[i] : bf2f(((const __hip_bfloat16*)xsrc)[i]);
            if (!(v == v) || fabsf(v) > 1e30f) v = 0.f;   // scrub
            canon[i] = v;
            if (i % 3 == 0) msk[i / 3] = (v == 0.0f) ? 1 : 0;
        }
    } else if (b < 86) {
        Seg sg = segs.s[b - 64];
        for (int i = t; i < sg.len; i += 256) {
            float v = f32 ? ((const float*)sg.src)[i] : bf2f(((const __hip_bfloat16*)sg.src)[i]);
            if (!(v == v) || fabsf(v) > 1e30f) v = 0.f;
            canon[sg.off + i] = v;
        }
    } else {
        int e = (b - 86) * 256 + t;
        if (e < E) {
            int d = eidx[E + e];
            if ((unsigned)d < (unsigned)N) atomicAdd(&cnt[d], 1);
        }
    }
}

// ---------------- packed 64-bit exclusive scan ------------------------------
// value(i) = (msk[i] << 32) | (cnt[i] + 1)  -- deg incl. self-loop in low word,
// tower mask in high word. One scan serves CSR offsets AND output partition.

DEV ull packval(const int* cnt, const int* msk, int i) {
    return ((ull)(unsigned)msk[i] << 32) | (unsigned)(cnt[i] + 1);
}

__global__ void k_scan_partial64(const int* __restrict__ cnt, const int* __restrict__ msk,
                                 int n, ull* __restrict__ partials) {
    __shared__ ull red[256];
    int t = threadIdx.x, b = blockIdx.x;
    int base = b * 1024 + t * 4;
    ull s = 0;
    #pragma unroll
    for (int j = 0; j < 4; j++) { int i = base + j; if (i < n) s += packval(cnt, msk, i); }
    red[t] = s; __syncthreads();
    for (int o = 128; o > 0; o >>= 1) { if (t < o) red[t] += red[t + o]; __syncthreads(); }
    if (t == 0) partials[b] = red[0];
}

// single block, 256 threads: exclusive scan of partials[nb] (any nb), plus
// writes off[N] (total degree incl self-loops) and totals (tower count).
__global__ void k_scan_mid64(ull* partials, int nb, int* offN, int* totals) {
    __shared__ ull sh[256];
    int t = threadIdx.x;
    ull carry = 0;
    for (int base = 0; base < nb; base += 256) {
        int i = base + t;
        ull v = (i < nb) ? partials[i] : 0;
        sh[t] = v; __syncthreads();
        for (int o = 1; o < 256; o <<= 1) {
            ull x = (t >= o) ? sh[t - o] : 0;
            __syncthreads();
            sh[t] += x;
            __syncthreads();
        }
        if (i < nb) partials[i] = carry + sh[t] - v;   // exclusive
        ull tot = sh[255];
        __syncthreads();
        carry += tot;
    }
    if (t == 0) { *offN = (int)(carry & 0xffffffffu); *totals = (int)(carry >> 32); }
}

// writes: off[i] = low(run) (CSR offset), cur[i] = off[i] (fill cursor,
// in-place over cnt), msk[i] = high(run) (tower rank, in place).
__global__ void k_scan_final64(int* __restrict__ cnt, int* __restrict__ msk, int n,
                               const ull* __restrict__ partials,
                               int* __restrict__ off, int* __restrict__ cur) {
    __shared__ ull sums[256];
    int t = threadIdx.x, b = blockIdx.x;
    int base = b * 1024 + t * 4;
    ull v0 = 0, v1 = 0, v2 = 0, v3 = 0;
    if (base     < n) v0 = packval(cnt, msk, base);
    if (base + 1 < n) v1 = packval(cnt, msk, base + 1);
    if (base + 2 < n) v2 = packval(cnt, msk, base + 2);
    if (base + 3 < n) v3 = packval(cnt, msk, base + 3);
    ull s = v0 + v1 + v2 + v3;
    sums[t] = s; __syncthreads();
    for (int o = 1; o < 256; o <<= 1) {
        ull x = (t >= o) ? sums[t - o] : 0;
        __syncthreads();
        sums[t] += x;
        __syncthreads();
    }
    ull run = partials[b] + (sums[t] - s);
    #pragma unroll
    for (int j = 0; j < 4; j++) {
        int i = base + j;
        if (i < n) {
            int lo = (int)(run & 0xffffffffu), hi = (int)(run >> 32);
            off[i] = lo; cur[i] = lo; msk[i] = hi;
            run += (j == 0 ? v0 : j == 1 ? v1 : j == 2 ? v2 : v3);
        }
    }
}

// ---------------- CSR fill ----------------

__global__ void k_fill(const int* __restrict__ eidx, int E, int N, int EE,
                       int* __restrict__ cursor, int* __restrict__ esrc) {
    int e = blockIdx.x * 256 + threadIdx.x;
    if (e < E) {
        int s = eidx[e], d = eidx[E + e];
        if ((unsigned)d < (unsigned)N && (unsigned)s < (unsigned)N) {
            int p = atomicAdd(&cursor[d], 1);
            if ((unsigned)p < (unsigned)EE) esrc[p] = s;
        }
    } else if (e < E + N) {
        int i = e - E;
        int p = atomicAdd(&cursor[i], 1);
        if ((unsigned)p < (unsigned)EE) esrc[p] = i;
    }
}

// ---------------- GAT node kernels ------------------------------------------
// One wave per node. Lane l owns COLUMN PAIR (2l, 2l+1) of h (head = l>>4).
// h stored packed bf16x2 -> one h-row gather = 256 B/wave.

__global__ __launch_bounds__(256) void k_node_first(
    const float* __restrict__ xF, const float* __restrict__ W,
    const float* __restrict__ atS, const float* __restrict__ atD,
    int N, __hip_bfloat162* __restrict__ h2, float* __restrict__ as_, float* __restrict__ ad_) {
    __shared__ float Wl[3 * 128];
    __shared__ float aS[128], aD[128];
    int t = threadIdx.x;
    for (int i = t; i < 384; i += 256) Wl[i] = W[i];
    if (t < 128) { aS[t] = atS[t]; aD[t] = atD[t]; }
    __syncthreads();
    int lane = t & 63;
    int n = blockIdx.x * 4 + (t >> 6);
    if (n >= N) return;
    float xv = (lane < 3) ? xF[n * 3 + lane] : 0.f;
    float acc0 = 0.f, acc1 = 0.f;
    const float2* W2 = (const float2*)Wl;
    #pragma unroll
    for (int k = 0; k < 3; k++) {
        float xk = __shfl(xv, k, 64);
        float2 wv = W2[k * 64 + lane];
        acc0 += xk * wv.x; acc1 += xk * wv.y;
    }
    __hip_bfloat162 hv; hv.x = __float2bfloat16(acc0); hv.y = __float2bfloat16(acc1);
    h2[(size_t)n * 64 + lane] = hv;
    int c0 = 2 * lane;
    float p = acc0 * aS[c0] + acc1 * aS[c0 + 1];
    float q = acc0 * aD[c0] + acc1 * aD[c0 + 1];
    #pragma unroll
    for (int o = 1; o < 16; o <<= 1) { p += __shfl_xor(p, o, 64); q += __shfl_xor(q, o, 64); }
    if ((lane & 15) == 0) { int hd = lane >> 4; as_[n * 4 + hd] = p; ad_[n * 4 + hd] = q; }
}

__global__ __launch_bounds__(256) void k_node_mid(
    const float* __restrict__ xin, const float* __restrict__ W,
    const float* __restrict__ atS, const float* __restrict__ atD,
    int N, __hip_bfloat162* __restrict__ h2, float* __restrict__ as_, float* __restrict__ ad_) {
    __shared__ float Wl[32 * 128];
    __shared__ float aS[128], aD[128];
    int t = threadIdx.x;
    for (int i = t; i < 4096; i += 256) Wl[i] = W[i];
    if (t < 128) { aS[t] = atS[t]; aD[t] = atD[t]; }
    __syncthreads();
    int lane = t & 63;
    int n = blockIdx.x * 4 + (t >> 6);
    if (n >= N) return;
    float xv = (lane < 32) ? xin[(size_t)n * 32 + lane] : 0.f;
    float acc0 = 0.f, acc1 = 0.f;
    const float2* W2 = (const float2*)Wl;
    #pragma unroll
    for (int k = 0; k < 32; k++) {
        float xk = __shfl(xv, k, 64);
        float2 wv = W2[k * 64 + lane];
        acc0 += xk * wv.x; acc1 += xk * wv.y;
    }
    __hip_bfloat162 hv; hv.x = __float2bfloat16(acc0); hv.y = __float2bfloat16(acc1);
    h2[(size_t)n * 64 + lane] = hv;
    int c0 = 2 * lane;
    float p = acc0 * aS[c0] + acc1 * aS[c0 + 1];
    float q = acc0 * aD[c0] + acc1 * aD[c0 + 1];
    #pragma unroll
    for (int o = 1; o < 16; o <<= 1) { p += __shfl_xor(p, o, 64); q += __shfl_xor(q, o, 64); }
    if ((lane & 15) == 0) { int hd = lane >> 4; as_[n * 4 + hd] = p; ad_[n * 4 + hd] = q; }
}

// ---------------- GAT edge kernel -------------------------------------------
// One wave per dst node, lane l gathers col pair (2l,2l+1), head hd = l>>4.
// deg<=16 fast path (~99% of nodes at Poisson(8)+1): lane = 4*edge+head holds
// ONE score; 4-step xor butterflies (strides 4..32) reduce all heads at once;
// pass-3 weights come from registers via shuffles -> no LDS at all.
// 16<deg<=64: per-lane-per-edge scores, alpha stash in small LDS.
// deg>64: full recompute (safety net, ~never taken).

constexpr int FCAP  = 64;
constexpr int FCAPP = 68;   // head stride: offsets 0,68,136,204 mod 32 distinct

__global__ __launch_bounds__(256) void k_edge(
    const __hip_bfloat162* __restrict__ h2, const float* __restrict__ as_,
    const float* __restrict__ ad_, const int* __restrict__ off,
    const int* __restrict__ esrc, const float* __restrict__ bias,
    int N, float* __restrict__ xout) {
    __shared__ float alphaS[4][4 * FCAPP];
    __shared__ int   srcS[4][FCAP];
    int t = threadIdx.x, lane = t & 63, w = t >> 6;
    int n = blockIdx.x * 4 + w;
    if (n >= N) return;
    int beg = off[n], end = off[n + 1];
    int deg = end - beg;
    float4 adn = ((const float4*)ad_)[n];
    const float4* as4 = (const float4*)as_;
    int hd = lane >> 4;

    float acc0 = 0.f, acc1 = 0.f;

    if (deg <= 16) {
        // ---- fast path: lane = 4*edge + head ----
        int e = lane >> 2, h = lane & 3;
        int s_e = n;
        float v = -1e30f;
        if (e < deg) {
            int s = esrc[beg + e];
            if ((unsigned)s < (unsigned)N) {
                s_e = s;
                float asv = as_[s * 4 + h];
                float adv = h == 0 ? adn.x : h == 1 ? adn.y : h == 2 ? adn.z : adn.w;
                v = asv + adv; v = v >= 0.f ? v : 0.2f * v;
            }
        }
        float m = v;
        #pragma unroll
        for (int o = 4; o < 64; o <<= 1) m = fmaxf(m, __shfl_xor(m, o, 64));
        float ex = (v > -1e29f) ? __expf(v - m) : 0.f;
        float ssum = ex;
        #pragma unroll
        for (int o = 4; o < 64; o <<= 1) ssum += __shfl_xor(ssum, o, 64);
        float inv = 1.f / (ssum + 1e-16f);
        float invH = __shfl(inv, hd, 64);     // lane hd holds head hd's inv
        for (int i = 0; i < deg; i++) {
            float wt = __shfl(ex, 4 * i + hd, 64) * invH;
            int s = __shfl(s_e, 4 * i, 64);
            __hip_bfloat162 hv = h2[(size_t)s * 64 + lane];
            acc0 += wt * bf2f(hv.x);
            acc1 += wt * bf2f(hv.y);
        }
    } else {
        // ---- slow path: lane per edge, all 4 heads per lane ----
        bool fits = (deg <= FCAP);
        float m0 = -1e30f, m1 = -1e30f, m2 = -1e30f, m3 = -1e30f;
        for (int e = beg + lane; e < end; e += 64) {
            int s = esrc[e];
            if ((unsigned)s >= (unsigned)N) continue;
            float4 a = as4[s];
            float v0 = a.x + adn.x; v0 = v0 >= 0.f ? v0 : 0.2f * v0;
            float v1 = a.y + adn.y; v1 = v1 >= 0.f ? v1 : 0.2f * v1;
            float v2 = a.z + adn.z; v2 = v2 >= 0.f ? v2 : 0.2f * v2;
            float v3 = a.w + adn.w; v3 = v3 >= 0.f ? v3 : 0.2f * v3;
            m0 = fmaxf(m0, v0); m1 = fmaxf(m1, v1); m2 = fmaxf(m2, v2); m3 = fmaxf(m3, v3);
        }
        #pragma unroll
        for (int o = 1; o < 64; o <<= 1) {
            m0 = fmaxf(m0, __shfl_xor(m0, o, 64));
            m1 = fmaxf(m1, __shfl_xor(m1, o, 64));
            m2 = fmaxf(m2, __shfl_xor(m2, o, 64));
            m3 = fmaxf(m3, __shfl_xor(m3, o, 64));
        }
        float s0 = 0.f, s1 = 0.f, s2 = 0.f, s3 = 0.f;
        for (int e = beg + lane; e < end; e += 64) {
            int s = esrc[e];
            bool ok = (unsigned)s < (unsigned)N;
            float4 a = ok ? as4[s] : make_float4(-1e30f, -1e30f, -1e30f, -1e30f);
            float v0 = a.x + adn.x; v0 = v0 >= 0.f ? v0 : 0.2f * v0;
            float v1 = a.y + adn.y; v1 = v1 >= 0.f ? v1 : 0.2f * v1;
            float v2 = a.z + adn.z; v2 = v2 >= 0.f ? v2 : 0.2f * v2;
            float v3 = a.w + adn.w; v3 = v3 >= 0.f ? v3 : 0.2f * v3;
            float e0 = __expf(v0 - m0), e1 = __expf(v1 - m1);
            float e2 = __expf(v2 - m2), e3 = __expf(v3 - m3);
            s0 += e0; s1 += e1; s2 += e2; s3 += e3;
            if (fits) {
                int i = e - beg;
                srcS[w][i] = ok ? s : n;
                alphaS[w][0 * FCAPP + i] = e0;
                alphaS[w][1 * FCAPP + i] = e1;
                alphaS[w][2 * FCAPP + i] = e2;
                alphaS[w][3 * FCAPP + i] = e3;
            }
        }
        #pragma unroll
        for (int o = 1; o < 64; o <<= 1) {
            s0 += __shfl_xor(s0, o, 64); s1 += __shfl_xor(s1, o, 64);
            s2 += __shfl_xor(s2, o, 64); s3 += __shfl_xor(s3, o, 64);
        }
        float i0 = 1.f / (s0 + 1e-16f), i1 = 1.f / (s1 + 1e-16f);
        float i2 = 1.f / (s2 + 1e-16f), i3 = 1.f / (s3 + 1e-16f);
        float invH = hd == 0 ? i0 : hd == 1 ? i1 : hd == 2 ? i2 : i3;
        if (fits) {
            for (int i = 0; i < deg; i++) {
                int s = srcS[w][i];
                float wt = alphaS[w][hd * FCAPP + i] * invH;
                __hip_bfloat162 hv = h2[(size_t)s * 64 + lane];
                acc0 += wt * bf2f(hv.x);
                acc1 += wt * bf2f(hv.y);
            }
        } else {
            float mH  = hd == 0 ? m0 : hd == 1 ? m1 : hd == 2 ? m2 : m3;
            float adH = hd == 0 ? adn.x : hd == 1 ? adn.y : hd == 2 ? adn.z : adn.w;
            for (int e = beg; e < end; e++) {
                int s = esrc[e];
                if ((unsigned)s >= (unsigned)N) continue;
                float4 a = as4[s];
                float aH = hd == 0 ? a.x : hd == 1 ? a.y : hd == 2 ? a.z : a.w;
                float v = aH + adH; v = v >= 0.f ? v : 0.2f * v;
                float wt = __expf(v - mH) * invH;
                __hip_bfloat162 hv = h2[(size_t)s * 64 + lane];
                acc0 += wt * bf2f(hv.x);
                acc1 += wt * bf2f(hv.y);
            }
        }
    }
    // head mean: col pair lives in lanes {x, x+16, x+32, x+48}
    acc0 += __shfl_xor(acc0, 16, 64); acc0 += __shfl_xor(acc0, 32, 64);
    acc1 += __shfl_xor(acc1, 16, 64); acc1 += __shfl_xor(acc1, 32, 64);
    if (lane < 16) {
        float o0 = acc0 * 0.25f + bias[2 * lane];     o0 = o0 >= 0.f ? o0 : 0.01f * o0;
        float o1 = acc1 * 0.25f + bias[2 * lane + 1]; o1 = o1 >= 0.f ? o1 : 0.01f * o1;
        ((float2*)xout)[(size_t)n * 16 + lane] = make_float2(o0, o1);
    }
}

// ---------------- MLP + output scatter ----------------
// 128 threads/block, one node per thread; activations transposed in LDS so no
// per-thread array needs register promotion (round-4 fix for scratch spill).

__global__ __launch_bounds__(128) void k_mlp(
    const float* __restrict__ xF, const float* __restrict__ x3,
    const float* __restrict__ mW1, const float* __restrict__ mb1,
    const float* __restrict__ mW2, const float* __restrict__ mb2,
    const float* __restrict__ mW3, const float* __restrict__ mb3,
    const float* __restrict__ mW4, const float* __restrict__ mb4,
    const float* __restrict__ mW5, const float* __restrict__ mb5,
    const int* __restrict__ smask, const int* __restrict__ totals,
    const int* __restrict__ flag, int N, void* __restrict__ out) {
    __shared__ float W1[35 * 32], W2[1024], W3[1024], W4[1024], W5[32 * 12];
    __shared__ float B1[32], B2[32], B3[32], B4[32], B5[12];
    __shared__ float actA[35 * 128];
    __shared__ float actB[32 * 128];
    int t = threadIdx.x;
    for (int i = t; i < 1120; i += 128) W1[i] = mW1[i];
    for (int i = t; i < 1024; i += 128) { W2[i] = mW2[i]; W3[i] = mW3[i]; W4[i] = mW4[i]; }
    for (int i = t; i < 384; i += 128) W5[i] = mW5[i];
    if (t < 32) { B1[t] = mb1[t]; B2[t] = mb2[t]; B3[t] = mb3[t]; B4[t] = mb4[t]; }
    if (t < 12) B5[t] = mb5[t];
    __syncthreads();

    int n = blockIdx.x * 128 + t;
    bool alive = (n < N);
    float x0 = 0.f;
    if (alive) {
        x0 = xF[n * 3 + 0];
        actA[0 * 128 + t] = x0;
        actA[1 * 128 + t] = xF[n * 3 + 1];
        actA[2 * 128 + t] = xF[n * 3 + 2];
        for (int i = 0; i < 32; i++) actA[(3 + i) * 128 + t] = x3[(size_t)n * 32 + i];
    }

    float acc[32];

    #pragma unroll
    for (int o = 0; o < 32; o++) acc[o] = B1[o];
    #pragma unroll 2
    for (int i = 0; i < 35; i++) {
        float ai = actA[i * 128 + t];
        const float4* w4 = (const float4*)&W1[i * 32];
        #pragma unroll
        for (int q = 0; q < 8; q++) {
            float4 w = w4[q];
            acc[q*4+0] += ai * w.x; acc[q*4+1] += ai * w.y;
            acc[q*4+2] += ai * w.z; acc[q*4+3] += ai * w.w;
        }
    }
    #pragma unroll
    for (int o = 0; o < 32; o++) { float v = acc[o]; actB[o * 128 + t] = (v >= 0.f ? v : 0.01f * v); }

    #pragma unroll
    for (int o = 0; o < 32; o++) acc[o] = B2[o];
    #pragma unroll 2
    for (int i = 0; i < 32; i++) {
        float ai = actB[i * 128 + t];
        const float4* w4 = (const float4*)&W2[i * 32];
        #pragma unroll
        for (int q = 0; q < 8; q++) {
            float4 w = w4[q];
            acc[q*4+0] += ai * w.x; acc[q*4+1] += ai * w.y;
            acc[q*4+2] += ai * w.z; acc[q*4+3] += ai * w.w;
        }
    }
    #pragma unroll
    for (int o = 0; o < 32; o++) { float v = acc[o]; actA[o * 128 + t] = (v >= 0.f ? v : 0.01f * v); }

    #pragma unroll
    for (int o = 0; o < 32; o++) acc[o] = B3[o];
    #pragma unroll 2
    for (int i = 0; i < 32; i++) {
        float ai = actA[i * 128 + t];
        const float4* w4 = (const float4*)&W3[i * 32];
        #pragma unroll
        for (int q = 0; q < 8; q++) {
            float4 w = w4[q];
            acc[q*4+0] += ai * w.x; acc[q*4+1] += ai * w.y;
            acc[q*4+2] += ai * w.z; acc[q*4+3] += ai * w.w;
        }
    }
    #pragma unroll
    for (int o = 0; o < 32; o++) { float v = acc[o]; actB[o * 128 + t] = (v >= 0.f ? v : 0.01f * v); }

    #pragma unroll
    for (int o = 0; o < 32; o++) acc[o] = B4[o];
    #pragma unroll 2
    for (int i = 0; i < 32; i++) {
        float ai = actB[i * 128 + t];
        const float4* w4 = (const float4*)&W4[i * 32];
        #pragma unroll
        for (int q = 0; q < 8; q++) {
            float4 w = w4[q];
            acc[q*4+0] += ai * w.x; acc[q*4+1] += ai * w.y;
            acc[q*4+2] += ai * w.z; acc[q*4+3] += ai * w.w;
        }
    }
    #pragma unroll
    for (int o = 0; o < 32; o++) { float v = acc[o]; actA[o * 128 + t] = (v >= 0.f ? v : 0.01f * v); }

    float d[12];
    #pragma unroll
    for (int o = 0; o < 12; o++) d[o] = B5[o];
    #pragma unroll 2
    for (int i = 0; i < 32; i++) {
        float ai = actA[i * 128 + t];
        const float4* w4 = (const float4*)&W5[i * 12];
        #pragma unroll
        for (int q = 0; q < 3; q++) {
            float4 w = w4[q];
            d[q*4+0] += ai * w.x; d[q*4+1] += ai * w.y;
            d[q*4+2] += ai * w.z; d[q*4+3] += ai * w.w;
        }
    }
    if (!alive) return;
    #pragma unroll
    for (int o = 0; o < 12; o++) if (!(d[o] == d[o])) d[o] = 0.f;  // NaN scrub

    bool tower = (x0 == 0.0f);
    int r = smask[n];
    int Nt = *totals;
    int f32o = *flag;
    int base9, base3, rr;
    if (tower) { rr = r;     base9 = 0;      base3 = 9 * N; }
    else       { rr = n - r; base9 = 9 * Nt; base3 = 9 * N + 3 * Nt; }
    if (f32o) {
        float* o = (float*)out;
        #pragma unroll
        for (int j = 0; j < 9; j++) o[base9 + rr * 9 + j] = d[j];
        #pragma unroll
        for (int j = 0; j < 3; j++) o[base3 + rr * 3 + j] = d[9 + j];
    } else {
        __hip_bfloat16* o = (__hip_bfloat16*)out;
        #pragma unroll
        for (int j = 0; j < 9; j++) o[base9 + rr * 9 + j] = __float2bfloat16(d[j]);
        #pragma unroll
        for (int j = 0; j < 3; j++) o[base3 + rr * 3 + j] = __float2bfloat16(d[9 + j]);
    }
}

// ---------------- launch ----------------

extern "C" void kernel_launch(void* const* d_in, const int* in_sizes, int n_in,
                              void* d_out, int out_size, void* d_ws, size_t ws_size,
                              hipStream_t stream) {
    const void* xraw = d_in[0];
    const int*  eidx = (const int*)d_in[1];
    // d_in[2] edge_attr: unused

    int N  = in_sizes[0] / 3;
    int E  = in_sizes[1] / 2;
    int EE = E + N;

    Segs segs;
    int coff[22];
    int canonN = 3 * N;
    for (int i = 3; i <= 24; i++) {
        int a = i - 3;
        segs.s[a].src = d_in[i];
        segs.s[a].off = canonN;
        segs.s[a].len = in_sizes[i];
        coff[a] = canonN;
        canonN += in_sizes[i];
    }

    auto alignv = [](size_t v, size_t a) { return (v + a - 1) & ~(a - 1); };
    char* base = (char*)d_ws;
    size_t o = 0;
    float* canon = (float*)(base + o); o = alignv(o + (size_t)canonN * 4, 16);
    int* flag     = (int*)(base + o); o = alignv(o + 16, 16);
    ull* partials = (ull*)(base + o); o = alignv(o + 1024 * 8, 16);
    int* totals   = (int*)(base + o); o = alignv(o + 16, 16);
    int* off      = (int*)(base + o); o = alignv(o + (size_t)(N + 1) * 4, 16);
    int* cur      = (int*)(base + o); o = alignv(o + (size_t)N * 4, 16);   // cnt/deg -> cursor
    int* esrc     = (int*)(base + o); o = alignv(o + (size_t)EE * 4, 16);
    int* msk      = (int*)(base + o); o = alignv(o + (size_t)N * 4, 256);  // mask -> rank
    __hip_bfloat162* h2 = (__hip_bfloat162*)(base + o); o = alignv(o + (size_t)N * 64 * 4, 16);
    float* xb  = (float*)(base + o); o = alignv(o + (size_t)N * 32 * 4, 16);
    float* as_ = (float*)(base + o); o = alignv(o + (size_t)N * 16, 16);
    float* ad_ = (float*)(base + o);

    int nb = (N + 1023) / 1024;
    int gN = (N + 255) / 256;
    int g4 = (N + 3) / 4;
    int gM = (N + 127) / 128;

    int nprobe = in_sizes[0] < 4096 ? in_sizes[0] : 4096;
    k_detect_zero<<<gN, 256, 0, stream>>>((const unsigned short*)xraw, nprobe, flag, cur, N);
    k_fused<<<86 + (E + 255) / 256, 256, 0, stream>>>(xraw, 3 * N, segs, canon, flag,
                                                      eidx, E, N, cur, msk);
    k_scan_partial64<<<nb, 256, 0, stream>>>(cur, msk, N, partials);
    k_scan_mid64<<<1, 256, 0, stream>>>(partials, nb, off + N, totals);
    k_scan_final64<<<nb, 256, 0, stream>>>(cur, msk, N, partials, off, cur);
    k_fill<<<(EE + 255) / 256, 256, 0, stream>>>(eidx, E, N, EE, cur, esrc);

    float* xF = canon;
    const float* W1  = canon + coff[0];  const float* aS1 = canon + coff[1];
    const float* aD1 = canon + coff[2];  const float* b1  = canon + coff[3];
    const float* W2  = canon + coff[4];  const float* aS2 = canon + coff[5];
    const float* aD2 = canon + coff[6];  const float* b2  = canon + coff[7];
    const float* W3  = canon + coff[8];  const float* aS3 = canon + coff[9];
    const float* aD3 = canon + coff[10]; const float* b3  = canon + coff[11];

    k_node_first<<<g4, 256, 0, stream>>>(xF, W1, aS1, aD1, N, h2, as_, ad_);
    k_edge<<<g4, 256, 0, stream>>>(h2, as_, ad_, off, esrc, b1, N, xb);
    k_node_mid<<<g4, 256, 0, stream>>>(xb, W2, aS2, aD2, N, h2, as_, ad_);
    k_edge<<<g4, 256, 0, stream>>>(h2, as_, ad_, off, esrc, b2, N, xb);
    k_node_mid<<<g4, 256, 0, stream>>>(xb, W3, aS3, aD3, N, h2, as_, ad_);
    k_edge<<<g4, 256, 0, stream>>>(h2, as_, ad_, off, esrc, b3, N, xb);

    k_mlp<<<gM, 128, 0, stream>>>(xF, xb,
        canon + coff[12], canon + coff[13], canon + coff[14], canon + coff[15],
        canon + coff[16], canon + coff[17], canon + coff[18], canon + coff[19],
        canon + coff[20], canon + coff[21], msk, totals, flag, N, d_out);
}

// Round 7
// 564.481 us; speedup vs baseline: 4.2282x; 1.1783x over previous
//
#include <hip/hip_runtime.h>
#include <hip/hip_bf16.h>

#define DEV __device__ __forceinline__

DEV float bf2f(__hip_bfloat16 v) { return __bfloat162float(v); }

typedef unsigned long long ull;

// ---------------- detect dtype + zero degree array ----------------
__global__ void k_detect_zero(const unsigned short* xr, int nprobe, int* flag,
                              int* cnt, int N) {
    int i = blockIdx.x * 256 + threadIdx.x;
    if (i < N) cnt[i] = 0;
    if (blockIdx.x == 0) {
        __shared__ int red[256];
        int t = threadIdx.x, bad = 0;
        for (int j = t; j < nprobe; j += 256) {
            unsigned e = (xr[j] >> 7) & 0xFF;
            if (e >= 0x8F) bad++;
        }
        red[t] = bad; __syncthreads();
        for (int o = 128; o > 0; o >>= 1) { if (t < o) red[t] += red[t + o]; __syncthreads(); }
        if (t == 0) flag[0] = (red[0] > 256) ? 1 : 0;   // 1 = inputs are f32
    }
}

// ---------------- fused ingest + tower mask + degree count ------------------
struct Seg  { const void* src; int off; int len; };
struct Segs { Seg s[22]; };

__global__ void k_fused(const void* xsrc, int nx3, Segs segs, float* canon,
                        const int* flag, const int* eidx, int E, int N,
                        int* cnt, int* msk) {
    int f32 = flag[0];
    int t = threadIdx.x, b = blockIdx.x;
    if (b < 64) {
        for (int i = b * 256 + t; i < nx3; i += 64 * 256) {
            float v = f32 ? ((const float*)xsrc)[i] : bf2f(((const __hip_bfloat16*)xsrc)[i]);
            if (!(v == v) || fabsf(v) > 1e30f) v = 0.f;   // scrub
            canon[i] = v;
            if (i % 3 == 0) msk[i / 3] = (v == 0.0f) ? 1 : 0;
        }
    } else if (b < 86) {
        Seg sg = segs.s[b - 64];
        for (int i = t; i < sg.len; i += 256) {
            float v = f32 ? ((const float*)sg.src)[i] : bf2f(((const __hip_bfloat16*)sg.src)[i]);
            if (!(v == v) || fabsf(v) > 1e30f) v = 0.f;
            canon[sg.off + i] = v;
        }
    } else {
        int e = (b - 86) * 256 + t;
        if (e < E) {
            int d = eidx[E + e];
            if ((unsigned)d < (unsigned)N) atomicAdd(&cnt[d], 1);
        }
    }
}

// ---------------- packed 64-bit exclusive scan ------------------------------

DEV ull packval(const int* cnt, const int* msk, int i) {
    return ((ull)(unsigned)msk[i] << 32) | (unsigned)(cnt[i] + 1);
}

__global__ void k_scan_partial64(const int* __restrict__ cnt, const int* __restrict__ msk,
                                 int n, ull* __restrict__ partials) {
    __shared__ ull red[256];
    int t = threadIdx.x, b = blockIdx.x;
    int base = b * 1024 + t * 4;
    ull s = 0;
    #pragma unroll
    for (int j = 0; j < 4; j++) { int i = base + j; if (i < n) s += packval(cnt, msk, i); }
    red[t] = s; __syncthreads();
    for (int o = 128; o > 0; o >>= 1) { if (t < o) red[t] += red[t + o]; __syncthreads(); }
    if (t == 0) partials[b] = red[0];
}

__global__ void k_scan_mid64(ull* partials, int nb, int* offN, int* totals) {
    __shared__ ull sh[256];
    int t = threadIdx.x;
    ull carry = 0;
    for (int base = 0; base < nb; base += 256) {
        int i = base + t;
        ull v = (i < nb) ? partials[i] : 0;
        sh[t] = v; __syncthreads();
        for (int o = 1; o < 256; o <<= 1) {
            ull x = (t >= o) ? sh[t - o] : 0;
            __syncthreads();
            sh[t] += x;
            __syncthreads();
        }
        if (i < nb) partials[i] = carry + sh[t] - v;   // exclusive
        ull tot = sh[255];
        __syncthreads();
        carry += tot;
    }
    if (t == 0) { *offN = (int)(carry & 0xffffffffu); *totals = (int)(carry >> 32); }
}

__global__ void k_scan_final64(int* __restrict__ cnt, int* __restrict__ msk, int n,
                               const ull* __restrict__ partials,
                               int* __restrict__ off, int* __restrict__ cur) {
    __shared__ ull sums[256];
    int t = threadIdx.x, b = blockIdx.x;
    int base = b * 1024 + t * 4;
    ull v0 = 0, v1 = 0, v2 = 0, v3 = 0;
    if (base     < n) v0 = packval(cnt, msk, base);
    if (base + 1 < n) v1 = packval(cnt, msk, base + 1);
    if (base + 2 < n) v2 = packval(cnt, msk, base + 2);
    if (base + 3 < n) v3 = packval(cnt, msk, base + 3);
    ull s = v0 + v1 + v2 + v3;
    sums[t] = s; __syncthreads();
    for (int o = 1; o < 256; o <<= 1) {
        ull x = (t >= o) ? sums[t - o] : 0;
        __syncthreads();
        sums[t] += x;
        __syncthreads();
    }
    ull run = partials[b] + (sums[t] - s);
    #pragma unroll
    for (int j = 0; j < 4; j++) {
        int i = base + j;
        if (i < n) {
            int lo = (int)(run & 0xffffffffu), hi = (int)(run >> 32);
            off[i] = lo; cur[i] = lo; msk[i] = hi;
            run += (j == 0 ? v0 : j == 1 ? v1 : j == 2 ? v2 : v3);
        }
    }
}

// ---------------- CSR fill ----------------

__global__ void k_fill(const int* __restrict__ eidx, int E, int N, int EE,
                       int* __restrict__ cursor, int* __restrict__ esrc) {
    int e = blockIdx.x * 256 + threadIdx.x;
    if (e < E) {
        int s = eidx[e], d = eidx[E + e];
        if ((unsigned)d < (unsigned)N && (unsigned)s < (unsigned)N) {
            int p = atomicAdd(&cursor[d], 1);
            if ((unsigned)p < (unsigned)EE) esrc[p] = s;
        }
    } else if (e < E + N) {
        int i = e - E;
        int p = atomicAdd(&cursor[i], 1);
        if ((unsigned)p < (unsigned)EE) esrc[p] = i;
    }
}

// ---------------- GAT node kernels ------------------------------------------
// Round-7 restructure: W column-pair lives in VGPRs (lane l owns cols 2l,2l+1;
// head = l>>4); x staged per 64-node block in LDS and read via WAVE-UNIFORM
// ds_read_b128 (same-address broadcast = conflict-free). This removes the
// round-6 bottleneck (64 LDS ops/node: 32 shfl + 32 ds_read_b64 -> 8 b128).
// Each of the block's 4 waves computes 16 nodes end-to-end.

__global__ __launch_bounds__(256) void k_node_first(
    const float* __restrict__ xF, const float* __restrict__ W,
    const float* __restrict__ atS, const float* __restrict__ atD,
    int N, __hip_bfloat162* __restrict__ h2, float* __restrict__ as_, float* __restrict__ ad_) {
    __shared__ float xl[64 * 4];   // padded to 4 floats/node
    int t = threadIdx.x, lane = t & 63, w = t >> 6;
    int nblk = blockIdx.x * 64;
    int cnt = N - nblk; if (cnt > 64) cnt = 64;

    if (t < 64) xl[t * 4 + 3] = 0.f;
    for (int i = t; i < cnt * 3; i += 256) xl[(i / 3) * 4 + (i % 3)] = xF[(size_t)nblk * 3 + i];

    const float2* W2 = (const float2*)W;
    float2 Wr0 = W2[0 * 64 + lane], Wr1 = W2[1 * 64 + lane], Wr2 = W2[2 * 64 + lane];
    float2 aSp = ((const float2*)atS)[lane];
    float2 aDp = ((const float2*)atD)[lane];
    int hd = lane >> 4;
    __syncthreads();

    for (int i = 0; i < 16; i++) {
        int n = nblk + w * 16 + i;
        if (n >= N) break;
        float4 xv = ((const float4*)xl)[w * 16 + i];   // wave-uniform broadcast
        float acc0 = xv.x * Wr0.x + xv.y * Wr1.x + xv.z * Wr2.x;
        float acc1 = xv.x * Wr0.y + xv.y * Wr1.y + xv.z * Wr2.y;
        __hip_bfloat162 hv; hv.x = __float2bfloat16(acc0); hv.y = __float2bfloat16(acc1);
        h2[(size_t)n * 64 + lane] = hv;
        float p = acc0 * aSp.x + acc1 * aSp.y;
        float q = acc0 * aDp.x + acc1 * aDp.y;
        #pragma unroll
        for (int o = 1; o < 16; o <<= 1) { p += __shfl_xor(p, o, 64); q += __shfl_xor(q, o, 64); }
        if ((lane & 15) == 0) { as_[n * 4 + hd] = p; ad_[n * 4 + hd] = q; }
    }
}

__global__ __launch_bounds__(256) void k_node_mid(
    const float* __restrict__ xin, const float* __restrict__ W,
    const float* __restrict__ atS, const float* __restrict__ atD,
    int N, __hip_bfloat162* __restrict__ h2, float* __restrict__ as_, float* __restrict__ ad_) {
    __shared__ float xl[64 * 32];
    int t = threadIdx.x, lane = t & 63, w = t >> 6;
    int nblk = blockIdx.x * 64;
    int cnt = N - nblk; if (cnt > 64) cnt = 64;

    {   // coalesced stage of x tile (cnt*32 floats, multiple of 8 float4s)
        const float4* g4 = (const float4*)(xin + (size_t)nblk * 32);
        float4* l4 = (float4*)xl;
        int lim = cnt * 8;
        if (t < lim) l4[t] = g4[t];
        int t2 = t + 256;
        if (t2 < lim) l4[t2] = g4[t2];
    }

    const float2* W2 = (const float2*)W;
    float2 Wr[32];
    #pragma unroll
    for (int k = 0; k < 32; k++) Wr[k] = W2[k * 64 + lane];   // 128 VGPRs
    float2 aSp = ((const float2*)atS)[lane];
    float2 aDp = ((const float2*)atD)[lane];
    int hd = lane >> 4;
    __syncthreads();

    for (int i = 0; i < 16; i++) {
        int n = nblk + w * 16 + i;
        if (n >= N) break;
        const float4* xv4 = (const float4*)&xl[(w * 16 + i) * 32];
        float acc0 = 0.f, acc1 = 0.f;
        #pragma unroll
        for (int kk = 0; kk < 8; kk++) {
            float4 xv = xv4[kk];                        // wave-uniform broadcast
            acc0 += xv.x * Wr[4*kk+0].x; acc1 += xv.x * Wr[4*kk+0].y;
            acc0 += xv.y * Wr[4*kk+1].x; acc1 += xv.y * Wr[4*kk+1].y;
            acc0 += xv.z * Wr[4*kk+2].x; acc1 += xv.z * Wr[4*kk+2].y;
            acc0 += xv.w * Wr[4*kk+3].x; acc1 += xv.w * Wr[4*kk+3].y;
        }
        __hip_bfloat162 hv; hv.x = __float2bfloat16(acc0); hv.y = __float2bfloat16(acc1);
        h2[(size_t)n * 64 + lane] = hv;
        float p = acc0 * aSp.x + acc1 * aSp.y;
        float q = acc0 * aDp.x + acc1 * aDp.y;
        #pragma unroll
        for (int o = 1; o < 16; o <<= 1) { p += __shfl_xor(p, o, 64); q += __shfl_xor(q, o, 64); }
        if ((lane & 15) == 0) { as_[n * 4 + hd] = p; ad_[n * 4 + hd] = q; }
    }
}

// ---------------- GAT edge kernel (unchanged from round 6) ------------------

constexpr int FCAP  = 64;
constexpr int FCAPP = 68;

__global__ __launch_bounds__(256) void k_edge(
    const __hip_bfloat162* __restrict__ h2, const float* __restrict__ as_,
    const float* __restrict__ ad_, const int* __restrict__ off,
    const int* __restrict__ esrc, const float* __restrict__ bias,
    int N, float* __restrict__ xout) {
    __shared__ float alphaS[4][4 * FCAPP];
    __shared__ int   srcS[4][FCAP];
    int t = threadIdx.x, lane = t & 63, w = t >> 6;
    int n = blockIdx.x * 4 + w;
    if (n >= N) return;
    int beg = off[n], end = off[n + 1];
    int deg = end - beg;
    float4 adn = ((const float4*)ad_)[n];
    const float4* as4 = (const float4*)as_;
    int hd = lane >> 4;

    float acc0 = 0.f, acc1 = 0.f;

    if (deg <= 16) {
        int e = lane >> 2, h = lane & 3;
        int s_e = n;
        float v = -1e30f;
        if (e < deg) {
            int s = esrc[beg + e];
            if ((unsigned)s < (unsigned)N) {
                s_e = s;
                float asv = as_[s * 4 + h];
                float adv = h == 0 ? adn.x : h == 1 ? adn.y : h == 2 ? adn.z : adn.w;
                v = asv + adv; v = v >= 0.f ? v : 0.2f * v;
            }
        }
        float m = v;
        #pragma unroll
        for (int o = 4; o < 64; o <<= 1) m = fmaxf(m, __shfl_xor(m, o, 64));
        float ex = (v > -1e29f) ? __expf(v - m) : 0.f;
        float ssum = ex;
        #pragma unroll
        for (int o = 4; o < 64; o <<= 1) ssum += __shfl_xor(ssum, o, 64);
        float inv = 1.f / (ssum + 1e-16f);
        float invH = __shfl(inv, hd, 64);
        for (int i = 0; i < deg; i++) {
            float wt = __shfl(ex, 4 * i + hd, 64) * invH;
            int s = __shfl(s_e, 4 * i, 64);
            __hip_bfloat162 hv = h2[(size_t)s * 64 + lane];
            acc0 += wt * bf2f(hv.x);
            acc1 += wt * bf2f(hv.y);
        }
    } else {
        bool fits = (deg <= FCAP);
        float m0 = -1e30f, m1 = -1e30f, m2 = -1e30f, m3 = -1e30f;
        for (int e = beg + lane; e < end; e += 64) {
            int s = esrc[e];
            if ((unsigned)s >= (unsigned)N) continue;
            float4 a = as4[s];
            float v0 = a.x + adn.x; v0 = v0 >= 0.f ? v0 : 0.2f * v0;
            float v1 = a.y + adn.y; v1 = v1 >= 0.f ? v1 : 0.2f * v1;
            float v2 = a.z + adn.z; v2 = v2 >= 0.f ? v2 : 0.2f * v2;
            float v3 = a.w + adn.w; v3 = v3 >= 0.f ? v3 : 0.2f * v3;
            m0 = fmaxf(m0, v0); m1 = fmaxf(m1, v1); m2 = fmaxf(m2, v2); m3 = fmaxf(m3, v3);
        }
        #pragma unroll
        for (int o = 1; o < 64; o <<= 1) {
            m0 = fmaxf(m0, __shfl_xor(m0, o, 64));
            m1 = fmaxf(m1, __shfl_xor(m1, o, 64));
            m2 = fmaxf(m2, __shfl_xor(m2, o, 64));
            m3 = fmaxf(m3, __shfl_xor(m3, o, 64));
        }
        float s0 = 0.f, s1 = 0.f, s2 = 0.f, s3 = 0.f;
        for (int e = beg + lane; e < end; e += 64) {
            int s = esrc[e];
            bool ok = (unsigned)s < (unsigned)N;
            float4 a = ok ? as4[s] : make_float4(-1e30f, -1e30f, -1e30f, -1e30f);
            float v0 = a.x + adn.x; v0 = v0 >= 0.f ? v0 : 0.2f * v0;
            float v1 = a.y + adn.y; v1 = v1 >= 0.f ? v1 : 0.2f * v1;
            float v2 = a.z + adn.z; v2 = v2 >= 0.f ? v2 : 0.2f * v2;
            float v3 = a.w + adn.w; v3 = v3 >= 0.f ? v3 : 0.2f * v3;
            float e0 = __expf(v0 - m0), e1 = __expf(v1 - m1);
            float e2 = __expf(v2 - m2), e3 = __expf(v3 - m3);
            s0 += e0; s1 += e1; s2 += e2; s3 += e3;
            if (fits) {
                int i = e - beg;
                srcS[w][i] = ok ? s : n;
                alphaS[w][0 * FCAPP + i] = e0;
                alphaS[w][1 * FCAPP + i] = e1;
                alphaS[w][2 * FCAPP + i] = e2;
                alphaS[w][3 * FCAPP + i] = e3;
            }
        }
        #pragma unroll
        for (int o = 1; o < 64; o <<= 1) {
            s0 += __shfl_xor(s0, o, 64); s1 += __shfl_xor(s1, o, 64);
            s2 += __shfl_xor(s2, o, 64); s3 += __shfl_xor(s3, o, 64);
        }
        float i0 = 1.f / (s0 + 1e-16f), i1 = 1.f / (s1 + 1e-16f);
        float i2 = 1.f / (s2 + 1e-16f), i3 = 1.f / (s3 + 1e-16f);
        float invH = hd == 0 ? i0 : hd == 1 ? i1 : hd == 2 ? i2 : i3;
        if (fits) {
            for (int i = 0; i < deg; i++) {
                int s = srcS[w][i];
                float wt = alphaS[w][hd * FCAPP + i] * invH;
                __hip_bfloat162 hv = h2[(size_t)s * 64 + lane];
                acc0 += wt * bf2f(hv.x);
                acc1 += wt * bf2f(hv.y);
            }
        } else {
            float mH  = hd == 0 ? m0 : hd == 1 ? m1 : hd == 2 ? m2 : m3;
            float adH = hd == 0 ? adn.x : hd == 1 ? adn.y : hd == 2 ? adn.z : adn.w;
            for (int e = beg; e < end; e++) {
                int s = esrc[e];
                if ((unsigned)s >= (unsigned)N) continue;
                float4 a = as4[s];
                float aH = hd == 0 ? a.x : hd == 1 ? a.y : hd == 2 ? a.z : a.w;
                float v = aH + adH; v = v >= 0.f ? v : 0.2f * v;
                float wt = __expf(v - mH) * invH;
                __hip_bfloat162 hv = h2[(size_t)s * 64 + lane];
                acc0 += wt * bf2f(hv.x);
                acc1 += wt * bf2f(hv.y);
            }
        }
    }
    acc0 += __shfl_xor(acc0, 16, 64); acc0 += __shfl_xor(acc0, 32, 64);
    acc1 += __shfl_xor(acc1, 16, 64); acc1 += __shfl_xor(acc1, 32, 64);
    if (lane < 16) {
        float o0 = acc0 * 0.25f + bias[2 * lane];     o0 = o0 >= 0.f ? o0 : 0.01f * o0;
        float o1 = acc1 * 0.25f + bias[2 * lane + 1]; o1 = o1 >= 0.f ? o1 : 0.01f * o1;
        ((float2*)xout)[(size_t)n * 16 + lane] = make_float2(o0, o1);
    }
}

// ---------------- MLP + output scatter (unchanged from round 6) -------------

__global__ __launch_bounds__(128) void k_mlp(
    const float* __restrict__ xF, const float* __restrict__ x3,
    const float* __restrict__ mW1, const float* __restrict__ mb1,
    const float* __restrict__ mW2, const float* __restrict__ mb2,
    const float* __restrict__ mW3, const float* __restrict__ mb3,
    const float* __restrict__ mW4, const float* __restrict__ mb4,
    const float* __restrict__ mW5, const float* __restrict__ mb5,
    const int* __restrict__ smask, const int* __restrict__ totals,
    const int* __restrict__ flag, int N, void* __restrict__ out) {
    __shared__ float W1[35 * 32], W2[1024], W3[1024], W4[1024], W5[32 * 12];
    __shared__ float B1[32], B2[32], B3[32], B4[32], B5[12];
    __shared__ float actA[35 * 128];
    __shared__ float actB[32 * 128];
    int t = threadIdx.x;
    for (int i = t; i < 1120; i += 128) W1[i] = mW1[i];
    for (int i = t; i < 1024; i += 128) { W2[i] = mW2[i]; W3[i] = mW3[i]; W4[i] = mW4[i]; }
    for (int i = t; i < 384; i += 128) W5[i] = mW5[i];
    if (t < 32) { B1[t] = mb1[t]; B2[t] = mb2[t]; B3[t] = mb3[t]; B4[t] = mb4[t]; }
    if (t < 12) B5[t] = mb5[t];
    __syncthreads();

    int n = blockIdx.x * 128 + t;
    bool alive = (n < N);
    float x0 = 0.f;
    if (alive) {
        x0 = xF[n * 3 + 0];
        actA[0 * 128 + t] = x0;
        actA[1 * 128 + t] = xF[n * 3 + 1];
        actA[2 * 128 + t] = xF[n * 3 + 2];
        for (int i = 0; i < 32; i++) actA[(3 + i) * 128 + t] = x3[(size_t)n * 32 + i];
    }

    float acc[32];

    #pragma unroll
    for (int o = 0; o < 32; o++) acc[o] = B1[o];
    #pragma unroll 2
    for (int i = 0; i < 35; i++) {
        float ai = actA[i * 128 + t];
        const float4* w4 = (const float4*)&W1[i * 32];
        #pragma unroll
        for (int q = 0; q < 8; q++) {
            float4 w = w4[q];
            acc[q*4+0] += ai * w.x; acc[q*4+1] += ai * w.y;
            acc[q*4+2] += ai * w.z; acc[q*4+3] += ai * w.w;
        }
    }
    #pragma unroll
    for (int o = 0; o < 32; o++) { float v = acc[o]; actB[o * 128 + t] = (v >= 0.f ? v : 0.01f * v); }

    #pragma unroll
    for (int o = 0; o < 32; o++) acc[o] = B2[o];
    #pragma unroll 2
    for (int i = 0; i < 32; i++) {
        float ai = actB[i * 128 + t];
        const float4* w4 = (const float4*)&W2[i * 32];
        #pragma unroll
        for (int q = 0; q < 8; q++) {
            float4 w = w4[q];
            acc[q*4+0] += ai * w.x; acc[q*4+1] += ai * w.y;
            acc[q*4+2] += ai * w.z; acc[q*4+3] += ai * w.w;
        }
    }
    #pragma unroll
    for (int o = 0; o < 32; o++) { float v = acc[o]; actA[o * 128 + t] = (v >= 0.f ? v : 0.01f * v); }

    #pragma unroll
    for (int o = 0; o < 32; o++) acc[o] = B3[o];
    #pragma unroll 2
    for (int i = 0; i < 32; i++) {
        float ai = actA[i * 128 + t];
        const float4* w4 = (const float4*)&W3[i * 32];
        #pragma unroll
        for (int q = 0; q < 8; q++) {
            float4 w = w4[q];
            acc[q*4+0] += ai * w.x; acc[q*4+1] += ai * w.y;
            acc[q*4+2] += ai * w.z; acc[q*4+3] += ai * w.w;
        }
    }
    #pragma unroll
    for (int o = 0; o < 32; o++) { float v = acc[o]; actB[o * 128 + t] = (v >= 0.f ? v : 0.01f * v); }

    #pragma unroll
    for (int o = 0; o < 32; o++) acc[o] = B4[o];
    #pragma unroll 2
    for (int i = 0; i < 32; i++) {
        float ai = actB[i * 128 + t];
        const float4* w4 = (const float4*)&W4[i * 32];
        #pragma unroll
        for (int q = 0; q < 8; q++) {
            float4 w = w4[q];
            acc[q*4+0] += ai * w.x; acc[q*4+1] += ai * w.y;
            acc[q*4+2] += ai * w.z; acc[q*4+3] += ai * w.w;
        }
    }
    #pragma unroll
    for (int o = 0; o < 32; o++) { float v = acc[o]; actA[o * 128 + t] = (v >= 0.f ? v : 0.01f * v); }

    float d[12];
    #pragma unroll
    for (int o = 0; o < 12; o++) d[o] = B5[o];
    #pragma unroll 2
    for (int i = 0; i < 32; i++) {
        float ai = actA[i * 128 + t];
        const float4* w4 = (const float4*)&W5[i * 12];
        #pragma unroll
        for (int q = 0; q < 3; q++) {
            float4 w = w4[q];
            d[q*4+0] += ai * w.x; d[q*4+1] += ai * w.y;
            d[q*4+2] += ai * w.z; d[q*4+3] += ai * w.w;
        }
    }
    if (!alive) return;
    #pragma unroll
    for (int o = 0; o < 12; o++) if (!(d[o] == d[o])) d[o] = 0.f;  // NaN scrub

    bool tower = (x0 == 0.0f);
    int r = smask[n];
    int Nt = *totals;
    int f32o = *flag;
    int base9, base3, rr;
    if (tower) { rr = r;     base9 = 0;      base3 = 9 * N; }
    else       { rr = n - r; base9 = 9 * Nt; base3 = 9 * N + 3 * Nt; }
    if (f32o) {
        float* o = (float*)out;
        #pragma unroll
        for (int j = 0; j < 9; j++) o[base9 + rr * 9 + j] = d[j];
        #pragma unroll
        for (int j = 0; j < 3; j++) o[base3 + rr * 3 + j] = d[9 + j];
    } else {
        __hip_bfloat16* o = (__hip_bfloat16*)out;
        #pragma unroll
        for (int j = 0; j < 9; j++) o[base9 + rr * 9 + j] = __float2bfloat16(d[j]);
        #pragma unroll
        for (int j = 0; j < 3; j++) o[base3 + rr * 3 + j] = __float2bfloat16(d[9 + j]);
    }
}

// ---------------- launch ----------------

extern "C" void kernel_launch(void* const* d_in, const int* in_sizes, int n_in,
                              void* d_out, int out_size, void* d_ws, size_t ws_size,
                              hipStream_t stream) {
    const void* xraw = d_in[0];
    const int*  eidx = (const int*)d_in[1];
    // d_in[2] edge_attr: unused

    int N  = in_sizes[0] / 3;
    int E  = in_sizes[1] / 2;
    int EE = E + N;

    Segs segs;
    int coff[22];
    int canonN = 3 * N;
    for (int i = 3; i <= 24; i++) {
        int a = i - 3;
        segs.s[a].src = d_in[i];
        segs.s[a].off = canonN;
        segs.s[a].len = in_sizes[i];
        coff[a] = canonN;
        canonN += in_sizes[i];
    }

    auto alignv = [](size_t v, size_t a) { return (v + a - 1) & ~(a - 1); };
    char* base = (char*)d_ws;
    size_t o = 0;
    float* canon = (float*)(base + o); o = alignv(o + (size_t)canonN * 4, 16);
    int* flag     = (int*)(base + o); o = alignv(o + 16, 16);
    ull* partials = (ull*)(base + o); o = alignv(o + 1024 * 8, 16);
    int* totals   = (int*)(base + o); o = alignv(o + 16, 16);
    int* off      = (int*)(base + o); o = alignv(o + (size_t)(N + 1) * 4, 16);
    int* cur      = (int*)(base + o); o = alignv(o + (size_t)N * 4, 16);
    int* esrc     = (int*)(base + o); o = alignv(o + (size_t)EE * 4, 16);
    int* msk      = (int*)(base + o); o = alignv(o + (size_t)N * 4, 256);
    __hip_bfloat162* h2 = (__hip_bfloat162*)(base + o); o = alignv(o + (size_t)N * 64 * 4, 16);
    float* xb  = (float*)(base + o); o = alignv(o + (size_t)N * 32 * 4, 16);
    float* as_ = (float*)(base + o); o = alignv(o + (size_t)N * 16, 16);
    float* ad_ = (float*)(base + o);

    int nb = (N + 1023) / 1024;
    int gN = (N + 255) / 256;
    int g4 = (N + 3) / 4;
    int g64 = (N + 63) / 64;
    int gM = (N + 127) / 128;

    int nprobe = in_sizes[0] < 4096 ? in_sizes[0] : 4096;
    k_detect_zero<<<gN, 256, 0, stream>>>((const unsigned short*)xraw, nprobe, flag, cur, N);
    k_fused<<<86 + (E + 255) / 256, 256, 0, stream>>>(xraw, 3 * N, segs, canon, flag,
                                                      eidx, E, N, cur, msk);
    k_scan_partial64<<<nb, 256, 0, stream>>>(cur, msk, N, partials);
    k_scan_mid64<<<1, 256, 0, stream>>>(partials, nb, off + N, totals);
    k_scan_final64<<<nb, 256, 0, stream>>>(cur, msk, N, partials, off, cur);
    k_fill<<<(EE + 255) / 256, 256, 0, stream>>>(eidx, E, N, EE, cur, esrc);

    float* xF = canon;
    const float* W1  = canon + coff[0];  const float* aS1 = canon + coff[1];
    const float* aD1 = canon + coff[2];  const float* b1  = canon + coff[3];
    const float* W2  = canon + coff[4];  const float* aS2 = canon + coff[5];
    const float* aD2 = canon + coff[6];  const float* b2  = canon + coff[7];
    const float* W3  = canon + coff[8];  const float* aS3 = canon + coff[9];
    const float* aD3 = canon + coff[10]; const float* b3  = canon + coff[11];

    k_node_first<<<g64, 256, 0, stream>>>(xF, W1, aS1, aD1, N, h2, as_, ad_);
    k_edge<<<g4, 256, 0, stream>>>(h2, as_, ad_, off, esrc, b1, N, xb);
    k_node_mid<<<g64, 256, 0, stream>>>(xb, W2, aS2, aD2, N, h2, as_, ad_);
    k_edge<<<g4, 256, 0, stream>>>(h2, as_, ad_, off, esrc, b2, N, xb);
    k_node_mid<<<g64, 256, 0, stream>>>(xb, W3, aS3, aD3, N, h2, as_, ad_);
    k_edge<<<g4, 256, 0, stream>>>(h2, as_, ad_, off, esrc, b3, N, xb);

    k_mlp<<<gM, 128, 0, stream>>>(xF, xb,
        canon + coff[12], canon + coff[13], canon + coff[14], canon + coff[15],
        canon + coff[16], canon + coff[17], canon + coff[18], canon + coff[19],
        canon + coff[20], canon + coff[21], msk, totals, flag, N, d_out);
}

// Round 8
// 491.315 us; speedup vs baseline: 4.8578x; 1.1489x over previous
//
#include <hip/hip_runtime.h>
#include <hip/hip_bf16.h>

#define DEV __device__ __forceinline__

DEV float bf2f(__hip_bfloat16 v) { return __bfloat162float(v); }

typedef unsigned long long ull;

// ---------------- detect dtype + zero degree array ----------------
__global__ void k_detect_zero(const unsigned short* xr, int nprobe, int* flag,
                              int* cnt, int N) {
    int i = blockIdx.x * 256 + threadIdx.x;
    if (i < N) cnt[i] = 0;
    if (blockIdx.x == 0) {
        __shared__ int red[256];
        int t = threadIdx.x, bad = 0;
        for (int j = t; j < nprobe; j += 256) {
            unsigned e = (xr[j] >> 7) & 0xFF;
            if (e >= 0x8F) bad++;
        }
        red[t] = bad; __syncthreads();
        for (int o = 128; o > 0; o >>= 1) { if (t < o) red[t] += red[t + o]; __syncthreads(); }
        if (t == 0) flag[0] = (red[0] > 256) ? 1 : 0;   // 1 = inputs are f32
    }
}

// ---------------- fused ingest + tower mask + degree count ------------------
struct Seg  { const void* src; int off; int len; };
struct Segs { Seg s[22]; };

__global__ void k_fused(const void* xsrc, int nx3, Segs segs, float* canon,
                        const int* flag, const int* eidx, int E, int N,
                        int* cnt, int* msk) {
    int f32 = flag[0];
    int t = threadIdx.x, b = blockIdx.x;
    if (b < 64) {
        for (int i = b * 256 + t; i < nx3; i += 64 * 256) {
            float v = f32 ? ((const float*)xsrc)[i] : bf2f(((const __hip_bfloat16*)xsrc)[i]);
            if (!(v == v) || fabsf(v) > 1e30f) v = 0.f;   // scrub
            canon[i] = v;
            if (i % 3 == 0) msk[i / 3] = (v == 0.0f) ? 1 : 0;
        }
    } else if (b < 86) {
        Seg sg = segs.s[b - 64];
        for (int i = t; i < sg.len; i += 256) {
            float v = f32 ? ((const float*)sg.src)[i] : bf2f(((const __hip_bfloat16*)sg.src)[i]);
            if (!(v == v) || fabsf(v) > 1e30f) v = 0.f;
            canon[sg.off + i] = v;
        }
    } else {
        int e = (b - 86) * 256 + t;
        if (e < E) {
            int d = eidx[E + e];
            if ((unsigned)d < (unsigned)N) atomicAdd(&cnt[d], 1);
        }
    }
}

// ---------------- packed 64-bit exclusive scan ------------------------------

DEV ull packval(const int* cnt, const int* msk, int i) {
    return ((ull)(unsigned)msk[i] << 32) | (unsigned)(cnt[i] + 1);
}

__global__ void k_scan_partial64(const int* __restrict__ cnt, const int* __restrict__ msk,
                                 int n, ull* __restrict__ partials) {
    __shared__ ull red[256];
    int t = threadIdx.x, b = blockIdx.x;
    int base = b * 1024 + t * 4;
    ull s = 0;
    #pragma unroll
    for (int j = 0; j < 4; j++) { int i = base + j; if (i < n) s += packval(cnt, msk, i); }
    red[t] = s; __syncthreads();
    for (int o = 128; o > 0; o >>= 1) { if (t < o) red[t] += red[t + o]; __syncthreads(); }
    if (t == 0) partials[b] = red[0];
}

__global__ void k_scan_mid64(ull* partials, int nb, int* offN, int* totals) {
    __shared__ ull sh[256];
    int t = threadIdx.x;
    ull carry = 0;
    for (int base = 0; base < nb; base += 256) {
        int i = base + t;
        ull v = (i < nb) ? partials[i] : 0;
        sh[t] = v; __syncthreads();
        for (int o = 1; o < 256; o <<= 1) {
            ull x = (t >= o) ? sh[t - o] : 0;
            __syncthreads();
            sh[t] += x;
            __syncthreads();
        }
        if (i < nb) partials[i] = carry + sh[t] - v;   // exclusive
        ull tot = sh[255];
        __syncthreads();
        carry += tot;
    }
    if (t == 0) { *offN = (int)(carry & 0xffffffffu); *totals = (int)(carry >> 32); }
}

__global__ void k_scan_final64(int* __restrict__ cnt, int* __restrict__ msk, int n,
                               const ull* __restrict__ partials,
                               int* __restrict__ off, int* __restrict__ cur) {
    __shared__ ull sums[256];
    int t = threadIdx.x, b = blockIdx.x;
    int base = b * 1024 + t * 4;
    ull v0 = 0, v1 = 0, v2 = 0, v3 = 0;
    if (base     < n) v0 = packval(cnt, msk, base);
    if (base + 1 < n) v1 = packval(cnt, msk, base + 1);
    if (base + 2 < n) v2 = packval(cnt, msk, base + 2);
    if (base + 3 < n) v3 = packval(cnt, msk, base + 3);
    ull s = v0 + v1 + v2 + v3;
    sums[t] = s; __syncthreads();
    for (int o = 1; o < 256; o <<= 1) {
        ull x = (t >= o) ? sums[t - o] : 0;
        __syncthreads();
        sums[t] += x;
        __syncthreads();
    }
    ull run = partials[b] + (sums[t] - s);
    #pragma unroll
    for (int j = 0; j < 4; j++) {
        int i = base + j;
        if (i < n) {
            int lo = (int)(run & 0xffffffffu), hi = (int)(run >> 32);
            off[i] = lo; cur[i] = lo; msk[i] = hi;
            run += (j == 0 ? v0 : j == 1 ? v1 : j == 2 ? v2 : v3);
        }
    }
}

// ---------------- CSR fill ----------------

__global__ void k_fill(const int* __restrict__ eidx, int E, int N, int EE,
                       int* __restrict__ cursor, int* __restrict__ esrc) {
    int e = blockIdx.x * 256 + threadIdx.x;
    if (e < E) {
        int s = eidx[e], d = eidx[E + e];
        if ((unsigned)d < (unsigned)N && (unsigned)s < (unsigned)N) {
            int p = atomicAdd(&cursor[d], 1);
            if ((unsigned)p < (unsigned)EE) esrc[p] = s;
        }
    } else if (e < E + N) {
        int i = e - E;
        int p = atomicAdd(&cursor[i], 1);
        if ((unsigned)p < (unsigned)EE) esrc[p] = i;
    }
}

// ---------------- GAT node kernels (unchanged from round 7) -----------------

__global__ __launch_bounds__(256) void k_node_first(
    const float* __restrict__ xF, const float* __restrict__ W,
    const float* __restrict__ atS, const float* __restrict__ atD,
    int N, __hip_bfloat162* __restrict__ h2, float* __restrict__ as_, float* __restrict__ ad_) {
    __shared__ float xl[64 * 4];
    int t = threadIdx.x, lane = t & 63, w = t >> 6;
    int nblk = blockIdx.x * 64;
    int cnt = N - nblk; if (cnt > 64) cnt = 64;

    if (t < 64) xl[t * 4 + 3] = 0.f;
    for (int i = t; i < cnt * 3; i += 256) xl[(i / 3) * 4 + (i % 3)] = xF[(size_t)nblk * 3 + i];

    const float2* W2 = (const float2*)W;
    float2 Wr0 = W2[0 * 64 + lane], Wr1 = W2[1 * 64 + lane], Wr2 = W2[2 * 64 + lane];
    float2 aSp = ((const float2*)atS)[lane];
    float2 aDp = ((const float2*)atD)[lane];
    int hd = lane >> 4;
    __syncthreads();

    for (int i = 0; i < 16; i++) {
        int n = nblk + w * 16 + i;
        if (n >= N) break;
        float4 xv = ((const float4*)xl)[w * 16 + i];
        float acc0 = xv.x * Wr0.x + xv.y * Wr1.x + xv.z * Wr2.x;
        float acc1 = xv.x * Wr0.y + xv.y * Wr1.y + xv.z * Wr2.y;
        __hip_bfloat162 hv; hv.x = __float2bfloat16(acc0); hv.y = __float2bfloat16(acc1);
        h2[(size_t)n * 64 + lane] = hv;
        float p = acc0 * aSp.x + acc1 * aSp.y;
        float q = acc0 * aDp.x + acc1 * aDp.y;
        #pragma unroll
        for (int o = 1; o < 16; o <<= 1) { p += __shfl_xor(p, o, 64); q += __shfl_xor(q, o, 64); }
        if ((lane & 15) == 0) { as_[n * 4 + hd] = p; ad_[n * 4 + hd] = q; }
    }
}

__global__ __launch_bounds__(256) void k_node_mid(
    const float* __restrict__ xin, const float* __restrict__ W,
    const float* __restrict__ atS, const float* __restrict__ atD,
    int N, __hip_bfloat162* __restrict__ h2, float* __restrict__ as_, float* __restrict__ ad_) {
    __shared__ float xl[64 * 32];
    int t = threadIdx.x, lane = t & 63, w = t >> 6;
    int nblk = blockIdx.x * 64;
    int cnt = N - nblk; if (cnt > 64) cnt = 64;

    {
        const float4* g4 = (const float4*)(xin + (size_t)nblk * 32);
        float4* l4 = (float4*)xl;
        int lim = cnt * 8;
        if (t < lim) l4[t] = g4[t];
        int t2 = t + 256;
        if (t2 < lim) l4[t2] = g4[t2];
    }

    const float2* W2 = (const float2*)W;
    float2 Wr[32];
    #pragma unroll
    for (int k = 0; k < 32; k++) Wr[k] = W2[k * 64 + lane];
    float2 aSp = ((const float2*)atS)[lane];
    float2 aDp = ((const float2*)atD)[lane];
    int hd = lane >> 4;
    __syncthreads();

    for (int i = 0; i < 16; i++) {
        int n = nblk + w * 16 + i;
        if (n >= N) break;
        const float4* xv4 = (const float4*)&xl[(w * 16 + i) * 32];
        float acc0 = 0.f, acc1 = 0.f;
        #pragma unroll
        for (int kk = 0; kk < 8; kk++) {
            float4 xv = xv4[kk];
            acc0 += xv.x * Wr[4*kk+0].x; acc1 += xv.x * Wr[4*kk+0].y;
            acc0 += xv.y * Wr[4*kk+1].x; acc1 += xv.y * Wr[4*kk+1].y;
            acc0 += xv.z * Wr[4*kk+2].x; acc1 += xv.z * Wr[4*kk+2].y;
            acc0 += xv.w * Wr[4*kk+3].x; acc1 += xv.w * Wr[4*kk+3].y;
        }
        __hip_bfloat162 hv; hv.x = __float2bfloat16(acc0); hv.y = __float2bfloat16(acc1);
        h2[(size_t)n * 64 + lane] = hv;
        float p = acc0 * aSp.x + acc1 * aSp.y;
        float q = acc0 * aDp.x + acc1 * aDp.y;
        #pragma unroll
        for (int o = 1; o < 16; o <<= 1) { p += __shfl_xor(p, o, 64); q += __shfl_xor(q, o, 64); }
        if ((lane & 15) == 0) { as_[n * 4 + hd] = p; ad_[n * 4 + hd] = q; }
    }
}

// ---------------- GAT edge kernel -------------------------------------------
// Round-8: fast path (deg<=16) hoists ALL 16 (wt,src) shuffle pairs into
// registers (fixed-trip unroll, constant indices -> register promotion), then
// gathers in 4 unrolled chunks of 4 INDEPENDENT loads (wave-uniform branch
// per chunk). Lanes beyond deg carry wt=0 / s=n, so over-fetch within a chunk
// is harmless. This breaks round-7's serialized shfl->load->fma chain
// (~250 cyc exposed latency per edge -> ~1/4).

constexpr int FCAP  = 64;
constexpr int FCAPP = 68;

__global__ __launch_bounds__(256) void k_edge(
    const __hip_bfloat162* __restrict__ h2, const float* __restrict__ as_,
    const float* __restrict__ ad_, const int* __restrict__ off,
    const int* __restrict__ esrc, const float* __restrict__ bias,
    int N, float* __restrict__ xout) {
    __shared__ float alphaS[4][4 * FCAPP];
    __shared__ int   srcS[4][FCAP];
    int t = threadIdx.x, lane = t & 63, w = t >> 6;
    int n = blockIdx.x * 4 + w;
    if (n >= N) return;
    int beg = off[n], end = off[n + 1];
    int deg = end - beg;
    float4 adn = ((const float4*)ad_)[n];
    const float4* as4 = (const float4*)as_;
    int hd = lane >> 4;

    float acc0 = 0.f, acc1 = 0.f;

    if (deg <= 16) {
        int e = lane >> 2, h = lane & 3;
        int s_e = n;
        float v = -1e30f;
        if (e < deg) {
            int s = esrc[beg + e];
            if ((unsigned)s < (unsigned)N) {
                s_e = s;
                float asv = as_[s * 4 + h];
                float adv = h == 0 ? adn.x : h == 1 ? adn.y : h == 2 ? adn.z : adn.w;
                v = asv + adv; v = v >= 0.f ? v : 0.2f * v;
            }
        }
        float m = v;
        #pragma unroll
        for (int o = 4; o < 64; o <<= 1) m = fmaxf(m, __shfl_xor(m, o, 64));
        float ex = (v > -1e29f) ? __expf(v - m) : 0.f;
        float ssum = ex;
        #pragma unroll
        for (int o = 4; o < 64; o <<= 1) ssum += __shfl_xor(ssum, o, 64);
        float inv = 1.f / (ssum + 1e-16f);
        float invH = __shfl(inv, hd, 64);

        // hoist all (wt, src) pairs into registers (constant indices)
        float wt[16]; int ss[16];
        #pragma unroll
        for (int i = 0; i < 16; i++) {
            wt[i] = __shfl(ex, 4 * i + hd, 64) * invH;
            ss[i] = __shfl(s_e, 4 * i, 64);
        }
        // 4 chunks x 4 independent loads, wave-uniform gating
        #pragma unroll
        for (int c = 0; c < 4; c++) {
            if (4 * c < deg) {
                __hip_bfloat162 g0 = h2[(size_t)ss[4*c+0] * 64 + lane];
                __hip_bfloat162 g1 = h2[(size_t)ss[4*c+1] * 64 + lane];
                __hip_bfloat162 g2 = h2[(size_t)ss[4*c+2] * 64 + lane];
                __hip_bfloat162 g3 = h2[(size_t)ss[4*c+3] * 64 + lane];
                acc0 += wt[4*c+0] * bf2f(g0.x) + wt[4*c+1] * bf2f(g1.x)
                      + wt[4*c+2] * bf2f(g2.x) + wt[4*c+3] * bf2f(g3.x);
                acc1 += wt[4*c+0] * bf2f(g0.y) + wt[4*c+1] * bf2f(g1.y)
                      + wt[4*c+2] * bf2f(g2.y) + wt[4*c+3] * bf2f(g3.y);
            }
        }
    } else {
        bool fits = (deg <= FCAP);
        float m0 = -1e30f, m1 = -1e30f, m2 = -1e30f, m3 = -1e30f;
        for (int e = beg + lane; e < end; e += 64) {
            int s = esrc[e];
            if ((unsigned)s >= (unsigned)N) continue;
            float4 a = as4[s];
            float v0 = a.x + adn.x; v0 = v0 >= 0.f ? v0 : 0.2f * v0;
            float v1 = a.y + adn.y; v1 = v1 >= 0.f ? v1 : 0.2f * v1;
            float v2 = a.z + adn.z; v2 = v2 >= 0.f ? v2 : 0.2f * v2;
            float v3 = a.w + adn.w; v3 = v3 >= 0.f ? v3 : 0.2f * v3;
            m0 = fmaxf(m0, v0); m1 = fmaxf(m1, v1); m2 = fmaxf(m2, v2); m3 = fmaxf(m3, v3);
        }
        #pragma unroll
        for (int o = 1; o < 64; o <<= 1) {
            m0 = fmaxf(m0, __shfl_xor(m0, o, 64));
            m1 = fmaxf(m1, __shfl_xor(m1, o, 64));
            m2 = fmaxf(m2, __shfl_xor(m2, o, 64));
            m3 = fmaxf(m3, __shfl_xor(m3, o, 64));
        }
        float s0 = 0.f, s1 = 0.f, s2 = 0.f, s3 = 0.f;
        for (int e = beg + lane; e < end; e += 64) {
            int s = esrc[e];
            bool ok = (unsigned)s < (unsigned)N;
            float4 a = ok ? as4[s] : make_float4(-1e30f, -1e30f, -1e30f, -1e30f);
            float v0 = a.x + adn.x; v0 = v0 >= 0.f ? v0 : 0.2f * v0;
            float v1 = a.y + adn.y; v1 = v1 >= 0.f ? v1 : 0.2f * v1;
            float v2 = a.z + adn.z; v2 = v2 >= 0.f ? v2 : 0.2f * v2;
            float v3 = a.w + adn.w; v3 = v3 >= 0.f ? v3 : 0.2f * v3;
            float e0 = __expf(v0 - m0), e1 = __expf(v1 - m1);
            float e2 = __expf(v2 - m2), e3 = __expf(v3 - m3);
            s0 += e0; s1 += e1; s2 += e2; s3 += e3;
            if (fits) {
                int i = e - beg;
                srcS[w][i] = ok ? s : n;
                alphaS[w][0 * FCAPP + i] = e0;
                alphaS[w][1 * FCAPP + i] = e1;
                alphaS[w][2 * FCAPP + i] = e2;
                alphaS[w][3 * FCAPP + i] = e3;
            }
        }
        #pragma unroll
        for (int o = 1; o < 64; o <<= 1) {
            s0 += __shfl_xor(s0, o, 64); s1 += __shfl_xor(s1, o, 64);
            s2 += __shfl_xor(s2, o, 64); s3 += __shfl_xor(s3, o, 64);
        }
        float i0 = 1.f / (s0 + 1e-16f), i1 = 1.f / (s1 + 1e-16f);
        float i2 = 1.f / (s2 + 1e-16f), i3 = 1.f / (s3 + 1e-16f);
        float invH = hd == 0 ? i0 : hd == 1 ? i1 : hd == 2 ? i2 : i3;
        if (fits) {
            for (int i = 0; i < deg; i++) {
                int s = srcS[w][i];
                float wt = alphaS[w][hd * FCAPP + i] * invH;
                __hip_bfloat162 hv = h2[(size_t)s * 64 + lane];
                acc0 += wt * bf2f(hv.x);
                acc1 += wt * bf2f(hv.y);
            }
        } else {
            float mH  = hd == 0 ? m0 : hd == 1 ? m1 : hd == 2 ? m2 : m3;
            float adH = hd == 0 ? adn.x : hd == 1 ? adn.y : hd == 2 ? adn.z : adn.w;
            for (int e = beg; e < end; e++) {
                int s = esrc[e];
                if ((unsigned)s >= (unsigned)N) continue;
                float4 a = as4[s];
                float aH = hd == 0 ? a.x : hd == 1 ? a.y : hd == 2 ? a.z : a.w;
                float v = aH + adH; v = v >= 0.f ? v : 0.2f * v;
                float wt = __expf(v - mH) * invH;
                __hip_bfloat162 hv = h2[(size_t)s * 64 + lane];
                acc0 += wt * bf2f(hv.x);
                acc1 += wt * bf2f(hv.y);
            }
        }
    }
    acc0 += __shfl_xor(acc0, 16, 64); acc0 += __shfl_xor(acc0, 32, 64);
    acc1 += __shfl_xor(acc1, 16, 64); acc1 += __shfl_xor(acc1, 32, 64);
    if (lane < 16) {
        float o0 = acc0 * 0.25f + bias[2 * lane];     o0 = o0 >= 0.f ? o0 : 0.01f * o0;
        float o1 = acc1 * 0.25f + bias[2 * lane + 1]; o1 = o1 >= 0.f ? o1 : 0.01f * o1;
        ((float2*)xout)[(size_t)n * 16 + lane] = make_float2(o0, o1);
    }
}

// ---------------- MLP + output scatter (unchanged from round 6) -------------

__global__ __launch_bounds__(128) void k_mlp(
    const float* __restrict__ xF, const float* __restrict__ x3,
    const float* __restrict__ mW1, const float* __restrict__ mb1,
    const float* __restrict__ mW2, const float* __restrict__ mb2,
    const float* __restrict__ mW3, const float* __restrict__ mb3,
    const float* __restrict__ mW4, const float* __restrict__ mb4,
    const float* __restrict__ mW5, const float* __restrict__ mb5,
    const int* __restrict__ smask, const int* __restrict__ totals,
    const int* __restrict__ flag, int N, void* __restrict__ out) {
    __shared__ float W1[35 * 32], W2[1024], W3[1024], W4[1024], W5[32 * 12];
    __shared__ float B1[32], B2[32], B3[32], B4[32], B5[12];
    __shared__ float actA[35 * 128];
    __shared__ float actB[32 * 128];
    int t = threadIdx.x;
    for (int i = t; i < 1120; i += 128) W1[i] = mW1[i];
    for (int i = t; i < 1024; i += 128) { W2[i] = mW2[i]; W3[i] = mW3[i]; W4[i] = mW4[i]; }
    for (int i = t; i < 384; i += 128) W5[i] = mW5[i];
    if (t < 32) { B1[t] = mb1[t]; B2[t] = mb2[t]; B3[t] = mb3[t]; B4[t] = mb4[t]; }
    if (t < 12) B5[t] = mb5[t];
    __syncthreads();

    int n = blockIdx.x * 128 + t;
    bool alive = (n < N);
    float x0 = 0.f;
    if (alive) {
        x0 = xF[n * 3 + 0];
        actA[0 * 128 + t] = x0;
        actA[1 * 128 + t] = xF[n * 3 + 1];
        actA[2 * 128 + t] = xF[n * 3 + 2];
        for (int i = 0; i < 32; i++) actA[(3 + i) * 128 + t] = x3[(size_t)n * 32 + i];
    }

    float acc[32];

    #pragma unroll
    for (int o = 0; o < 32; o++) acc[o] = B1[o];
    #pragma unroll 2
    for (int i = 0; i < 35; i++) {
        float ai = actA[i * 128 + t];
        const float4* w4 = (const float4*)&W1[i * 32];
        #pragma unroll
        for (int q = 0; q < 8; q++) {
            float4 w = w4[q];
            acc[q*4+0] += ai * w.x; acc[q*4+1] += ai * w.y;
            acc[q*4+2] += ai * w.z; acc[q*4+3] += ai * w.w;
        }
    }
    #pragma unroll
    for (int o = 0; o < 32; o++) { float v = acc[o]; actB[o * 128 + t] = (v >= 0.f ? v : 0.01f * v); }

    #pragma unroll
    for (int o = 0; o < 32; o++) acc[o] = B2[o];
    #pragma unroll 2
    for (int i = 0; i < 32; i++) {
        float ai = actB[i * 128 + t];
        const float4* w4 = (const float4*)&W2[i * 32];
        #pragma unroll
        for (int q = 0; q < 8; q++) {
            float4 w = w4[q];
            acc[q*4+0] += ai * w.x; acc[q*4+1] += ai * w.y;
            acc[q*4+2] += ai * w.z; acc[q*4+3] += ai * w.w;
        }
    }
    #pragma unroll
    for (int o = 0; o < 32; o++) { float v = acc[o]; actA[o * 128 + t] = (v >= 0.f ? v : 0.01f * v); }

    #pragma unroll
    for (int o = 0; o < 32; o++) acc[o] = B3[o];
    #pragma unroll 2
    for (int i = 0; i < 32; i++) {
        float ai = actA[i * 128 + t];
        const float4* w4 = (const float4*)&W3[i * 32];
        #pragma unroll
        for (int q = 0; q < 8; q++) {
            float4 w = w4[q];
            acc[q*4+0] += ai * w.x; acc[q*4+1] += ai * w.y;
            acc[q*4+2] += ai * w.z; acc[q*4+3] += ai * w.w;
        }
    }
    #pragma unroll
    for (int o = 0; o < 32; o++) { float v = acc[o]; actB[o * 128 + t] = (v >= 0.f ? v : 0.01f * v); }

    #pragma unroll
    for (int o = 0; o < 32; o++) acc[o] = B4[o];
    #pragma unroll 2
    for (int i = 0; i < 32; i++) {
        float ai = actB[i * 128 + t];
        const float4* w4 = (const float4*)&W4[i * 32];
        #pragma unroll
        for (int q = 0; q < 8; q++) {
            float4 w = w4[q];
            acc[q*4+0] += ai * w.x; acc[q*4+1] += ai * w.y;
            acc[q*4+2] += ai * w.z; acc[q*4+3] += ai * w.w;
        }
    }
    #pragma unroll
    for (int o = 0; o < 32; o++) { float v = acc[o]; actA[o * 128 + t] = (v >= 0.f ? v : 0.01f * v); }

    float d[12];
    #pragma unroll
    for (int o = 0; o < 12; o++) d[o] = B5[o];
    #pragma unroll 2
    for (int i = 0; i < 32; i++) {
        float ai = actA[i * 128 + t];
        const float4* w4 = (const float4*)&W5[i * 12];
        #pragma unroll
        for (int q = 0; q < 3; q++) {
            float4 w = w4[q];
            d[q*4+0] += ai * w.x; d[q*4+1] += ai * w.y;
            d[q*4+2] += ai * w.z; d[q*4+3] += ai * w.w;
        }
    }
    if (!alive) return;
    #pragma unroll
    for (int o = 0; o < 12; o++) if (!(d[o] == d[o])) d[o] = 0.f;  // NaN scrub

    bool tower = (x0 == 0.0f);
    int r = smask[n];
    int Nt = *totals;
    int f32o = *flag;
    int base9, base3, rr;
    if (tower) { rr = r;     base9 = 0;      base3 = 9 * N; }
    else       { rr = n - r; base9 = 9 * Nt; base3 = 9 * N + 3 * Nt; }
    if (f32o) {
        float* o = (float*)out;
        #pragma unroll
        for (int j = 0; j < 9; j++) o[base9 + rr * 9 + j] = d[j];
        #pragma unroll
        for (int j = 0; j < 3; j++) o[base3 + rr * 3 + j] = d[9 + j];
    } else {
        __hip_bfloat16* o = (__hip_bfloat16*)out;
        #pragma unroll
        for (int j = 0; j < 9; j++) o[base9 + rr * 9 + j] = __float2bfloat16(d[j]);
        #pragma unroll
        for (int j = 0; j < 3; j++) o[base3 + rr * 3 + j] = __float2bfloat16(d[9 + j]);
    }
}

// ---------------- launch ----------------

extern "C" void kernel_launch(void* const* d_in, const int* in_sizes, int n_in,
                              void* d_out, int out_size, void* d_ws, size_t ws_size,
                              hipStream_t stream) {
    const void* xraw = d_in[0];
    const int*  eidx = (const int*)d_in[1];
    // d_in[2] edge_attr: unused

    int N  = in_sizes[0] / 3;
    int E  = in_sizes[1] / 2;
    int EE = E + N;

    Segs segs;
    int coff[22];
    int canonN = 3 * N;
    for (int i = 3; i <= 24; i++) {
        int a = i - 3;
        segs.s[a].src = d_in[i];
        segs.s[a].off = canonN;
        segs.s[a].len = in_sizes[i];
        coff[a] = canonN;
        canonN += in_sizes[i];
    }

    auto alignv = [](size_t v, size_t a) { return (v + a - 1) & ~(a - 1); };
    char* base = (char*)d_ws;
    size_t o = 0;
    float* canon = (float*)(base + o); o = alignv(o + (size_t)canonN * 4, 16);
    int* flag     = (int*)(base + o); o = alignv(o + 16, 16);
    ull* partials = (ull*)(base + o); o = alignv(o + 1024 * 8, 16);
    int* totals   = (int*)(base + o); o = alignv(o + 16, 16);
    int* off      = (int*)(base + o); o = alignv(o + (size_t)(N + 1) * 4, 16);
    int* cur      = (int*)(base + o); o = alignv(o + (size_t)N * 4, 16);
    int* esrc     = (int*)(base + o); o = alignv(o + (size_t)EE * 4, 16);
    int* msk      = (int*)(base + o); o = alignv(o + (size_t)N * 4, 256);
    __hip_bfloat162* h2 = (__hip_bfloat162*)(base + o); o = alignv(o + (size_t)N * 64 * 4, 16);
    float* xb  = (float*)(base + o); o = alignv(o + (size_t)N * 32 * 4, 16);
    float* as_ = (float*)(base + o); o = alignv(o + (size_t)N * 16, 16);
    float* ad_ = (float*)(base + o);

    int nb = (N + 1023) / 1024;
    int gN = (N + 255) / 256;
    int g4 = (N + 3) / 4;
    int g64 = (N + 63) / 64;
    int gM = (N + 127) / 128;

    int nprobe = in_sizes[0] < 4096 ? in_sizes[0] : 4096;
    k_detect_zero<<<gN, 256, 0, stream>>>((const unsigned short*)xraw, nprobe, flag, cur, N);
    k_fused<<<86 + (E + 255) / 256, 256, 0, stream>>>(xraw, 3 * N, segs, canon, flag,
                                                      eidx, E, N, cur, msk);
    k_scan_partial64<<<nb, 256, 0, stream>>>(cur, msk, N, partials);
    k_scan_mid64<<<1, 256, 0, stream>>>(partials, nb, off + N, totals);
    k_scan_final64<<<nb, 256, 0, stream>>>(cur, msk, N, partials, off, cur);
    k_fill<<<(EE + 255) / 256, 256, 0, stream>>>(eidx, E, N, EE, cur, esrc);

    float* xF = canon;
    const float* W1  = canon + coff[0];  const float* aS1 = canon + coff[1];
    const float* aD1 = canon + coff[2];  const float* b1  = canon + coff[3];
    const float* W2  = canon + coff[4];  const float* aS2 = canon + coff[5];
    const float* aD2 = canon + coff[6];  const float* b2  = canon + coff[7];
    const float* W3  = canon + coff[8];  const float* aS3 = canon + coff[9];
    const float* aD3 = canon + coff[10]; const float* b3  = canon + coff[11];

    k_node_first<<<g64, 256, 0, stream>>>(xF, W1, aS1, aD1, N, h2, as_, ad_);
    k_edge<<<g4, 256, 0, stream>>>(h2, as_, ad_, off, esrc, b1, N, xb);
    k_node_mid<<<g64, 256, 0, stream>>>(xb, W2, aS2, aD2, N, h2, as_, ad_);
    k_edge<<<g4, 256, 0, stream>>>(h2, as_, ad_, off, esrc, b2, N, xb);
    k_node_mid<<<g64, 256, 0, stream>>>(xb, W3, aS3, aD3, N, h2, as_, ad_);
    k_edge<<<g4, 256, 0, stream>>>(h2, as_, ad_, off, esrc, b3, N, xb);

    k_mlp<<<gM, 128, 0, stream>>>(xF, xb,
        canon + coff[12], canon + coff[13], canon + coff[14], canon + coff[15],
        canon + coff[16], canon + coff[17], canon + coff[18], canon + coff[19],
        canon + coff[20], canon + coff[21], msk, totals, flag, N, d_out);
}

// Round 9
// 437.644 us; speedup vs baseline: 5.4536x; 1.1226x over previous
//
#include <hip/hip_runtime.h>
#include <hip/hip_bf16.h>

#define DEV __device__ __forceinline__

DEV float bf2f(__hip_bfloat16 v) { return __bfloat162float(v); }

typedef unsigned long long ull;

// ---------------- detect dtype + zero degree array ----------------
__global__ void k_detect_zero(const unsigned short* xr, int nprobe, int* flag,
                              int* cnt, int N) {
    int i = blockIdx.x * 256 + threadIdx.x;
    if (i < N) cnt[i] = 0;
    if (blockIdx.x == 0) {
        __shared__ int red[256];
        int t = threadIdx.x, bad = 0;
        for (int j = t; j < nprobe; j += 256) {
            unsigned e = (xr[j] >> 7) & 0xFF;
            if (e >= 0x8F) bad++;
        }
        red[t] = bad; __syncthreads();
        for (int o = 128; o > 0; o >>= 1) { if (t < o) red[t] += red[t + o]; __syncthreads(); }
        if (t == 0) flag[0] = (red[0] > 256) ? 1 : 0;   // 1 = inputs are f32
    }
}

// ---------------- fused ingest + tower mask + degree count (+rank) ----------
// The count atomicAdd's return value IS the edge's rank within its dst bucket
// -> stored to rank[] so the CSR fill needs no atomics at all (round-9).
struct Seg  { const void* src; int off; int len; };
struct Segs { Seg s[22]; };

__global__ void k_fused(const void* xsrc, int nx3, Segs segs, float* canon,
                        const int* flag, const int* eidx, int E, int N,
                        int* cnt, int* msk, int* rank) {
    int f32 = flag[0];
    int t = threadIdx.x, b = blockIdx.x;
    if (b < 64) {
        for (int i = b * 256 + t; i < nx3; i += 64 * 256) {
            float v = f32 ? ((const float*)xsrc)[i] : bf2f(((const __hip_bfloat16*)xsrc)[i]);
            if (!(v == v) || fabsf(v) > 1e30f) v = 0.f;   // scrub
            canon[i] = v;
            if (i % 3 == 0) msk[i / 3] = (v == 0.0f) ? 1 : 0;
        }
    } else if (b < 86) {
        Seg sg = segs.s[b - 64];
        for (int i = t; i < sg.len; i += 256) {
            float v = f32 ? ((const float*)sg.src)[i] : bf2f(((const __hip_bfloat16*)sg.src)[i]);
            if (!(v == v) || fabsf(v) > 1e30f) v = 0.f;
            canon[sg.off + i] = v;
        }
    } else {
        int e = (b - 86) * 256 + t;
        if (e < E) {
            int d = eidx[E + e];
            if ((unsigned)d < (unsigned)N) {
                int p = atomicAdd(&cnt[d], 1);
                rank[e] = p;
            }
        }
    }
}

// ---------------- packed 64-bit exclusive scan ------------------------------

DEV ull packval(const int* cnt, const int* msk, int i) {
    return ((ull)(unsigned)msk[i] << 32) | (unsigned)(cnt[i] + 1);
}

__global__ void k_scan_partial64(const int* __restrict__ cnt, const int* __restrict__ msk,
                                 int n, ull* __restrict__ partials) {
    __shared__ ull red[256];
    int t = threadIdx.x, b = blockIdx.x;
    int base = b * 1024 + t * 4;
    ull s = 0;
    #pragma unroll
    for (int j = 0; j < 4; j++) { int i = base + j; if (i < n) s += packval(cnt, msk, i); }
    red[t] = s; __syncthreads();
    for (int o = 128; o > 0; o >>= 1) { if (t < o) red[t] += red[t + o]; __syncthreads(); }
    if (t == 0) partials[b] = red[0];
}

__global__ void k_scan_mid64(ull* partials, int nb, int* offN, int* totals) {
    __shared__ ull sh[256];
    int t = threadIdx.x;
    ull carry = 0;
    for (int base = 0; base < nb; base += 256) {
        int i = base + t;
        ull v = (i < nb) ? partials[i] : 0;
        sh[t] = v; __syncthreads();
        for (int o = 1; o < 256; o <<= 1) {
            ull x = (t >= o) ? sh[t - o] : 0;
            __syncthreads();
            sh[t] += x;
            __syncthreads();
        }
        if (i < nb) partials[i] = carry + sh[t] - v;   // exclusive
        ull tot = sh[255];
        __syncthreads();
        carry += tot;
    }
    if (t == 0) { *offN = (int)(carry & 0xffffffffu); *totals = (int)(carry >> 32); }
}

__global__ void k_scan_final64(const int* __restrict__ cnt, int* __restrict__ msk, int n,
                               const ull* __restrict__ partials,
                               int* __restrict__ off) {
    __shared__ ull sums[256];
    int t = threadIdx.x, b = blockIdx.x;
    int base = b * 1024 + t * 4;
    ull v0 = 0, v1 = 0, v2 = 0, v3 = 0;
    if (base     < n) v0 = packval(cnt, msk, base);
    if (base + 1 < n) v1 = packval(cnt, msk, base + 1);
    if (base + 2 < n) v2 = packval(cnt, msk, base + 2);
    if (base + 3 < n) v3 = packval(cnt, msk, base + 3);
    ull s = v0 + v1 + v2 + v3;
    sums[t] = s; __syncthreads();
    for (int o = 1; o < 256; o <<= 1) {
        ull x = (t >= o) ? sums[t - o] : 0;
        __syncthreads();
        sums[t] += x;
        __syncthreads();
    }
    ull run = partials[b] + (sums[t] - s);
    #pragma unroll
    for (int j = 0; j < 4; j++) {
        int i = base + j;
        if (i < n) {
            off[i] = (int)(run & 0xffffffffu);
            msk[i] = (int)(run >> 32);
            run += (j == 0 ? v0 : j == 1 ? v1 : j == 2 ? v2 : v3);
        }
    }
}

// ---------------- fused CSR fill (atomic-free) + GAT layer-1 node -----------
// Blocks [0, gfill) scatter edges via precomputed rank (self-loop at
// off[d+1]-1); blocks [gfill, ...) run the layer-1 node transform. The two
// are independent (both only need scan_final64 + k_fused outputs).

__global__ __launch_bounds__(256) void k_fill_node1(
    const int* __restrict__ eidx, const int* __restrict__ rank, int E, int N,
    const int* __restrict__ off, int* __restrict__ esrc,
    const float* __restrict__ xF, const float* __restrict__ W,
    const float* __restrict__ atS, const float* __restrict__ atD,
    __hip_bfloat162* __restrict__ h2, float* __restrict__ as_, float* __restrict__ ad_,
    int gfill) {
    __shared__ float xl[64 * 4];
    int b = blockIdx.x;
    if (b < gfill) {
        int e = b * 256 + threadIdx.x;
        if (e < E) {
            int s = eidx[e], d = eidx[E + e];
            if ((unsigned)d < (unsigned)N && (unsigned)s < (unsigned)N)
                esrc[off[d] + rank[e]] = s;
        } else if (e < E + N) {
            int i = e - E;
            esrc[off[i + 1] - 1] = i;   // self-loop in the last slot
        }
        return;
    }
    int t = threadIdx.x, lane = t & 63, w = t >> 6;
    int nblk = (b - gfill) * 64;
    int cnt = N - nblk; if (cnt > 64) cnt = 64;

    if (t < 64) xl[t * 4 + 3] = 0.f;
    for (int i = t; i < cnt * 3; i += 256) xl[(i / 3) * 4 + (i % 3)] = xF[(size_t)nblk * 3 + i];

    const float2* W2 = (const float2*)W;
    float2 Wr0 = W2[0 * 64 + lane], Wr1 = W2[1 * 64 + lane], Wr2 = W2[2 * 64 + lane];
    float2 aSp = ((const float2*)atS)[lane];
    float2 aDp = ((const float2*)atD)[lane];
    int hd = lane >> 4;
    __syncthreads();

    for (int i = 0; i < 16; i++) {
        int n = nblk + w * 16 + i;
        if (n >= N) break;
        float4 xv = ((const float4*)xl)[w * 16 + i];
        float acc0 = xv.x * Wr0.x + xv.y * Wr1.x + xv.z * Wr2.x;
        float acc1 = xv.x * Wr0.y + xv.y * Wr1.y + xv.z * Wr2.y;
        __hip_bfloat162 hv; hv.x = __float2bfloat16(acc0); hv.y = __float2bfloat16(acc1);
        h2[(size_t)n * 64 + lane] = hv;
        float p = acc0 * aSp.x + acc1 * aSp.y;
        float q = acc0 * aDp.x + acc1 * aDp.y;
        #pragma unroll
        for (int o = 1; o < 16; o <<= 1) { p += __shfl_xor(p, o, 64); q += __shfl_xor(q, o, 64); }
        if ((lane & 15) == 0) { as_[n * 4 + hd] = p; ad_[n * 4 + hd] = q; }
    }
}

// ---------------- GAT node kernel (layers 2,3; unchanged from round 7) ------

__global__ __launch_bounds__(256) void k_node_mid(
    const float* __restrict__ xin, const float* __restrict__ W,
    const float* __restrict__ atS, const float* __restrict__ atD,
    int N, __hip_bfloat162* __restrict__ h2, float* __restrict__ as_, float* __restrict__ ad_) {
    __shared__ float xl[64 * 32];
    int t = threadIdx.x, lane = t & 63, w = t >> 6;
    int nblk = blockIdx.x * 64;
    int cnt = N - nblk; if (cnt > 64) cnt = 64;

    {
        const float4* g4 = (const float4*)(xin + (size_t)nblk * 32);
        float4* l4 = (float4*)xl;
        int lim = cnt * 8;
        if (t < lim) l4[t] = g4[t];
        int t2 = t + 256;
        if (t2 < lim) l4[t2] = g4[t2];
    }

    const float2* W2 = (const float2*)W;
    float2 Wr[32];
    #pragma unroll
    for (int k = 0; k < 32; k++) Wr[k] = W2[k * 64 + lane];
    float2 aSp = ((const float2*)atS)[lane];
    float2 aDp = ((const float2*)atD)[lane];
    int hd = lane >> 4;
    __syncthreads();

    for (int i = 0; i < 16; i++) {
        int n = nblk + w * 16 + i;
        if (n >= N) break;
        const float4* xv4 = (const float4*)&xl[(w * 16 + i) * 32];
        float acc0 = 0.f, acc1 = 0.f;
        #pragma unroll
        for (int kk = 0; kk < 8; kk++) {
            float4 xv = xv4[kk];
            acc0 += xv.x * Wr[4*kk+0].x; acc1 += xv.x * Wr[4*kk+0].y;
            acc0 += xv.y * Wr[4*kk+1].x; acc1 += xv.y * Wr[4*kk+1].y;
            acc0 += xv.z * Wr[4*kk+2].x; acc1 += xv.z * Wr[4*kk+2].y;
            acc0 += xv.w * Wr[4*kk+3].x; acc1 += xv.w * Wr[4*kk+3].y;
        }
        __hip_bfloat162 hv; hv.x = __float2bfloat16(acc0); hv.y = __float2bfloat16(acc1);
        h2[(size_t)n * 64 + lane] = hv;
        float p = acc0 * aSp.x + acc1 * aSp.y;
        float q = acc0 * aDp.x + acc1 * aDp.y;
        #pragma unroll
        for (int o = 1; o < 16; o <<= 1) { p += __shfl_xor(p, o, 64); q += __shfl_xor(q, o, 64); }
        if ((lane & 15) == 0) { as_[n * 4 + hd] = p; ad_[n * 4 + hd] = q; }
    }
}

// ---------------- GAT edge kernel -------------------------------------------
// Round-9: fast path hoist is chunk-gated (deg 9 typical -> 3 of 4 chunks),
// saving ~8 shuffles + 4 muls per skipped chunk vs round-8's full hoist.

constexpr int FCAP  = 64;
constexpr int FCAPP = 68;

__global__ __launch_bounds__(256) void k_edge(
    const __hip_bfloat162* __restrict__ h2, const float* __restrict__ as_,
    const float* __restrict__ ad_, const int* __restrict__ off,
    const int* __restrict__ esrc, const float* __restrict__ bias,
    int N, float* __restrict__ xout) {
    __shared__ float alphaS[4][4 * FCAPP];
    __shared__ int   srcS[4][FCAP];
    int t = threadIdx.x, lane = t & 63, w = t >> 6;
    int n = blockIdx.x * 4 + w;
    if (n >= N) return;
    int beg = off[n], end = off[n + 1];
    int deg = end - beg;
    float4 adn = ((const float4*)ad_)[n];
    const float4* as4 = (const float4*)as_;
    int hd = lane >> 4;

    float acc0 = 0.f, acc1 = 0.f;

    if (deg <= 16) {
        int e = lane >> 2, h = lane & 3;
        int s_e = n;
        float v = -1e30f;
        if (e < deg) {
            int s = esrc[beg + e];
            if ((unsigned)s < (unsigned)N) {
                s_e = s;
                float asv = as_[s * 4 + h];
                float adv = h == 0 ? adn.x : h == 1 ? adn.y : h == 2 ? adn.z : adn.w;
                v = asv + adv; v = v >= 0.f ? v : 0.2f * v;
            }
        }
        float m = v;
        #pragma unroll
        for (int o = 4; o < 64; o <<= 1) m = fmaxf(m, __shfl_xor(m, o, 64));
        float ex = (v > -1e29f) ? __expf(v - m) : 0.f;
        float ssum = ex;
        #pragma unroll
        for (int o = 4; o < 64; o <<= 1) ssum += __shfl_xor(ssum, o, 64);
        float inv = 1.f / (ssum + 1e-16f);
        float invH = __shfl(inv, hd, 64);

        // chunk-gated hoist + gather: 4 edges (16 lanes) per chunk
        #pragma unroll
        for (int c = 0; c < 4; c++) {
            if (4 * c < deg) {
                float w0 = __shfl(ex, 16 * c + 0  + hd, 64) * invH;
                float w1 = __shfl(ex, 16 * c + 4  + hd, 64) * invH;
                float w2 = __shfl(ex, 16 * c + 8  + hd, 64) * invH;
                float w3 = __shfl(ex, 16 * c + 12 + hd, 64) * invH;
                int s0 = __shfl(s_e, 16 * c + 0, 64);
                int s1 = __shfl(s_e, 16 * c + 4, 64);
                int s2 = __shfl(s_e, 16 * c + 8, 64);
                int s3 = __shfl(s_e, 16 * c + 12, 64);
                __hip_bfloat162 g0 = h2[(size_t)s0 * 64 + lane];
                __hip_bfloat162 g1 = h2[(size_t)s1 * 64 + lane];
                __hip_bfloat162 g2 = h2[(size_t)s2 * 64 + lane];
                __hip_bfloat162 g3 = h2[(size_t)s3 * 64 + lane];
                acc0 += w0 * bf2f(g0.x) + w1 * bf2f(g1.x) + w2 * bf2f(g2.x) + w3 * bf2f(g3.x);
                acc1 += w0 * bf2f(g0.y) + w1 * bf2f(g1.y) + w2 * bf2f(g2.y) + w3 * bf2f(g3.y);
            }
        }
    } else {
        bool fits = (deg <= FCAP);
        float m0 = -1e30f, m1 = -1e30f, m2 = -1e30f, m3 = -1e30f;
        for (int e = beg + lane; e < end; e += 64) {
            int s = esrc[e];
            if ((unsigned)s >= (unsigned)N) continue;
            float4 a = as4[s];
            float v0 = a.x + adn.x; v0 = v0 >= 0.f ? v0 : 0.2f * v0;
            float v1 = a.y + adn.y; v1 = v1 >= 0.f ? v1 : 0.2f * v1;
            float v2 = a.z + adn.z; v2 = v2 >= 0.f ? v2 : 0.2f * v2;
            float v3 = a.w + adn.w; v3 = v3 >= 0.f ? v3 : 0.2f * v3;
            m0 = fmaxf(m0, v0); m1 = fmaxf(m1, v1); m2 = fmaxf(m2, v2); m3 = fmaxf(m3, v3);
        }
        #pragma unroll
        for (int o = 1; o < 64; o <<= 1) {
            m0 = fmaxf(m0, __shfl_xor(m0, o, 64));
            m1 = fmaxf(m1, __shfl_xor(m1, o, 64));
            m2 = fmaxf(m2, __shfl_xor(m2, o, 64));
            m3 = fmaxf(m3, __shfl_xor(m3, o, 64));
        }
        float s0 = 0.f, s1 = 0.f, s2 = 0.f, s3 = 0.f;
        for (int e = beg + lane; e < end; e += 64) {
            int s = esrc[e];
            bool ok = (unsigned)s < (unsigned)N;
            float4 a = ok ? as4[s] : make_float4(-1e30f, -1e30f, -1e30f, -1e30f);
            float v0 = a.x + adn.x; v0 = v0 >= 0.f ? v0 : 0.2f * v0;
            float v1 = a.y + adn.y; v1 = v1 >= 0.f ? v1 : 0.2f * v1;
            float v2 = a.z + adn.z; v2 = v2 >= 0.f ? v2 : 0.2f * v2;
            float v3 = a.w + adn.w; v3 = v3 >= 0.f ? v3 : 0.2f * v3;
            float e0 = __expf(v0 - m0), e1 = __expf(v1 - m1);
            float e2 = __expf(v2 - m2), e3 = __expf(v3 - m3);
            s0 += e0; s1 += e1; s2 += e2; s3 += e3;
            if (fits) {
                int i = e - beg;
                srcS[w][i] = ok ? s : n;
                alphaS[w][0 * FCAPP + i] = e0;
                alphaS[w][1 * FCAPP + i] = e1;
                alphaS[w][2 * FCAPP + i] = e2;
                alphaS[w][3 * FCAPP + i] = e3;
            }
        }
        #pragma unroll
        for (int o = 1; o < 64; o <<= 1) {
            s0 += __shfl_xor(s0, o, 64); s1 += __shfl_xor(s1, o, 64);
            s2 += __shfl_xor(s2, o, 64); s3 += __shfl_xor(s3, o, 64);
        }
        float i0 = 1.f / (s0 + 1e-16f), i1 = 1.f / (s1 + 1e-16f);
        float i2 = 1.f / (s2 + 1e-16f), i3 = 1.f / (s3 + 1e-16f);
        float invH = hd == 0 ? i0 : hd == 1 ? i1 : hd == 2 ? i2 : i3;
        if (fits) {
            for (int i = 0; i < deg; i++) {
                int s = srcS[w][i];
                float wt = alphaS[w][hd * FCAPP + i] * invH;
                __hip_bfloat162 hv = h2[(size_t)s * 64 + lane];
                acc0 += wt * bf2f(hv.x);
                acc1 += wt * bf2f(hv.y);
            }
        } else {
            float mH  = hd == 0 ? m0 : hd == 1 ? m1 : hd == 2 ? m2 : m3;
            float adH = hd == 0 ? adn.x : hd == 1 ? adn.y : hd == 2 ? adn.z : adn.w;
            for (int e = beg; e < end; e++) {
                int s = esrc[e];
                if ((unsigned)s >= (unsigned)N) continue;
                float4 a = as4[s];
                float aH = hd == 0 ? a.x : hd == 1 ? a.y : hd == 2 ? a.z : a.w;
                float v = aH + adH; v = v >= 0.f ? v : 0.2f * v;
                float wt = __expf(v - mH) * invH;
                __hip_bfloat162 hv = h2[(size_t)s * 64 + lane];
                acc0 += wt * bf2f(hv.x);
                acc1 += wt * bf2f(hv.y);
            }
        }
    }
    acc0 += __shfl_xor(acc0, 16, 64); acc0 += __shfl_xor(acc0, 32, 64);
    acc1 += __shfl_xor(acc1, 16, 64); acc1 += __shfl_xor(acc1, 32, 64);
    if (lane < 16) {
        float o0 = acc0 * 0.25f + bias[2 * lane];     o0 = o0 >= 0.f ? o0 : 0.01f * o0;
        float o1 = acc1 * 0.25f + bias[2 * lane + 1]; o1 = o1 >= 0.f ? o1 : 0.01f * o1;
        ((float2*)xout)[(size_t)n * 16 + lane] = make_float2(o0, o1);
    }
}

// ---------------- MLP + output scatter (unchanged) --------------------------

__global__ __launch_bounds__(128) void k_mlp(
    const float* __restrict__ xF, const float* __restrict__ x3,
    const float* __restrict__ mW1, const float* __restrict__ mb1,
    const float* __restrict__ mW2, const float* __restrict__ mb2,
    const float* __restrict__ mW3, const float* __restrict__ mb3,
    const float* __restrict__ mW4, const float* __restrict__ mb4,
    const float* __restrict__ mW5, const float* __restrict__ mb5,
    const int* __restrict__ smask, const int* __restrict__ totals,
    const int* __restrict__ flag, int N, void* __restrict__ out) {
    __shared__ float W1[35 * 32], W2[1024], W3[1024], W4[1024], W5[32 * 12];
    __shared__ float B1[32], B2[32], B3[32], B4[32], B5[12];
    __shared__ float actA[35 * 128];
    __shared__ float actB[32 * 128];
    int t = threadIdx.x;
    for (int i = t; i < 1120; i += 128) W1[i] = mW1[i];
    for (int i = t; i < 1024; i += 128) { W2[i] = mW2[i]; W3[i] = mW3[i]; W4[i] = mW4[i]; }
    for (int i = t; i < 384; i += 128) W5[i] = mW5[i];
    if (t < 32) { B1[t] = mb1[t]; B2[t] = mb2[t]; B3[t] = mb3[t]; B4[t] = mb4[t]; }
    if (t < 12) B5[t] = mb5[t];
    __syncthreads();

    int n = blockIdx.x * 128 + t;
    bool alive = (n < N);
    float x0 = 0.f;
    if (alive) {
        x0 = xF[n * 3 + 0];
        actA[0 * 128 + t] = x0;
        actA[1 * 128 + t] = xF[n * 3 + 1];
        actA[2 * 128 + t] = xF[n * 3 + 2];
        for (int i = 0; i < 32; i++) actA[(3 + i) * 128 + t] = x3[(size_t)n * 32 + i];
    }

    float acc[32];

    #pragma unroll
    for (int o = 0; o < 32; o++) acc[o] = B1[o];
    #pragma unroll 2
    for (int i = 0; i < 35; i++) {
        float ai = actA[i * 128 + t];
        const float4* w4 = (const float4*)&W1[i * 32];
        #pragma unroll
        for (int q = 0; q < 8; q++) {
            float4 w = w4[q];
            acc[q*4+0] += ai * w.x; acc[q*4+1] += ai * w.y;
            acc[q*4+2] += ai * w.z; acc[q*4+3] += ai * w.w;
        }
    }
    #pragma unroll
    for (int o = 0; o < 32; o++) { float v = acc[o]; actB[o * 128 + t] = (v >= 0.f ? v : 0.01f * v); }

    #pragma unroll
    for (int o = 0; o < 32; o++) acc[o] = B2[o];
    #pragma unroll 2
    for (int i = 0; i < 32; i++) {
        float ai = actB[i * 128 + t];
        const float4* w4 = (const float4*)&W2[i * 32];
        #pragma unroll
        for (int q = 0; q < 8; q++) {
            float4 w = w4[q];
            acc[q*4+0] += ai * w.x; acc[q*4+1] += ai * w.y;
            acc[q*4+2] += ai * w.z; acc[q*4+3] += ai * w.w;
        }
    }
    #pragma unroll
    for (int o = 0; o < 32; o++) { float v = acc[o]; actA[o * 128 + t] = (v >= 0.f ? v : 0.01f * v); }

    #pragma unroll
    for (int o = 0; o < 32; o++) acc[o] = B3[o];
    #pragma unroll 2
    for (int i = 0; i < 32; i++) {
        float ai = actA[i * 128 + t];
        const float4* w4 = (const float4*)&W3[i * 32];
        #pragma unroll
        for (int q = 0; q < 8; q++) {
            float4 w = w4[q];
            acc[q*4+0] += ai * w.x; acc[q*4+1] += ai * w.y;
            acc[q*4+2] += ai * w.z; acc[q*4+3] += ai * w.w;
        }
    }
    #pragma unroll
    for (int o = 0; o < 32; o++) { float v = acc[o]; actB[o * 128 + t] = (v >= 0.f ? v : 0.01f * v); }

    #pragma unroll
    for (int o = 0; o < 32; o++) acc[o] = B4[o];
    #pragma unroll 2
    for (int i = 0; i < 32; i++) {
        float ai = actB[i * 128 + t];
        const float4* w4 = (const float4*)&W4[i * 32];
        #pragma unroll
        for (int q = 0; q < 8; q++) {
            float4 w = w4[q];
            acc[q*4+0] += ai * w.x; acc[q*4+1] += ai * w.y;
            acc[q*4+2] += ai * w.z; acc[q*4+3] += ai * w.w;
        }
    }
    #pragma unroll
    for (int o = 0; o < 32; o++) { float v = acc[o]; actA[o * 128 + t] = (v >= 0.f ? v : 0.01f * v); }

    float d[12];
    #pragma unroll
    for (int o = 0; o < 12; o++) d[o] = B5[o];
    #pragma unroll 2
    for (int i = 0; i < 32; i++) {
        float ai = actA[i * 128 + t];
        const float4* w4 = (const float4*)&W5[i * 12];
        #pragma unroll
        for (int q = 0; q < 3; q++) {
            float4 w = w4[q];
            d[q*4+0] += ai * w.x; d[q*4+1] += ai * w.y;
            d[q*4+2] += ai * w.z; d[q*4+3] += ai * w.w;
        }
    }
    if (!alive) return;
    #pragma unroll
    for (int o = 0; o < 12; o++) if (!(d[o] == d[o])) d[o] = 0.f;  // NaN scrub

    bool tower = (x0 == 0.0f);
    int r = smask[n];
    int Nt = *totals;
    int f32o = *flag;
    int base9, base3, rr;
    if (tower) { rr = r;     base9 = 0;      base3 = 9 * N; }
    else       { rr = n - r; base9 = 9 * Nt; base3 = 9 * N + 3 * Nt; }
    if (f32o) {
        float* o = (float*)out;
        #pragma unroll
        for (int j = 0; j < 9; j++) o[base9 + rr * 9 + j] = d[j];
        #pragma unroll
        for (int j = 0; j < 3; j++) o[base3 + rr * 3 + j] = d[9 + j];
    } else {
        __hip_bfloat16* o = (__hip_bfloat16*)out;
        #pragma unroll
        for (int j = 0; j < 9; j++) o[base9 + rr * 9 + j] = __float2bfloat16(d[j]);
        #pragma unroll
        for (int j = 0; j < 3; j++) o[base3 + rr * 3 + j] = __float2bfloat16(d[9 + j]);
    }
}

// ---------------- launch ----------------

extern "C" void kernel_launch(void* const* d_in, const int* in_sizes, int n_in,
                              void* d_out, int out_size, void* d_ws, size_t ws_size,
                              hipStream_t stream) {
    const void* xraw = d_in[0];
    const int*  eidx = (const int*)d_in[1];
    // d_in[2] edge_attr: unused

    int N  = in_sizes[0] / 3;
    int E  = in_sizes[1] / 2;
    int EE = E + N;

    Segs segs;
    int coff[22];
    int canonN = 3 * N;
    for (int i = 3; i <= 24; i++) {
        int a = i - 3;
        segs.s[a].src = d_in[i];
        segs.s[a].off = canonN;
        segs.s[a].len = in_sizes[i];
        coff[a] = canonN;
        canonN += in_sizes[i];
    }

    auto alignv = [](size_t v, size_t a) { return (v + a - 1) & ~(a - 1); };
    char* base = (char*)d_ws;
    size_t o = 0;
    float* canon = (float*)(base + o); o = alignv(o + (size_t)canonN * 4, 16);
    int* flag     = (int*)(base + o); o = alignv(o + 16, 16);
    ull* partials = (ull*)(base + o); o = alignv(o + 1024 * 8, 16);
    int* totals   = (int*)(base + o); o = alignv(o + 16, 16);
    int* off      = (int*)(base + o); o = alignv(o + (size_t)(N + 1) * 4, 16);
    int* cnt      = (int*)(base + o); o = alignv(o + (size_t)N * 4, 16);
    int* esrc     = (int*)(base + o); o = alignv(o + (size_t)EE * 4, 16);
    int* rank     = (int*)(base + o); o = alignv(o + (size_t)E * 4, 16);
    int* msk      = (int*)(base + o); o = alignv(o + (size_t)N * 4, 256);
    __hip_bfloat162* h2 = (__hip_bfloat162*)(base + o); o = alignv(o + (size_t)N * 64 * 4, 16);
    float* xb  = (float*)(base + o); o = alignv(o + (size_t)N * 32 * 4, 16);
    float* as_ = (float*)(base + o); o = alignv(o + (size_t)N * 16, 16);
    float* ad_ = (float*)(base + o);

    int nb = (N + 1023) / 1024;
    int gN = (N + 255) / 256;
    int g4 = (N + 3) / 4;
    int g64 = (N + 63) / 64;
    int gM = (N + 127) / 128;
    int gfill = (EE + 255) / 256;

    int nprobe = in_sizes[0] < 4096 ? in_sizes[0] : 4096;
    k_detect_zero<<<gN, 256, 0, stream>>>((const unsigned short*)xraw, nprobe, flag, cnt, N);
    k_fused<<<86 + (E + 255) / 256, 256, 0, stream>>>(xraw, 3 * N, segs, canon, flag,
                                                      eidx, E, N, cnt, msk, rank);
    k_scan_partial64<<<nb, 256, 0, stream>>>(cnt, msk, N, partials);
    k_scan_mid64<<<1, 256, 0, stream>>>(partials, nb, off + N, totals);
    k_scan_final64<<<nb, 256, 0, stream>>>(cnt, msk, N, partials, off);

    float* xF = canon;
    const float* W1  = canon + coff[0];  const float* aS1 = canon + coff[1];
    const float* aD1 = canon + coff[2];  const float* b1  = canon + coff[3];
    const float* W2  = canon + coff[4];  const float* aS2 = canon + coff[5];
    const float* aD2 = canon + coff[6];  const float* b2  = canon + coff[7];
    const float* W3  = canon + coff[8];  const float* aS3 = canon + coff[9];
    const float* aD3 = canon + coff[10]; const float* b3  = canon + coff[11];

    k_fill_node1<<<gfill + g64, 256, 0, stream>>>(eidx, rank, E, N, off, esrc,
                                                  xF, W1, aS1, aD1, h2, as_, ad_, gfill);
    k_edge<<<g4, 256, 0, stream>>>(h2, as_, ad_, off, esrc, b1, N, xb);
    k_node_mid<<<g64, 256, 0, stream>>>(xb, W2, aS2, aD2, N, h2, as_, ad_);
    k_edge<<<g4, 256, 0, stream>>>(h2, as_, ad_, off, esrc, b2, N, xb);
    k_node_mid<<<g64, 256, 0, stream>>>(xb, W3, aS3, aD3, N, h2, as_, ad_);
    k_edge<<<g4, 256, 0, stream>>>(h2, as_, ad_, off, esrc, b3, N, xb);

    k_mlp<<<gM, 128, 0, stream>>>(xF, xb,
        canon + coff[12], canon + coff[13], canon + coff[14], canon + coff[15],
        canon + coff[16], canon + coff[17], canon + coff[18], canon + coff[19],
        canon + coff[20], canon + coff[21], msk, totals, flag, N, d_out);
}